// Round 2
// baseline (540.457 us; speedup 1.0000x reference)
//
#include <hip/hip_runtime.h>

#define NN 100000
#define NE 1600000
#define D 128
#define LEAKY 0.01f
#define BNEPS 1e-5f

#define G 256        // sort groups (workgroups)
#define CHUNK 6250   // NE / G exactly
#define B 782        // ceil(NN/128) dst-buckets
#define BSHIFT 7
#define BMASK 127
#define NXCD 8       // MI355X: 8 XCDs, each with private (non-cross-coherent) L2

typedef short v8s __attribute__((ext_vector_type(8)));
typedef float v4f __attribute__((ext_vector_type(4)));

// round-to-nearest-even f32 -> bf16 (returns low 16 bits)
__device__ __forceinline__ unsigned f2bf(float f) {
    unsigned u = __float_as_uint(f);
    return (u + 0x7fffu + ((u >> 16) & 1u)) >> 16;
}
__device__ __forceinline__ float bf2f(unsigned h) {
    return __uint_as_float(h << 16);
}

// physical XCD id (0..7)
__device__ __forceinline__ int xcc_id() {
    int x;
    asm volatile("s_getreg_b32 %0, hwreg(HW_REG_XCC_ID)" : "=s"(x));
    return x & (NXCD - 1);
}

// ---------------- counting sort by dst bucket + fused out-degree ----------------
// Round-1 evidence: workgroup-scope atomics did NOT change WRITE_SIZE (56 MB
// both ways) -> deg atomics execute memory-side regardless; 1024-thread blocks
// (occupancy 9->38%) bought 72->66 us. Kept as measured.

__global__ __launch_bounds__(1024) void hist_kernel(const int* __restrict__ src,
                                                    const int* __restrict__ dst,
                                                    int* __restrict__ degP,
                                                    int* __restrict__ hist) {
    __shared__ int h[B];
    for (int i = threadIdx.x; i < B; i += 1024) h[i] = 0;
    __syncthreads();
    int g = blockIdx.x;
    int* dp0 = (int*)(degP) + (size_t)xcc_id() * NN;
    const int* dp = dst + g * CHUNK;
    const int* sp = src + g * CHUNK;
    for (int k = threadIdx.x; k < CHUNK; k += 1024) {
        atomicAdd(&h[dp[k] >> BSHIFT], 1);
        __hip_atomic_fetch_add(&dp0[sp[k]], 1, __ATOMIC_RELAXED,
                               __HIP_MEMORY_SCOPE_WORKGROUP);
    }
    __syncthreads();
    for (int i = threadIdx.x; i < B; i += 1024) hist[i * G + g] = h[i];
}

__global__ void scanA(const int* __restrict__ a, int* __restrict__ bsum) {
    __shared__ int sm[256];
    int t = threadIdx.x;
    sm[t] = a[blockIdx.x * 256 + t];
    __syncthreads();
    for (int s = 128; s > 0; s >>= 1) {
        if (t < s) sm[t] += sm[t + s];
        __syncthreads();
    }
    if (t == 0) bsum[blockIdx.x] = sm[0];
}

__global__ void scanB(const int* __restrict__ bsum, int* __restrict__ boffs) {
    int lane = threadIdx.x;
    int run = 0;
    for (int base = 0; base < B; base += 64) {
        int i = base + lane;
        int v = (i < B) ? bsum[i] : 0;
        int orig = v;
        for (int off = 1; off < 64; off <<= 1) {
            int t = __shfl_up(v, off);
            if (lane >= off) v += t;
        }
        if (i < B) boffs[i] = run + v - orig;   // exclusive
        run += __shfl(v, 63);
    }
}

__global__ void scanC(const int* __restrict__ a, const int* __restrict__ boffs,
                      int* __restrict__ offs) {
    __shared__ int sm[256];
    int t = threadIdx.x;
    int i = blockIdx.x * 256 + t;
    int v = a[i];
    sm[t] = v;
    __syncthreads();
    for (int off = 1; off < 256; off <<= 1) {
        int x = (t >= off) ? sm[t - off] : 0;
        __syncthreads();
        sm[t] += x;
        __syncthreads();
    }
    offs[i] = boffs[blockIdx.x] + sm[t] - v;    // exclusive
}

__global__ __launch_bounds__(1024) void sort_kernel(const int* __restrict__ src,
                                                    const int* __restrict__ dst,
                                                    const int* __restrict__ offs,
                                                    unsigned* __restrict__ ebuf) {
    __shared__ int cur[B];
    int g = blockIdx.x;
    for (int i = threadIdx.x; i < B; i += 1024) cur[i] = offs[i * G + g];
    __syncthreads();
    const int* sp = src + g * CHUNK;
    const int* dp = dst + g * CHUNK;
    for (int k = threadIdx.x; k < CHUNK; k += 1024) {
        int d = dp[k], s = sp[k];
        int pos = atomicAdd(&cur[d >> BSHIFT], 1);
        ebuf[pos] = ((unsigned)(d & BMASK) << 17) | (unsigned)s;   // src < 2^17
    }
}

// ---------------- norm_s + x*norm_s -> bf16 gather source (fused) ----------------

__global__ __launch_bounds__(256) void conv_kernel(const float* __restrict__ x,
                                                   const int* __restrict__ degP,
                                                   float* __restrict__ norm_s,
                                                   unsigned* __restrict__ hb) {
    int t = blockIdx.x * 256 + threadIdx.x;     // one u32 pair per thread
    if (t >= NN * 64) return;
    int row = t >> 6;
    int dsum = 0;
    #pragma unroll
    for (int p = 0; p < NXCD; ++p) dsum += degP[(size_t)p * NN + row];
    float ns = rsqrtf((float)(dsum + 1));       // +1 = self-loop
    if ((t & 63) == 0) norm_s[row] = ns;
    float2 v = ((const float2*)x)[t];
    hb[t] = f2bf(v.x * ns) | (f2bf(v.y * ns) << 16);
}

// ---------------- per-bucket local sort: bucket order -> per-node CSR ----------

__global__ __launch_bounds__(256) void local_sort(
    const int* __restrict__ offs, unsigned* __restrict__ ebuf,
    int* __restrict__ row, float* __restrict__ norm_d)
{
    __shared__ int cnt[128];
    __shared__ int sc[128];
    const int b = blockIdx.x;
    const int t = threadIdx.x;
    const int s = offs[b * G];
    const int e = (b == B - 1) ? NE : offs[(b + 1) * G];
    if (t < 128) cnt[t] = 0;
    __syncthreads();

    unsigned ent[16];   // 16*256 = 4096 capacity; bucket mean 2048, sd ~45
    int nent = 0;
    for (int k = s + t; k < e && nent < 16; k += 256) {
        unsigned u = ebuf[k];
        ent[nent++] = u;
        atomicAdd(&cnt[u >> 17], 1);
    }
    __syncthreads();

    if (t < 128) sc[t] = cnt[t];
    __syncthreads();
    for (int off = 1; off < 128; off <<= 1) {
        int v = 0;
        if (t < 128 && t >= off) v = sc[t - off];
        __syncthreads();
        if (t < 128) sc[t] += v;
        __syncthreads();
    }
    if (t < 128) {
        int st = s + sc[t] - cnt[t];   // exclusive start
        int node = b * 128 + t;
        if (node < NN) {
            row[node] = st;
            norm_d[node] = rsqrtf((float)(cnt[t] + 1));
        }
        cnt[t] = st;                   // becomes cursor
    }
    if (b == B - 1 && t == 0) row[NN] = NE;
    __syncthreads();

    for (int i = 0; i < nent; ++i) {
        unsigned u = ent[i];
        int pos = atomicAdd(&cnt[u >> 17], 1);
        ebuf[pos] = u & 0x1FFFFu;      // strip bucket bits -> plain src id
    }
}

// ---------------- FUSED gather-aggregate + MFMA GEMM ---------------------------
// Round-1 evidence: csr_agg wrote 50 MB of Ahi/Alo staging per layer that
// gemm_kernel read straight back (~100 MB round trip/layer). Fused: each block
// owns one 64-row tile; its 4 waves aggregate 16 rows each (8-deep gather
// pipeline, proven best round 6) and split bf16 hi/lo DIRECTLY into the LDS
// tile the MFMA phase consumes. Saves ~200 MB HBM traffic + 2 launches.

template<bool LAYER0>
__global__ __launch_bounds__(256) void fused_kernel(
    const int* __restrict__ rowp, const int* __restrict__ csr,
    const unsigned* __restrict__ hp,
    const float* __restrict__ W, const float* __restrict__ bias,
    const float* __restrict__ norm_s, const float* __restrict__ norm_d,
    const float* __restrict__ gamma, const float* __restrict__ beta,
    const float* __restrict__ rmean, const float* __restrict__ rvar,
    float* __restrict__ outf, unsigned short* __restrict__ outb)
{
    __shared__ unsigned lhi[64 * 68];   // 64 rows x 136 bf16 (pad 8)
    __shared__ unsigned llo[64 * 68];

    const int w    = threadIdx.x >> 6;
    const int lane = threadIdx.x & 63;
    const int quad = lane >> 4;
    const int l16  = lane & 15;
    const int row0 = blockIdx.x * 64;

    // ---- B fragments (hi/lo) for this wave's 2 col-tiles, all K ----
    v8s Bhi[2][4], Blo[2][4];
    int col[2];
    #pragma unroll
    for (int ct = 0; ct < 2; ++ct) {
        col[ct] = 32 * w + 16 * ct + l16;
        #pragma unroll
        for (int q = 0; q < 4; ++q) {
            int kb = 32 * q + quad * 8;
            v8s hi8, lo8;
            #pragma unroll
            for (int kk = 0; kk < 8; ++kk) {
                float wv = W[(kb + kk) * D + col[ct]];
                unsigned h = f2bf(wv);
                hi8[kk] = (short)h;
                lo8[kk] = (short)f2bf(wv - bf2f(h));
            }
            Bhi[ct][q] = hi8;
            Blo[ct][q] = lo8;
        }
    }

    float bcol[2], s[2] = {0.f, 0.f}, sh[2] = {0.f, 0.f};
    #pragma unroll
    for (int ct = 0; ct < 2; ++ct) {
        bcol[ct] = bias[col[ct]];
        if (LAYER0) {
            s[ct]  = gamma[col[ct]] * rsqrtf(rvar[col[ct]] + BNEPS);
            sh[ct] = beta[col[ct]] - rmean[col[ct]] * s[ct];
        }
    }

    // ---- gather phase: wave w aggregates LDS rows [w*16, w*16+16) ----
    for (int k16 = 0; k16 < 16; ++k16) {
        const int r = w * 16 + k16;
        const int i = row0 + r;
        float2 acc = {0.f, 0.f};
        if (i < NN) {
            unsigned u = hp[(size_t)i * 64 + lane];   // self-loop row
            acc.x = __uint_as_float(u << 16);
            acc.y = __uint_as_float(u & 0xffff0000u);
            int start = rowp[i], end = rowp[i + 1];
            for (int base = start; base < end; base += 64) {
                int n = end - base; if (n > 64) n = 64;
                int sv = csr[base + (lane < n ? lane : n - 1)];
                int j = 0;
                for (; j + 8 <= n; j += 8) {
                    int ss[8]; unsigned uu[8];
                    #pragma unroll
                    for (int t = 0; t < 8; ++t) ss[t] = __shfl(sv, j + t);
                    #pragma unroll
                    for (int t = 0; t < 8; ++t) uu[t] = hp[(size_t)ss[t] * 64 + lane];
                    #pragma unroll
                    for (int t = 0; t < 8; ++t) {
                        acc.x += __uint_as_float(uu[t] << 16);
                        acc.y += __uint_as_float(uu[t] & 0xffff0000u);
                    }
                }
                for (; j < n; ++j) {
                    int sidx = __shfl(sv, j);
                    unsigned u2 = hp[(size_t)sidx * 64 + lane];
                    acc.x += __uint_as_float(u2 << 16);
                    acc.y += __uint_as_float(u2 & 0xffff0000u);
                }
            }
        }
        unsigned hx = f2bf(acc.x), hy = f2bf(acc.y);
        float lx = acc.x - bf2f(hx), ly = acc.y - bf2f(hy);
        lhi[r * 68 + lane] = hx | (hy << 16);
        llo[r * 68 + lane] = f2bf(lx) | (f2bf(ly) << 16);
    }
    __syncthreads();

    // ---- MFMA phase: one 64x128 tile, split-precision bf16 (3 mfma) ----
    #pragma unroll
    for (int rt = 0; rt < 4; ++rt) {
        v4f acc0 = {0.f, 0.f, 0.f, 0.f};
        v4f acc1 = {0.f, 0.f, 0.f, 0.f};
        #pragma unroll
        for (int q = 0; q < 4; ++q) {
            const unsigned short* ph = (const unsigned short*)lhi
                + (rt * 16 + l16) * 136 + q * 32 + quad * 8;
            const unsigned short* pl = (const unsigned short*)llo
                + (rt * 16 + l16) * 136 + q * 32 + quad * 8;
            v8s ahi = *(const v8s*)ph;
            v8s alo = *(const v8s*)pl;
            acc0 = __builtin_amdgcn_mfma_f32_16x16x32_bf16(ahi, Bhi[0][q], acc0, 0, 0, 0);
            acc0 = __builtin_amdgcn_mfma_f32_16x16x32_bf16(alo, Bhi[0][q], acc0, 0, 0, 0);
            acc0 = __builtin_amdgcn_mfma_f32_16x16x32_bf16(ahi, Blo[0][q], acc0, 0, 0, 0);
            acc1 = __builtin_amdgcn_mfma_f32_16x16x32_bf16(ahi, Bhi[1][q], acc1, 0, 0, 0);
            acc1 = __builtin_amdgcn_mfma_f32_16x16x32_bf16(alo, Bhi[1][q], acc1, 0, 0, 0);
            acc1 = __builtin_amdgcn_mfma_f32_16x16x32_bf16(ahi, Blo[1][q], acc1, 0, 0, 0);
        }
        #pragma unroll
        for (int r = 0; r < 4; ++r) {
            int rw = row0 + rt * 16 + quad * 4 + r;
            if (rw >= NN) continue;
            float nd = norm_d[rw];
            float o0 = acc0[r] * nd + bcol[0];
            float o1 = acc1[r] * nd + bcol[1];
            if (LAYER0) {
                o0 = o0 * s[0] + sh[0];
                o1 = o1 * s[1] + sh[1];
                o0 = o0 > 0.f ? o0 : LEAKY * o0;
                o1 = o1 > 0.f ? o1 : LEAKY * o1;
                float ns = norm_s[rw];
                o0 *= ns; o1 *= ns;
                outb[(size_t)rw * D + col[0]] = (unsigned short)f2bf(o0);
                outb[(size_t)rw * D + col[1]] = (unsigned short)f2bf(o1);
            } else {
                outf[(size_t)rw * D + col[0]] = o0;
                outf[(size_t)rw * D + col[1]] = o1;
            }
        }
    }
}

// ---------------- launch ----------------

extern "C" void kernel_launch(void* const* d_in, const int* in_sizes, int n_in,
                              void* d_out, int out_size, void* d_ws, size_t ws_size,
                              hipStream_t stream) {
    const float* x     = (const float*)d_in[0];
    const int*   src   = (const int*)d_in[1];
    const int*   dst   = (const int*)d_in[2];
    const float* W1    = (const float*)d_in[3];
    const float* b1    = (const float*)d_in[4];
    const float* W2    = (const float*)d_in[5];
    const float* b2    = (const float*)d_in[6];
    const float* gamma = (const float*)d_in[7];
    const float* beta  = (const float*)d_in[8];
    const float* rmean = (const float*)d_in[9];
    const float* rvar  = (const float*)d_in[10];
    float* out = (float*)d_out;

    // bf16 gather-source scratch lives in d_out's first half (dead once the
    // layer-1 fused GEMM overwrites all of d_out with fp32 results).
    unsigned* hb = (unsigned*)d_out;                    // NN*64 u32 = 25.6 MB

    // ws layout (4B units) — hs replaces the old Ahi staging slot; layer-0
    // fused output (bf16 hs) goes here so layer-0 never writes its own gather
    // source (race-free), and layer-1 gathers from it.
    unsigned* hs    = (unsigned*)d_ws;                  // NN*64 u32 (bf16 pairs)
    unsigned* spare = hs + (size_t)NN * 64;             // old Alo slot (unused)
    float*    norm  = (float*)(spare + (size_t)NN * 64);// 2N f32
    int*      deg   = (int*)(norm + 2 * NN);            // N int (unused)
    int*      hist  = deg + NN;                         // B*G int; row[] aliases after scanC
    int*      offs  = hist + B * G;                     // B*G int
    int*      bsum  = offs + B * G;                     // B int
    int*      boffs = bsum + B;                         // B int
    unsigned* ebuf  = (unsigned*)(boffs + B);           // NE u32
    float* norm_s = norm;
    float* norm_d = norm + NN;
    int*   row    = hist;                // aliases hist (dead after scanC)

    // per-XCD out-degree partials alias hs (dead until layer-0 fused kernel,
    // which runs after conv_kernel has consumed the reduction)
    int* degP = (int*)hs;                               // 8 * NN int = 3.2 MB

    hipMemsetAsync(degP, 0, (size_t)NXCD * NN * sizeof(int), stream);

    // counting sort by dst bucket (+ fused out-degree), local sort -> CSR
    hist_kernel<<<G, 1024, 0, stream>>>(src, dst, degP, hist);
    scanA<<<B * G / 256, 256, 0, stream>>>(hist, bsum);
    scanB<<<1, 64, 0, stream>>>(bsum, boffs);
    scanC<<<B * G / 256, 256, 0, stream>>>(hist, boffs, offs);
    sort_kernel<<<G, 1024, 0, stream>>>(src, dst, offs, ebuf);
    conv_kernel<<<(NN * 64 + 255) / 256, 256, 0, stream>>>(x, degP, norm_s, hb);
    local_sort<<<B, 256, 0, stream>>>(offs, ebuf, row, norm_d);

    const int NB = (NN + 63) / 64;   // 1563 tiles
    // layer 0: gather hb -> MFMA -> BN+leaky+norm_s -> bf16 hs
    fused_kernel<true><<<NB, 256, 0, stream>>>(row, (const int*)ebuf, hb,
                                               W1, b1, norm_s, norm_d,
                                               gamma, beta, rmean, rvar,
                                               nullptr, (unsigned short*)hs);
    // layer 1: gather hs -> MFMA -> fp32 out
    fused_kernel<false><<<NB, 256, 0, stream>>>(row, (const int*)ebuf, hs,
                                                W2, b2, norm_s, norm_d,
                                                nullptr, nullptr, nullptr, nullptr,
                                                out, nullptr);
}

// Round 3
// 436.033 us; speedup vs baseline: 1.2395x; 1.2395x over previous
//
#include <hip/hip_runtime.h>

#define NN 100000
#define NE 1600000
#define D 128
#define LEAKY 0.01f
#define BNEPS 1e-5f

#define G 256        // sort groups (workgroups)
#define CHUNK 6250   // NE / G exactly
#define B 782        // ceil(NN/128) buckets (128 nodes each)
#define BSHIFT 7
#define BMASK 127

typedef short v8s __attribute__((ext_vector_type(8)));
typedef float v4f __attribute__((ext_vector_type(4)));

// round-to-nearest-even f32 -> bf16 (returns low 16 bits)
__device__ __forceinline__ unsigned f2bf(float f) {
    unsigned u = __float_as_uint(f);
    return (u + 0x7fffu + ((u >> 16) & 1u)) >> 16;
}
__device__ __forceinline__ float bf2f(unsigned h) {
    return __uint_as_float(h << 16);
}

// ---------------- counting sort by dst bucket + src bucket ---------------------
// Round-1/2 evidence: the 1.6M global deg atomics execute memory-side no matter
// the scope (56 MB WRITE both ways, 66 us). Eliminated structurally: histogram
// BOTH dst and src buckets in LDS here (no global atomics), scatter src into a
// bucket-grouped sbuf in sort_kernel, per-bucket LDS count -> deg (deg_count).

__global__ __launch_bounds__(1024) void hist_kernel(const int* __restrict__ src,
                                                    const int* __restrict__ dst,
                                                    int* __restrict__ hist,
                                                    int* __restrict__ hist2) {
    __shared__ int h[B];
    __shared__ int h2[B];
    for (int i = threadIdx.x; i < B; i += 1024) { h[i] = 0; h2[i] = 0; }
    __syncthreads();
    int g = blockIdx.x;
    const int* dp = dst + g * CHUNK;
    const int* sp = src + g * CHUNK;
    for (int k = threadIdx.x; k < CHUNK; k += 1024) {
        atomicAdd(&h[dp[k] >> BSHIFT], 1);
        atomicAdd(&h2[sp[k] >> BSHIFT], 1);
    }
    __syncthreads();
    for (int i = threadIdx.x; i < B; i += 1024) {
        hist[i * G + g]  = h[i];
        hist2[i * G + g] = h2[i];
    }
}

__global__ void scanA(const int* __restrict__ a, int* __restrict__ bsum) {
    __shared__ int sm[256];
    int t = threadIdx.x;
    sm[t] = a[blockIdx.x * 256 + t];
    __syncthreads();
    for (int s = 128; s > 0; s >>= 1) {
        if (t < s) sm[t] += sm[t + s];
        __syncthreads();
    }
    if (t == 0) bsum[blockIdx.x] = sm[0];
}

__global__ void scanB(const int* __restrict__ bsum, int* __restrict__ boffs) {
    int lane = threadIdx.x;
    int run = 0;
    for (int base = 0; base < B; base += 64) {
        int i = base + lane;
        int v = (i < B) ? bsum[i] : 0;
        int orig = v;
        for (int off = 1; off < 64; off <<= 1) {
            int t = __shfl_up(v, off);
            if (lane >= off) v += t;
        }
        if (i < B) boffs[i] = run + v - orig;   // exclusive
        run += __shfl(v, 63);
    }
}

__global__ void scanC(const int* __restrict__ a, const int* __restrict__ boffs,
                      int* __restrict__ offs) {
    __shared__ int sm[256];
    int t = threadIdx.x;
    int i = blockIdx.x * 256 + t;
    int v = a[i];
    sm[t] = v;
    __syncthreads();
    for (int off = 1; off < 256; off <<= 1) {
        int x = (t >= off) ? sm[t - off] : 0;
        __syncthreads();
        sm[t] += x;
        __syncthreads();
    }
    offs[i] = boffs[blockIdx.x] + sm[t] - v;    // exclusive
}

__global__ __launch_bounds__(1024) void sort_kernel(const int* __restrict__ src,
                                                    const int* __restrict__ dst,
                                                    const int* __restrict__ offs,
                                                    const int* __restrict__ offs2,
                                                    unsigned* __restrict__ ebuf,
                                                    unsigned* __restrict__ sbuf) {
    __shared__ int cur[B];
    __shared__ int cur2[B];
    int g = blockIdx.x;
    for (int i = threadIdx.x; i < B; i += 1024) {
        cur[i]  = offs[i * G + g];
        cur2[i] = offs2[i * G + g];
    }
    __syncthreads();
    const int* sp = src + g * CHUNK;
    const int* dp = dst + g * CHUNK;
    for (int k = threadIdx.x; k < CHUNK; k += 1024) {
        int d = dp[k], s = sp[k];
        int pos = atomicAdd(&cur[d >> BSHIFT], 1);
        ebuf[pos] = ((unsigned)(d & BMASK) << 17) | (unsigned)s;   // src < 2^17
        int pos2 = atomicAdd(&cur2[s >> BSHIFT], 1);
        sbuf[pos2] = (unsigned)s;
    }
}

// per-bucket out-degree count (mirror of local_sort's in-degree count)
__global__ __launch_bounds__(256) void deg_count(const int* __restrict__ offs2,
                                                 const unsigned* __restrict__ sbuf,
                                                 int* __restrict__ deg) {
    __shared__ int cnt[128];
    const int b = blockIdx.x;
    const int t = threadIdx.x;
    const int s = offs2[b * G];
    const int e = (b == B - 1) ? NE : offs2[(b + 1) * G];
    if (t < 128) cnt[t] = 0;
    __syncthreads();
    for (int k = s + t; k < e; k += 256)
        atomicAdd(&cnt[sbuf[k] & BMASK], 1);
    __syncthreads();
    if (t < 128) {
        int node = b * 128 + t;
        if (node < NN) deg[node] = cnt[t];
    }
}

// ---------------- norm_s + x*norm_s -> bf16 gather source (fused) ----------------

__global__ __launch_bounds__(256) void conv_kernel(const float* __restrict__ x,
                                                   const int* __restrict__ deg,
                                                   float* __restrict__ norm_s,
                                                   unsigned* __restrict__ hb) {
    int t = blockIdx.x * 256 + threadIdx.x;     // one u32 pair per thread
    if (t >= NN * 64) return;
    int row = t >> 6;
    float ns = rsqrtf((float)(deg[row] + 1));   // +1 = self-loop
    if ((t & 63) == 0) norm_s[row] = ns;
    float2 v = ((const float2*)x)[t];
    hb[t] = f2bf(v.x * ns) | (f2bf(v.y * ns) << 16);
}

// ---------------- per-bucket local sort: bucket order -> per-node CSR ----------

__global__ __launch_bounds__(256) void local_sort(
    const int* __restrict__ offs, unsigned* __restrict__ ebuf,
    int* __restrict__ row, float* __restrict__ norm_d)
{
    __shared__ int cnt[128];
    __shared__ int sc[128];
    const int b = blockIdx.x;
    const int t = threadIdx.x;
    const int s = offs[b * G];
    const int e = (b == B - 1) ? NE : offs[(b + 1) * G];
    if (t < 128) cnt[t] = 0;
    __syncthreads();

    unsigned ent[16];   // 16*256 = 4096 capacity; bucket mean 2048, sd ~45
    int nent = 0;
    for (int k = s + t; k < e && nent < 16; k += 256) {
        unsigned u = ebuf[k];
        ent[nent++] = u;
        atomicAdd(&cnt[u >> 17], 1);
    }
    __syncthreads();

    if (t < 128) sc[t] = cnt[t];
    __syncthreads();
    for (int off = 1; off < 128; off <<= 1) {
        int v = 0;
        if (t < 128 && t >= off) v = sc[t - off];
        __syncthreads();
        if (t < 128) sc[t] += v;
        __syncthreads();
    }
    if (t < 128) {
        int st = s + sc[t] - cnt[t];   // exclusive start
        int node = b * 128 + t;
        if (node < NN) {
            row[node] = st;
            norm_d[node] = rsqrtf((float)(cnt[t] + 1));
        }
        cnt[t] = st;                   // becomes cursor
    }
    if (b == B - 1 && t == 0) row[NN] = NE;
    __syncthreads();

    for (int i = 0; i < nent; ++i) {
        unsigned u = ent[i];
        int pos = atomicAdd(&cnt[u >> 17], 1);
        ebuf[pos] = u & 0x1FFFFu;      // strip bucket bits -> plain src id
    }
}

// ---------------- CSR gather-aggregate over bf16 rows, fp32 accumulate --------
// Round-2 change: uint2 gathers (8 B/lane). Half-wave 0 takes even edges,
// half-wave 1 odd edges; each lane covers u32 cols [2c,2c+1]. Doubles in-flight
// bytes/wave (2 KB -> 4 KB) and halves instructions/byte for this latency-bound
// gather. Cross-half combine: 4 shfl_xor(32); lanes<32 store Ahi, >=32 Alo.

__global__ __launch_bounds__(256) void csr_agg(
    const int* __restrict__ rowp, const int* __restrict__ csr,
    const unsigned* __restrict__ hp,
    unsigned* __restrict__ Ahi, unsigned* __restrict__ Alo)
{
    int i = blockIdx.x * 4 + (threadIdx.x >> 6);
    if (i >= NN) return;
    const int lane = threadIdx.x & 63;
    const int half = lane >> 5;     // 0: even edges, 1: odd edges
    const int c2   = lane & 31;     // u32 column pair [2c2, 2c2+1]

    float4 acc = {0.f, 0.f, 0.f, 0.f};
    if (half == 0) {                // self-loop row counted once
        uint2 u = *(const uint2*)(hp + (size_t)i * 64 + 2 * c2);
        acc.x = __uint_as_float(u.x << 16);
        acc.y = __uint_as_float(u.x & 0xffff0000u);
        acc.z = __uint_as_float(u.y << 16);
        acc.w = __uint_as_float(u.y & 0xffff0000u);
    }

    int start = rowp[i], end = rowp[i + 1];
    for (int base = start; base < end; base += 64) {
        int n = end - base; if (n > 64) n = 64;
        int sv = csr[base + (lane < n ? lane : n - 1)];
        int j = 0;
        for (; j + 16 <= n; j += 16) {
            int ss[8]; uint2 uu[8];
            #pragma unroll
            for (int t = 0; t < 8; ++t) ss[t] = __shfl(sv, j + 2 * t + half);
            #pragma unroll
            for (int t = 0; t < 8; ++t)
                uu[t] = *(const uint2*)(hp + (size_t)ss[t] * 64 + 2 * c2);
            #pragma unroll
            for (int t = 0; t < 8; ++t) {
                acc.x += __uint_as_float(uu[t].x << 16);
                acc.y += __uint_as_float(uu[t].x & 0xffff0000u);
                acc.z += __uint_as_float(uu[t].y << 16);
                acc.w += __uint_as_float(uu[t].y & 0xffff0000u);
            }
        }
        for (; j < n; j += 2) {
            int e = j + half;
            int sidx = __shfl(sv, e < n ? e : n - 1);   // all lanes active
            if (e < n) {
                uint2 u2 = *(const uint2*)(hp + (size_t)sidx * 64 + 2 * c2);
                acc.x += __uint_as_float(u2.x << 16);
                acc.y += __uint_as_float(u2.x & 0xffff0000u);
                acc.z += __uint_as_float(u2.y << 16);
                acc.w += __uint_as_float(u2.y & 0xffff0000u);
            }
        }
    }

    // combine halves: both sides end with the full sum
    acc.x += __shfl_xor(acc.x, 32);
    acc.y += __shfl_xor(acc.y, 32);
    acc.z += __shfl_xor(acc.z, 32);
    acc.w += __shfl_xor(acc.w, 32);

    unsigned h0 = f2bf(acc.x), h1 = f2bf(acc.y);
    unsigned h2 = f2bf(acc.z), h3 = f2bf(acc.w);
    if (half == 0) {
        uint2 w = { h0 | (h1 << 16), h2 | (h3 << 16) };
        *(uint2*)(Ahi + (size_t)i * 64 + 2 * c2) = w;
    } else {
        float l0 = acc.x - bf2f(h0), l1 = acc.y - bf2f(h1);
        float l2 = acc.z - bf2f(h2), l3 = acc.w - bf2f(h3);
        uint2 w = { f2bf(l0) | (f2bf(l1) << 16), f2bf(l2) | (f2bf(l3) << 16) };
        *(uint2*)(Alo + (size_t)i * 64 + 2 * c2) = w;
    }
}

// ---------------- MFMA GEMM, split-precision bf16 (3-mfma ~ fp32 accuracy) -----

template<bool LAYER0>
__global__ __launch_bounds__(256) void gemm_kernel(
    const unsigned* __restrict__ Ahi_g, const unsigned* __restrict__ Alo_g,
    const float* __restrict__ W, const float* __restrict__ bias,
    const float* __restrict__ norm_s, const float* __restrict__ norm_d,
    const float* __restrict__ gamma, const float* __restrict__ beta,
    const float* __restrict__ rmean, const float* __restrict__ rvar,
    float* __restrict__ outf, unsigned short* __restrict__ outb)
{
    __shared__ unsigned lhi[64 * 68];   // 64 rows x 136 bf16 (pad 8)
    __shared__ unsigned llo[64 * 68];

    const int w    = threadIdx.x >> 6;
    const int lane = threadIdx.x & 63;
    const int quad = lane >> 4;
    const int l16  = lane & 15;

    // ---- B fragments (hi/lo) for this wave's 2 col-tiles, all K ----
    v8s Bhi[2][4], Blo[2][4];
    int col[2];
    #pragma unroll
    for (int ct = 0; ct < 2; ++ct) {
        col[ct] = 32 * w + 16 * ct + l16;
        #pragma unroll
        for (int q = 0; q < 4; ++q) {
            int kb = 32 * q + quad * 8;
            v8s hi8, lo8;
            #pragma unroll
            for (int kk = 0; kk < 8; ++kk) {
                float wv = W[(kb + kk) * D + col[ct]];
                unsigned h = f2bf(wv);
                hi8[kk] = (short)h;
                lo8[kk] = (short)f2bf(wv - bf2f(h));
            }
            Bhi[ct][q] = hi8;
            Blo[ct][q] = lo8;
        }
    }

    float bcol[2], s[2] = {0.f, 0.f}, sh[2] = {0.f, 0.f};
    #pragma unroll
    for (int ct = 0; ct < 2; ++ct) {
        bcol[ct] = bias[col[ct]];
        if (LAYER0) {
            s[ct]  = gamma[col[ct]] * rsqrtf(rvar[col[ct]] + BNEPS);
            sh[ct] = beta[col[ct]] - rmean[col[ct]] * s[ct];
        }
    }

    for (int row0 = blockIdx.x * 64; row0 < NN; row0 += gridDim.x * 64) {
        __syncthreads();
        for (int idx = threadIdx.x; idx < 64 * 64; idx += 256) {
            int r = idx >> 6, cp = idx & 63;
            int rw = row0 + r;
            unsigned vh = 0, vl = 0;
            if (rw < NN) {
                vh = Ahi_g[(size_t)rw * 64 + cp];
                vl = Alo_g[(size_t)rw * 64 + cp];
            }
            lhi[r * 68 + cp] = vh;
            llo[r * 68 + cp] = vl;
        }
        __syncthreads();

        #pragma unroll
        for (int rt = 0; rt < 4; ++rt) {
            v4f acc0 = {0.f, 0.f, 0.f, 0.f};
            v4f acc1 = {0.f, 0.f, 0.f, 0.f};
            #pragma unroll
            for (int q = 0; q < 4; ++q) {
                const unsigned short* ph = (const unsigned short*)lhi
                    + (rt * 16 + l16) * 136 + q * 32 + quad * 8;
                const unsigned short* pl = (const unsigned short*)llo
                    + (rt * 16 + l16) * 136 + q * 32 + quad * 8;
                v8s ahi = *(const v8s*)ph;
                v8s alo = *(const v8s*)pl;
                acc0 = __builtin_amdgcn_mfma_f32_16x16x32_bf16(ahi, Bhi[0][q], acc0, 0, 0, 0);
                acc0 = __builtin_amdgcn_mfma_f32_16x16x32_bf16(alo, Bhi[0][q], acc0, 0, 0, 0);
                acc0 = __builtin_amdgcn_mfma_f32_16x16x32_bf16(ahi, Blo[0][q], acc0, 0, 0, 0);
                acc1 = __builtin_amdgcn_mfma_f32_16x16x32_bf16(ahi, Bhi[1][q], acc1, 0, 0, 0);
                acc1 = __builtin_amdgcn_mfma_f32_16x16x32_bf16(alo, Bhi[1][q], acc1, 0, 0, 0);
                acc1 = __builtin_amdgcn_mfma_f32_16x16x32_bf16(ahi, Blo[1][q], acc1, 0, 0, 0);
            }
            #pragma unroll
            for (int r = 0; r < 4; ++r) {
                int rw = row0 + rt * 16 + quad * 4 + r;
                if (rw >= NN) continue;
                float nd = norm_d[rw];
                float o0 = acc0[r] * nd + bcol[0];
                float o1 = acc1[r] * nd + bcol[1];
                if (LAYER0) {
                    o0 = o0 * s[0] + sh[0];
                    o1 = o1 * s[1] + sh[1];
                    o0 = o0 > 0.f ? o0 : LEAKY * o0;
                    o1 = o1 > 0.f ? o1 : LEAKY * o1;
                    float ns = norm_s[rw];
                    o0 *= ns; o1 *= ns;
                    outb[(size_t)rw * D + col[0]] = (unsigned short)f2bf(o0);
                    outb[(size_t)rw * D + col[1]] = (unsigned short)f2bf(o1);
                } else {
                    outf[(size_t)rw * D + col[0]] = o0;
                    outf[(size_t)rw * D + col[1]] = o1;
                }
            }
        }
    }
}

// ---------------- launch ----------------

extern "C" void kernel_launch(void* const* d_in, const int* in_sizes, int n_in,
                              void* d_out, int out_size, void* d_ws, size_t ws_size,
                              hipStream_t stream) {
    const float* x     = (const float*)d_in[0];
    const int*   src   = (const int*)d_in[1];
    const int*   dst   = (const int*)d_in[2];
    const float* W1    = (const float*)d_in[3];
    const float* b1    = (const float*)d_in[4];
    const float* W2    = (const float*)d_in[5];
    const float* b2    = (const float*)d_in[6];
    const float* gamma = (const float*)d_in[7];
    const float* beta  = (const float*)d_in[8];
    const float* rmean = (const float*)d_in[9];
    const float* rvar  = (const float*)d_in[10];
    float* out = (float*)d_out;

    // bf16 gather-source scratch lives in d_out's first half (dead once the
    // final GEMM overwrites all of d_out with fp32 results).
    unsigned* hb = (unsigned*)d_out;                    // NN*64 u32 = 25.6 MB

    // ws layout (4B units)
    unsigned* Ahi   = (unsigned*)d_ws;                  // NN*64 u32 (bf16 hi pairs)
    unsigned* Alo   = Ahi + (size_t)NN * 64;            // NN*64 u32 (bf16 lo pairs)
    float*    norm  = (float*)(Alo + (size_t)NN * 64);  // 2N f32
    int*      deg   = (int*)(norm + 2 * NN);            // N int (out-degree)
    int*      hist  = deg + NN;                         // B*G int; row[] aliases after scanC
    int*      offs  = hist + B * G;                     // B*G int
    int*      bsum  = offs + B * G;                     // B int
    int*      boffs = bsum + B;                         // B int
    unsigned* ebuf  = (unsigned*)(boffs + B);           // NE u32
    float* norm_s = norm;
    float* norm_d = norm + NN;
    int*   row    = hist;                // aliases hist (dead after scanC)

    // src-side scratch aliases the Ahi slot (dead until csr_agg writes it):
    int*      hist2 = (int*)Ahi;                        // B*G int
    int*      offs2 = hist2 + B * G;                    // B*G int
    unsigned* sbuf  = (unsigned*)(offs2 + B * G);       // NE u32  (total 8 MB < 25.6 MB)

    // counting sort by dst bucket + src-bucket scatter (no global atomics)
    hist_kernel<<<G, 1024, 0, stream>>>(src, dst, hist, hist2);
    scanA<<<B * G / 256, 256, 0, stream>>>(hist, bsum);
    scanB<<<1, 64, 0, stream>>>(bsum, boffs);
    scanC<<<B * G / 256, 256, 0, stream>>>(hist, boffs, offs);
    scanA<<<B * G / 256, 256, 0, stream>>>(hist2, bsum);
    scanB<<<1, 64, 0, stream>>>(bsum, boffs);
    scanC<<<B * G / 256, 256, 0, stream>>>(hist2, boffs, offs2);
    sort_kernel<<<G, 1024, 0, stream>>>(src, dst, offs, offs2, ebuf, sbuf);
    deg_count<<<B, 256, 0, stream>>>(offs2, sbuf, deg);
    conv_kernel<<<(NN * 64 + 255) / 256, 256, 0, stream>>>(x, deg, norm_s, hb);
    local_sort<<<B, 256, 0, stream>>>(offs, ebuf, row, norm_d);

    const int AGG_BLOCKS = (NN + 3) / 4;
    const int GEMM_BLOCKS = 784;
    // layer 0: agg = selfloop + sum_e xs[src]  -> split bf16 hi/lo
    csr_agg<<<AGG_BLOCKS, 256, 0, stream>>>(row, (const int*)ebuf, hb, Ahi, Alo);
    gemm_kernel<true><<<GEMM_BLOCKS, 256, 0, stream>>>(Ahi, Alo, W1, b1,
                                                       norm_s, norm_d,
                                                       gamma, beta, rmean, rvar,
                                                       nullptr, (unsigned short*)hb);
    // layer 1: gather source = bf16 hs (norm_src folded)
    csr_agg<<<AGG_BLOCKS, 256, 0, stream>>>(row, (const int*)ebuf, hb, Ahi, Alo);
    gemm_kernel<false><<<GEMM_BLOCKS, 256, 0, stream>>>(Ahi, Alo, W2, b2,
                                                        norm_s, norm_d,
                                                        nullptr, nullptr, nullptr, nullptr,
                                                        out, nullptr);
}

// Round 4
// 429.067 us; speedup vs baseline: 1.2596x; 1.0162x over previous
//
#include <hip/hip_runtime.h>

#define NN 100000
#define NE 1600000
#define D 128
#define LEAKY 0.01f
#define BNEPS 1e-5f

#define G 256        // sort groups (workgroups)
#define CHUNK 6250   // NE / G exactly
#define B 782        // ceil(NN/128) buckets (128 nodes each)
#define BSHIFT 7
#define BMASK 127

typedef short v8s __attribute__((ext_vector_type(8)));
typedef float v4f __attribute__((ext_vector_type(4)));

// round-to-nearest-even f32 -> bf16 (returns low 16 bits)
__device__ __forceinline__ unsigned f2bf(float f) {
    unsigned u = __float_as_uint(f);
    return (u + 0x7fffu + ((u >> 16) & 1u)) >> 16;
}
__device__ __forceinline__ float bf2f(unsigned h) {
    return __uint_as_float(h << 16);
}

// ---------------- counting sort by dst bucket + src bucket ---------------------
// Round-3 evidence: LDS-only histograms (no global deg atomics) removed the
// 56 MB memory-side atomic traffic; hist dropped out of top-5. Kept.

__global__ __launch_bounds__(1024) void hist_kernel(const int* __restrict__ src,
                                                    const int* __restrict__ dst,
                                                    int* __restrict__ hist,
                                                    int* __restrict__ hist2) {
    __shared__ int h[B];
    __shared__ int h2[B];
    for (int i = threadIdx.x; i < B; i += 1024) { h[i] = 0; h2[i] = 0; }
    __syncthreads();
    int g = blockIdx.x;
    const int* dp = dst + g * CHUNK;
    const int* sp = src + g * CHUNK;
    for (int k = threadIdx.x; k < CHUNK; k += 1024) {
        atomicAdd(&h[dp[k] >> BSHIFT], 1);
        atomicAdd(&h2[sp[k] >> BSHIFT], 1);
    }
    __syncthreads();
    for (int i = threadIdx.x; i < B; i += 1024) {
        hist[i * G + g]  = h[i];
        hist2[i * G + g] = h2[i];
    }
}

__global__ void scanA(const int* __restrict__ a, int* __restrict__ bsum) {
    __shared__ int sm[256];
    int t = threadIdx.x;
    sm[t] = a[blockIdx.x * 256 + t];
    __syncthreads();
    for (int s = 128; s > 0; s >>= 1) {
        if (t < s) sm[t] += sm[t + s];
        __syncthreads();
    }
    if (t == 0) bsum[blockIdx.x] = sm[0];
}

__global__ void scanB(const int* __restrict__ bsum, int* __restrict__ boffs) {
    int lane = threadIdx.x;
    int run = 0;
    for (int base = 0; base < B; base += 64) {
        int i = base + lane;
        int v = (i < B) ? bsum[i] : 0;
        int orig = v;
        for (int off = 1; off < 64; off <<= 1) {
            int t = __shfl_up(v, off);
            if (lane >= off) v += t;
        }
        if (i < B) boffs[i] = run + v - orig;   // exclusive
        run += __shfl(v, 63);
    }
}

__global__ void scanC(const int* __restrict__ a, const int* __restrict__ boffs,
                      int* __restrict__ offs) {
    __shared__ int sm[256];
    int t = threadIdx.x;
    int i = blockIdx.x * 256 + t;
    int v = a[i];
    sm[t] = v;
    __syncthreads();
    for (int off = 1; off < 256; off <<= 1) {
        int x = (t >= off) ? sm[t - off] : 0;
        __syncthreads();
        sm[t] += x;
        __syncthreads();
    }
    offs[i] = boffs[blockIdx.x] + sm[t] - v;    // exclusive
}

__global__ __launch_bounds__(1024) void sort_kernel(const int* __restrict__ src,
                                                    const int* __restrict__ dst,
                                                    const int* __restrict__ offs,
                                                    const int* __restrict__ offs2,
                                                    unsigned* __restrict__ ebuf,
                                                    unsigned* __restrict__ sbuf) {
    __shared__ int cur[B];
    __shared__ int cur2[B];
    int g = blockIdx.x;
    for (int i = threadIdx.x; i < B; i += 1024) {
        cur[i]  = offs[i * G + g];
        cur2[i] = offs2[i * G + g];
    }
    __syncthreads();
    const int* sp = src + g * CHUNK;
    const int* dp = dst + g * CHUNK;
    for (int k = threadIdx.x; k < CHUNK; k += 1024) {
        int d = dp[k], s = sp[k];
        int pos = atomicAdd(&cur[d >> BSHIFT], 1);
        ebuf[pos] = ((unsigned)(d & BMASK) << 17) | (unsigned)s;   // src < 2^17
        int pos2 = atomicAdd(&cur2[s >> BSHIFT], 1);
        sbuf[pos2] = (unsigned)s;
    }
}

// per-bucket out-degree count (mirror of local_sort's in-degree count)
__global__ __launch_bounds__(256) void deg_count(const int* __restrict__ offs2,
                                                 const unsigned* __restrict__ sbuf,
                                                 int* __restrict__ deg) {
    __shared__ int cnt[128];
    const int b = blockIdx.x;
    const int t = threadIdx.x;
    const int s = offs2[b * G];
    const int e = (b == B - 1) ? NE : offs2[(b + 1) * G];
    if (t < 128) cnt[t] = 0;
    __syncthreads();
    for (int k = s + t; k < e; k += 256)
        atomicAdd(&cnt[sbuf[k] & BMASK], 1);
    __syncthreads();
    if (t < 128) {
        int node = b * 128 + t;
        if (node < NN) deg[node] = cnt[t];
    }
}

// ---------------- norm_s + x*norm_s -> bf16 gather source (fused) ----------------

__global__ __launch_bounds__(256) void conv_kernel(const float* __restrict__ x,
                                                   const int* __restrict__ deg,
                                                   float* __restrict__ norm_s,
                                                   unsigned* __restrict__ hb) {
    int t = blockIdx.x * 256 + threadIdx.x;     // one u32 pair per thread
    if (t >= NN * 64) return;
    int row = t >> 6;
    float ns = rsqrtf((float)(deg[row] + 1));   // +1 = self-loop
    if ((t & 63) == 0) norm_s[row] = ns;
    float2 v = ((const float2*)x)[t];
    hb[t] = f2bf(v.x * ns) | (f2bf(v.y * ns) << 16);
}

// ---------------- per-bucket local sort: bucket order -> per-node CSR ----------

__global__ __launch_bounds__(256) void local_sort(
    const int* __restrict__ offs, unsigned* __restrict__ ebuf,
    int* __restrict__ row, float* __restrict__ norm_d)
{
    __shared__ int cnt[128];
    __shared__ int sc[128];
    const int b = blockIdx.x;
    const int t = threadIdx.x;
    const int s = offs[b * G];
    const int e = (b == B - 1) ? NE : offs[(b + 1) * G];
    if (t < 128) cnt[t] = 0;
    __syncthreads();

    unsigned ent[16];   // 16*256 = 4096 capacity; bucket mean 2048, sd ~45
    int nent = 0;
    for (int k = s + t; k < e && nent < 16; k += 256) {
        unsigned u = ebuf[k];
        ent[nent++] = u;
        atomicAdd(&cnt[u >> 17], 1);
    }
    __syncthreads();

    if (t < 128) sc[t] = cnt[t];
    __syncthreads();
    for (int off = 1; off < 128; off <<= 1) {
        int v = 0;
        if (t < 128 && t >= off) v = sc[t - off];
        __syncthreads();
        if (t < 128) sc[t] += v;
        __syncthreads();
    }
    if (t < 128) {
        int st = s + sc[t] - cnt[t];   // exclusive start
        int node = b * 128 + t;
        if (node < NN) {
            row[node] = st;
            norm_d[node] = rsqrtf((float)(cnt[t] + 1));
        }
        cnt[t] = st;                   // becomes cursor
    }
    if (b == B - 1 && t == 0) row[NN] = NE;
    __syncthreads();

    for (int i = 0; i < nent; ++i) {
        unsigned u = ent[i];
        int pos = atomicAdd(&cnt[u >> 17], 1);
        ebuf[pos] = u & 0x1FFFFu;      // strip bucket bits -> plain src id
    }
}

// ---------------- CSR gather-aggregate over bf16 rows, fp32 accumulate --------
// Round-4 change: NO serialized tail. Degrees are Poisson(16) so the old
// "pipelined main + 2-at-a-time remainder" put ~half the edges through a
// dependent load chain (~600 cyc each). Now every row is ceil(n/16) masked
// 16-edge blocks: OOB lanes clamp their shfl index to n-1 (same cache lines
// as the genuine last edge -> L1 hits, no extra memory-side traffic), all 8
// uint2 loads issue before any accumulate, adds predicated per-edge.

__global__ __launch_bounds__(256) void csr_agg(
    const int* __restrict__ rowp, const int* __restrict__ csr,
    const unsigned* __restrict__ hp,
    unsigned* __restrict__ Ahi, unsigned* __restrict__ Alo)
{
    int i = blockIdx.x * 4 + (threadIdx.x >> 6);
    if (i >= NN) return;
    const int lane = threadIdx.x & 63;
    const int half = lane >> 5;     // 0: even edges, 1: odd edges
    const int c2   = lane & 31;     // u32 column pair [2c2, 2c2+1]

    float4 acc = {0.f, 0.f, 0.f, 0.f};
    if (half == 0) {                // self-loop row counted once
        uint2 u = *(const uint2*)(hp + (size_t)i * 64 + 2 * c2);
        acc.x = __uint_as_float(u.x << 16);
        acc.y = __uint_as_float(u.x & 0xffff0000u);
        acc.z = __uint_as_float(u.y << 16);
        acc.w = __uint_as_float(u.y & 0xffff0000u);
    }

    int start = rowp[i], end = rowp[i + 1];
    for (int base = start; base < end; base += 64) {
        int n = end - base; if (n > 64) n = 64;
        int sv = csr[base + (lane < n ? lane : n - 1)];
        for (int j = 0; j < n; j += 16) {
            int ss[8]; uint2 uu[8];
            #pragma unroll
            for (int t = 0; t < 8; ++t) {
                int e = j + 2 * t + half;
                ss[t] = __shfl(sv, e < n ? e : n - 1);
            }
            #pragma unroll
            for (int t = 0; t < 8; ++t)
                uu[t] = *(const uint2*)(hp + (size_t)ss[t] * 64 + 2 * c2);
            #pragma unroll
            for (int t = 0; t < 8; ++t) {
                if (j + 2 * t + half < n) {
                    acc.x += __uint_as_float(uu[t].x << 16);
                    acc.y += __uint_as_float(uu[t].x & 0xffff0000u);
                    acc.z += __uint_as_float(uu[t].y << 16);
                    acc.w += __uint_as_float(uu[t].y & 0xffff0000u);
                }
            }
        }
    }

    // combine halves: both sides end with the full sum
    acc.x += __shfl_xor(acc.x, 32);
    acc.y += __shfl_xor(acc.y, 32);
    acc.z += __shfl_xor(acc.z, 32);
    acc.w += __shfl_xor(acc.w, 32);

    unsigned h0 = f2bf(acc.x), h1 = f2bf(acc.y);
    unsigned h2 = f2bf(acc.z), h3 = f2bf(acc.w);
    if (half == 0) {
        uint2 w = { h0 | (h1 << 16), h2 | (h3 << 16) };
        *(uint2*)(Ahi + (size_t)i * 64 + 2 * c2) = w;
    } else {
        float l0 = acc.x - bf2f(h0), l1 = acc.y - bf2f(h1);
        float l2 = acc.z - bf2f(h2), l3 = acc.w - bf2f(h3);
        uint2 w = { f2bf(l0) | (f2bf(l1) << 16), f2bf(l2) | (f2bf(l3) << 16) };
        *(uint2*)(Alo + (size_t)i * 64 + 2 * c2) = w;
    }
}

// ---------------- MFMA GEMM, split-precision bf16 (3-mfma ~ fp32 accuracy) -----

template<bool LAYER0>
__global__ __launch_bounds__(256) void gemm_kernel(
    const unsigned* __restrict__ Ahi_g, const unsigned* __restrict__ Alo_g,
    const float* __restrict__ W, const float* __restrict__ bias,
    const float* __restrict__ norm_s, const float* __restrict__ norm_d,
    const float* __restrict__ gamma, const float* __restrict__ beta,
    const float* __restrict__ rmean, const float* __restrict__ rvar,
    float* __restrict__ outf, unsigned short* __restrict__ outb)
{
    __shared__ unsigned lhi[64 * 68];   // 64 rows x 136 bf16 (pad 8)
    __shared__ unsigned llo[64 * 68];

    const int w    = threadIdx.x >> 6;
    const int lane = threadIdx.x & 63;
    const int quad = lane >> 4;
    const int l16  = lane & 15;

    // ---- B fragments (hi/lo) for this wave's 2 col-tiles, all K ----
    v8s Bhi[2][4], Blo[2][4];
    int col[2];
    #pragma unroll
    for (int ct = 0; ct < 2; ++ct) {
        col[ct] = 32 * w + 16 * ct + l16;
        #pragma unroll
        for (int q = 0; q < 4; ++q) {
            int kb = 32 * q + quad * 8;
            v8s hi8, lo8;
            #pragma unroll
            for (int kk = 0; kk < 8; ++kk) {
                float wv = W[(kb + kk) * D + col[ct]];
                unsigned h = f2bf(wv);
                hi8[kk] = (short)h;
                lo8[kk] = (short)f2bf(wv - bf2f(h));
            }
            Bhi[ct][q] = hi8;
            Blo[ct][q] = lo8;
        }
    }

    float bcol[2], s[2] = {0.f, 0.f}, sh[2] = {0.f, 0.f};
    #pragma unroll
    for (int ct = 0; ct < 2; ++ct) {
        bcol[ct] = bias[col[ct]];
        if (LAYER0) {
            s[ct]  = gamma[col[ct]] * rsqrtf(rvar[col[ct]] + BNEPS);
            sh[ct] = beta[col[ct]] - rmean[col[ct]] * s[ct];
        }
    }

    for (int row0 = blockIdx.x * 64; row0 < NN; row0 += gridDim.x * 64) {
        __syncthreads();
        for (int idx = threadIdx.x; idx < 64 * 64; idx += 256) {
            int r = idx >> 6, cp = idx & 63;
            int rw = row0 + r;
            unsigned vh = 0, vl = 0;
            if (rw < NN) {
                vh = Ahi_g[(size_t)rw * 64 + cp];
                vl = Alo_g[(size_t)rw * 64 + cp];
            }
            lhi[r * 68 + cp] = vh;
            llo[r * 68 + cp] = vl;
        }
        __syncthreads();

        #pragma unroll
        for (int rt = 0; rt < 4; ++rt) {
            v4f acc0 = {0.f, 0.f, 0.f, 0.f};
            v4f acc1 = {0.f, 0.f, 0.f, 0.f};
            #pragma unroll
            for (int q = 0; q < 4; ++q) {
                const unsigned short* ph = (const unsigned short*)lhi
                    + (rt * 16 + l16) * 136 + q * 32 + quad * 8;
                const unsigned short* pl = (const unsigned short*)llo
                    + (rt * 16 + l16) * 136 + q * 32 + quad * 8;
                v8s ahi = *(const v8s*)ph;
                v8s alo = *(const v8s*)pl;
                acc0 = __builtin_amdgcn_mfma_f32_16x16x32_bf16(ahi, Bhi[0][q], acc0, 0, 0, 0);
                acc0 = __builtin_amdgcn_mfma_f32_16x16x32_bf16(alo, Bhi[0][q], acc0, 0, 0, 0);
                acc0 = __builtin_amdgcn_mfma_f32_16x16x32_bf16(ahi, Blo[0][q], acc0, 0, 0, 0);
                acc1 = __builtin_amdgcn_mfma_f32_16x16x32_bf16(ahi, Bhi[1][q], acc1, 0, 0, 0);
                acc1 = __builtin_amdgcn_mfma_f32_16x16x32_bf16(alo, Bhi[1][q], acc1, 0, 0, 0);
                acc1 = __builtin_amdgcn_mfma_f32_16x16x32_bf16(ahi, Blo[1][q], acc1, 0, 0, 0);
            }
            #pragma unroll
            for (int r = 0; r < 4; ++r) {
                int rw = row0 + rt * 16 + quad * 4 + r;
                if (rw >= NN) continue;
                float nd = norm_d[rw];
                float o0 = acc0[r] * nd + bcol[0];
                float o1 = acc1[r] * nd + bcol[1];
                if (LAYER0) {
                    o0 = o0 * s[0] + sh[0];
                    o1 = o1 * s[1] + sh[1];
                    o0 = o0 > 0.f ? o0 : LEAKY * o0;
                    o1 = o1 > 0.f ? o1 : LEAKY * o1;
                    float ns = norm_s[rw];
                    o0 *= ns; o1 *= ns;
                    outb[(size_t)rw * D + col[0]] = (unsigned short)f2bf(o0);
                    outb[(size_t)rw * D + col[1]] = (unsigned short)f2bf(o1);
                } else {
                    outf[(size_t)rw * D + col[0]] = o0;
                    outf[(size_t)rw * D + col[1]] = o1;
                }
            }
        }
    }
}

// ---------------- launch ----------------

extern "C" void kernel_launch(void* const* d_in, const int* in_sizes, int n_in,
                              void* d_out, int out_size, void* d_ws, size_t ws_size,
                              hipStream_t stream) {
    const float* x     = (const float*)d_in[0];
    const int*   src   = (const int*)d_in[1];
    const int*   dst   = (const int*)d_in[2];
    const float* W1    = (const float*)d_in[3];
    const float* b1    = (const float*)d_in[4];
    const float* W2    = (const float*)d_in[5];
    const float* b2    = (const float*)d_in[6];
    const float* gamma = (const float*)d_in[7];
    const float* beta  = (const float*)d_in[8];
    const float* rmean = (const float*)d_in[9];
    const float* rvar  = (const float*)d_in[10];
    float* out = (float*)d_out;

    // bf16 gather-source scratch lives in d_out's first half (dead once the
    // final GEMM overwrites all of d_out with fp32 results).
    unsigned* hb = (unsigned*)d_out;                    // NN*64 u32 = 25.6 MB

    // ws layout (4B units)
    unsigned* Ahi   = (unsigned*)d_ws;                  // NN*64 u32 (bf16 hi pairs)
    unsigned* Alo   = Ahi + (size_t)NN * 64;            // NN*64 u32 (bf16 lo pairs)
    float*    norm  = (float*)(Alo + (size_t)NN * 64);  // 2N f32
    int*      deg   = (int*)(norm + 2 * NN);            // N int (out-degree)
    int*      hist  = deg + NN;                         // B*G int; row[] aliases after scanC
    int*      offs  = hist + B * G;                     // B*G int
    int*      bsum  = offs + B * G;                     // B int
    int*      boffs = bsum + B;                         // B int
    unsigned* ebuf  = (unsigned*)(boffs + B);           // NE u32
    float* norm_s = norm;
    float* norm_d = norm + NN;
    int*   row    = hist;                // aliases hist (dead after scanC)

    // src-side scratch aliases the Ahi slot (dead until csr_agg writes it):
    int*      hist2 = (int*)Ahi;                        // B*G int
    int*      offs2 = hist2 + B * G;                    // B*G int
    unsigned* sbuf  = (unsigned*)(offs2 + B * G);       // NE u32  (total 8 MB < 25.6 MB)

    // counting sort by dst bucket + src-bucket scatter (no global atomics)
    hist_kernel<<<G, 1024, 0, stream>>>(src, dst, hist, hist2);
    scanA<<<B * G / 256, 256, 0, stream>>>(hist, bsum);
    scanB<<<1, 64, 0, stream>>>(bsum, boffs);
    scanC<<<B * G / 256, 256, 0, stream>>>(hist, boffs, offs);
    scanA<<<B * G / 256, 256, 0, stream>>>(hist2, bsum);
    scanB<<<1, 64, 0, stream>>>(bsum, boffs);
    scanC<<<B * G / 256, 256, 0, stream>>>(hist2, boffs, offs2);
    sort_kernel<<<G, 1024, 0, stream>>>(src, dst, offs, offs2, ebuf, sbuf);
    deg_count<<<B, 256, 0, stream>>>(offs2, sbuf, deg);
    conv_kernel<<<(NN * 64 + 255) / 256, 256, 0, stream>>>(x, deg, norm_s, hb);
    local_sort<<<B, 256, 0, stream>>>(offs, ebuf, row, norm_d);

    const int AGG_BLOCKS = (NN + 3) / 4;
    const int GEMM_BLOCKS = 784;
    // layer 0: agg = selfloop + sum_e xs[src]  -> split bf16 hi/lo
    csr_agg<<<AGG_BLOCKS, 256, 0, stream>>>(row, (const int*)ebuf, hb, Ahi, Alo);
    gemm_kernel<true><<<GEMM_BLOCKS, 256, 0, stream>>>(Ahi, Alo, W1, b1,
                                                       norm_s, norm_d,
                                                       gamma, beta, rmean, rvar,
                                                       nullptr, (unsigned short*)hb);
    // layer 1: gather source = bf16 hs (norm_src folded)
    csr_agg<<<AGG_BLOCKS, 256, 0, stream>>>(row, (const int*)ebuf, hb, Ahi, Alo);
    gemm_kernel<false><<<GEMM_BLOCKS, 256, 0, stream>>>(Ahi, Alo, W2, b2,
                                                        norm_s, norm_d,
                                                        nullptr, nullptr, nullptr, nullptr,
                                                        out, nullptr);
}

// Round 5
// 427.239 us; speedup vs baseline: 1.2650x; 1.0043x over previous
//
#include <hip/hip_runtime.h>

#define NN 100000
#define NE 1600000
#define D 128
#define LEAKY 0.01f
#define BNEPS 1e-5f

#define G 256        // sort groups (workgroups)
#define CHUNK 6250   // NE / G exactly
#define B 782        // ceil(NN/128) buckets (128 nodes each)
#define BSHIFT 7
#define BMASK 127
#define NSB (B * G / 256)   // 782 scan blocks per histogram

typedef short v8s __attribute__((ext_vector_type(8)));
typedef float v4f __attribute__((ext_vector_type(4)));

// round-to-nearest-even f32 -> bf16 (returns low 16 bits)
__device__ __forceinline__ unsigned f2bf(float f) {
    unsigned u = __float_as_uint(f);
    return (u + 0x7fffu + ((u >> 16) & 1u)) >> 16;
}
__device__ __forceinline__ float bf2f(unsigned h) {
    return __uint_as_float(h << 16);
}

// ---------------- counting sort by dst bucket + src bucket ---------------------

__global__ __launch_bounds__(1024) void hist_kernel(const int* __restrict__ src,
                                                    const int* __restrict__ dst,
                                                    int* __restrict__ hist,
                                                    int* __restrict__ hist2) {
    __shared__ int h[B];
    __shared__ int h2[B];
    for (int i = threadIdx.x; i < B; i += 1024) { h[i] = 0; h2[i] = 0; }
    __syncthreads();
    int g = blockIdx.x;
    const int* dp = dst + g * CHUNK;
    const int* sp = src + g * CHUNK;
    for (int k = threadIdx.x; k < CHUNK; k += 1024) {
        atomicAdd(&h[dp[k] >> BSHIFT], 1);
        atomicAdd(&h2[sp[k] >> BSHIFT], 1);
    }
    __syncthreads();
    for (int i = threadIdx.x; i < B; i += 1024) {
        hist[i * G + g]  = h[i];
        hist2[i * G + g] = h2[i];
    }
}

// merged scans: one launch covers both histograms (round-5: 15 -> 11 dispatches)

__global__ void scanA2(const int* __restrict__ a, const int* __restrict__ a2,
                       int* __restrict__ bsum, int* __restrict__ bsum2) {
    __shared__ int sm[256];
    int t = threadIdx.x;
    bool second = blockIdx.x >= NSB;
    int blk = second ? blockIdx.x - NSB : blockIdx.x;
    const int* sp = second ? a2 : a;
    sm[t] = sp[blk * 256 + t];
    __syncthreads();
    for (int s = 128; s > 0; s >>= 1) {
        if (t < s) sm[t] += sm[t + s];
        __syncthreads();
    }
    if (t == 0) (second ? bsum2 : bsum)[blk] = sm[0];
}

__device__ __forceinline__ void scanB_one(const int* __restrict__ bsum,
                                          int* __restrict__ boffs, int lane) {
    int run = 0;
    for (int base = 0; base < B; base += 64) {
        int i = base + lane;
        int v = (i < B) ? bsum[i] : 0;
        int orig = v;
        for (int off = 1; off < 64; off <<= 1) {
            int t = __shfl_up(v, off);
            if (lane >= off) v += t;
        }
        if (i < B) boffs[i] = run + v - orig;   // exclusive
        run += __shfl(v, 63);
    }
}

__global__ void scanB2(const int* __restrict__ bsum, int* __restrict__ boffs,
                       const int* __restrict__ bsum2, int* __restrict__ boffs2) {
    int lane = threadIdx.x;
    scanB_one(bsum, boffs, lane);
    scanB_one(bsum2, boffs2, lane);
}

__global__ void scanC2(const int* __restrict__ a, const int* __restrict__ a2,
                       const int* __restrict__ boffs, const int* __restrict__ boffs2,
                       int* __restrict__ offs, int* __restrict__ offs2) {
    __shared__ int sm[256];
    int t = threadIdx.x;
    bool second = blockIdx.x >= NSB;
    int blk = second ? blockIdx.x - NSB : blockIdx.x;
    const int* sp = second ? a2 : a;
    int i = blk * 256 + t;
    int v = sp[i];
    sm[t] = v;
    __syncthreads();
    for (int off = 1; off < 256; off <<= 1) {
        int x = (t >= off) ? sm[t - off] : 0;
        __syncthreads();
        sm[t] += x;
        __syncthreads();
    }
    (second ? offs2 : offs)[i] = (second ? boffs2 : boffs)[blk] + sm[t] - v;
}

__global__ __launch_bounds__(1024) void sort_kernel(const int* __restrict__ src,
                                                    const int* __restrict__ dst,
                                                    const int* __restrict__ offs,
                                                    const int* __restrict__ offs2,
                                                    unsigned* __restrict__ ebuf,
                                                    unsigned* __restrict__ sbuf) {
    __shared__ int cur[B];
    __shared__ int cur2[B];
    int g = blockIdx.x;
    for (int i = threadIdx.x; i < B; i += 1024) {
        cur[i]  = offs[i * G + g];
        cur2[i] = offs2[i * G + g];
    }
    __syncthreads();
    const int* sp = src + g * CHUNK;
    const int* dp = dst + g * CHUNK;
    for (int k = threadIdx.x; k < CHUNK; k += 1024) {
        int d = dp[k], s = sp[k];
        int pos = atomicAdd(&cur[d >> BSHIFT], 1);
        ebuf[pos] = ((unsigned)(d & BMASK) << 17) | (unsigned)s;   // src < 2^17
        int pos2 = atomicAdd(&cur2[s >> BSHIFT], 1);
        sbuf[pos2] = (unsigned)s;
    }
}

// ---------------- out-degree count + norm_s + x*norm_s -> bf16 (fused) ---------
// Round-5: deg_count and conv_kernel fused (one launch, no deg round-trip).
// Per bucket: count out-degrees from sbuf segment in LDS, then convert the
// bucket's 128 rows with float4 reads.

__global__ __launch_bounds__(256) void conv_deg(const int* __restrict__ offs2,
                                                const unsigned* __restrict__ sbuf,
                                                const float* __restrict__ x,
                                                float* __restrict__ norm_s,
                                                unsigned* __restrict__ hb) {
    __shared__ int cnt[128];
    __shared__ float nsm[128];
    const int b = blockIdx.x;
    const int t = threadIdx.x;
    const int s = offs2[b * G];
    const int e = (b == B - 1) ? NE : offs2[(b + 1) * G];
    if (t < 128) cnt[t] = 0;
    __syncthreads();
    for (int k = s + t; k < e; k += 256)
        atomicAdd(&cnt[sbuf[k] & BMASK], 1);
    __syncthreads();
    if (t < 128) {
        int node = b * 128 + t;
        if (node < NN) {
            float ns = rsqrtf((float)(cnt[t] + 1));   // +1 = self-loop
            norm_s[node] = ns;
            nsm[t] = ns;
        }
    }
    __syncthreads();
    // convert 128 rows x 32 float4-quads
    for (int idx = t; idx < 128 * 32; idx += 256) {
        int r = idx >> 5, q = idx & 31;
        int node = b * 128 + r;
        if (node >= NN) continue;
        float ns = nsm[r];
        float4 v = ((const float4*)x)[(size_t)node * 32 + q];
        uint2 w;
        w.x = f2bf(v.x * ns) | (f2bf(v.y * ns) << 16);
        w.y = f2bf(v.z * ns) | (f2bf(v.w * ns) << 16);
        *(uint2*)(hb + (size_t)node * 64 + 2 * q) = w;
    }
}

// ---------------- per-bucket local sort: bucket order -> per-node CSR ----------

__global__ __launch_bounds__(256) void local_sort(
    const int* __restrict__ offs, unsigned* __restrict__ ebuf,
    int* __restrict__ row, float* __restrict__ norm_d)
{
    __shared__ int cnt[128];
    __shared__ int sc[128];
    const int b = blockIdx.x;
    const int t = threadIdx.x;
    const int s = offs[b * G];
    const int e = (b == B - 1) ? NE : offs[(b + 1) * G];
    if (t < 128) cnt[t] = 0;
    __syncthreads();

    unsigned ent[16];   // 16*256 = 4096 capacity; bucket mean 2048, sd ~45
    int nent = 0;
    for (int k = s + t; k < e && nent < 16; k += 256) {
        unsigned u = ebuf[k];
        ent[nent++] = u;
        atomicAdd(&cnt[u >> 17], 1);
    }
    __syncthreads();

    if (t < 128) sc[t] = cnt[t];
    __syncthreads();
    for (int off = 1; off < 128; off <<= 1) {
        int v = 0;
        if (t < 128 && t >= off) v = sc[t - off];
        __syncthreads();
        if (t < 128) sc[t] += v;
        __syncthreads();
    }
    if (t < 128) {
        int st = s + sc[t] - cnt[t];   // exclusive start
        int node = b * 128 + t;
        if (node < NN) {
            row[node] = st;
            norm_d[node] = rsqrtf((float)(cnt[t] + 1));
        }
        cnt[t] = st;                   // becomes cursor
    }
    if (b == B - 1 && t == 0) row[NN] = NE;
    __syncthreads();

    for (int i = 0; i < nent; ++i) {
        unsigned u = ent[i];
        int pos = atomicAdd(&cnt[u >> 17], 1);
        ebuf[pos] = u & 0x1FFFFu;      // strip bucket bits -> plain src id
    }
}

// ---------------- CSR gather-aggregate over bf16 rows, fp32 accumulate --------
// Round-5 change: TWO nodes per wave. Evidence: fetch rate scaled ~linearly
// with occupancy (round-2 fused: same FETCH, 24% occ, 2.8x slower) -> still
// concurrency-limited, not fabric-limited. Pairing doubles outstanding loads
// per wave (16 x 512 B): node A's fetch latency hides under node B's
// issue+accumulate and vice versa.

__global__ __launch_bounds__(256) void csr_agg(
    const int* __restrict__ rowp, const int* __restrict__ csr,
    const unsigned* __restrict__ hp,
    unsigned* __restrict__ Ahi, unsigned* __restrict__ Alo)
{
    int i0 = (blockIdx.x * 4 + (threadIdx.x >> 6)) * 2;   // wave's node pair
    if (i0 >= NN) return;
    const int lane = threadIdx.x & 63;
    const int half = lane >> 5;     // 0: even edges, 1: odd edges
    const int c2   = lane & 31;     // u32 column pair [2c2, 2c2+1]

    float4 accA = {0.f, 0.f, 0.f, 0.f};
    float4 accB = {0.f, 0.f, 0.f, 0.f};
    if (half == 0) {                // self-loop rows counted once
        uint2 u = *(const uint2*)(hp + (size_t)i0 * 64 + 2 * c2);
        accA.x = __uint_as_float(u.x << 16);
        accA.y = __uint_as_float(u.x & 0xffff0000u);
        accA.z = __uint_as_float(u.y << 16);
        accA.w = __uint_as_float(u.y & 0xffff0000u);
        uint2 v = *(const uint2*)(hp + (size_t)(i0 + 1) * 64 + 2 * c2);
        accB.x = __uint_as_float(v.x << 16);
        accB.y = __uint_as_float(v.x & 0xffff0000u);
        accB.z = __uint_as_float(v.y << 16);
        accB.w = __uint_as_float(v.y & 0xffff0000u);
    }

    int baseA = rowp[i0];
    int eA    = rowp[i0 + 1];
    int baseB = eA;
    int eB    = rowp[i0 + 2];
    bool actA = baseA < eA, actB = baseB < eB;
    int nA = 0, nB = 0, svA = 0, svB = 0, jA = 0, jB = 0;
    if (actA) { nA = eA - baseA; if (nA > 64) nA = 64;
                svA = csr[baseA + (lane < nA ? lane : nA - 1)]; }
    if (actB) { nB = eB - baseB; if (nB > 64) nB = 64;
                svB = csr[baseB + (lane < nB ? lane : nB - 1)]; }

    while (actA || actB) {
        uint2 uA[8], uB[8];
        int vA = 0, vB = 0;
        if (actA) {
            int ss[8];
            #pragma unroll
            for (int t = 0; t < 8; ++t) {
                int e2 = jA + 2 * t + half;
                ss[t] = __shfl(svA, e2 < nA ? e2 : nA - 1);
            }
            #pragma unroll
            for (int t = 0; t < 8; ++t)
                uA[t] = *(const uint2*)(hp + (size_t)ss[t] * 64 + 2 * c2);
            vA = 1;
        }
        if (actB) {
            int ss[8];
            #pragma unroll
            for (int t = 0; t < 8; ++t) {
                int e2 = jB + 2 * t + half;
                ss[t] = __shfl(svB, e2 < nB ? e2 : nB - 1);
            }
            #pragma unroll
            for (int t = 0; t < 8; ++t)
                uB[t] = *(const uint2*)(hp + (size_t)ss[t] * 64 + 2 * c2);
            vB = 1;
        }
        if (vA) {
            #pragma unroll
            for (int t = 0; t < 8; ++t) {
                if (jA + 2 * t + half < nA) {
                    accA.x += __uint_as_float(uA[t].x << 16);
                    accA.y += __uint_as_float(uA[t].x & 0xffff0000u);
                    accA.z += __uint_as_float(uA[t].y << 16);
                    accA.w += __uint_as_float(uA[t].y & 0xffff0000u);
                }
            }
            jA += 16;
            if (jA >= nA) {
                baseA += 64; jA = 0;
                actA = baseA < eA;
                if (actA) { nA = eA - baseA; if (nA > 64) nA = 64;
                            svA = csr[baseA + (lane < nA ? lane : nA - 1)]; }
            }
        }
        if (vB) {
            #pragma unroll
            for (int t = 0; t < 8; ++t) {
                if (jB + 2 * t + half < nB) {
                    accB.x += __uint_as_float(uB[t].x << 16);
                    accB.y += __uint_as_float(uB[t].x & 0xffff0000u);
                    accB.z += __uint_as_float(uB[t].y << 16);
                    accB.w += __uint_as_float(uB[t].y & 0xffff0000u);
                }
            }
            jB += 16;
            if (jB >= nB) {
                baseB += 64; jB = 0;
                actB = baseB < eB;
                if (actB) { nB = eB - baseB; if (nB > 64) nB = 64;
                            svB = csr[baseB + (lane < nB ? lane : nB - 1)]; }
            }
        }
    }

    // combine halves: both sides end with the full sum
    accA.x += __shfl_xor(accA.x, 32);
    accA.y += __shfl_xor(accA.y, 32);
    accA.z += __shfl_xor(accA.z, 32);
    accA.w += __shfl_xor(accA.w, 32);
    accB.x += __shfl_xor(accB.x, 32);
    accB.y += __shfl_xor(accB.y, 32);
    accB.z += __shfl_xor(accB.z, 32);
    accB.w += __shfl_xor(accB.w, 32);

    {
        unsigned h0 = f2bf(accA.x), h1 = f2bf(accA.y);
        unsigned h2 = f2bf(accA.z), h3 = f2bf(accA.w);
        if (half == 0) {
            uint2 w = { h0 | (h1 << 16), h2 | (h3 << 16) };
            *(uint2*)(Ahi + (size_t)i0 * 64 + 2 * c2) = w;
        } else {
            float l0 = accA.x - bf2f(h0), l1 = accA.y - bf2f(h1);
            float l2 = accA.z - bf2f(h2), l3 = accA.w - bf2f(h3);
            uint2 w = { f2bf(l0) | (f2bf(l1) << 16), f2bf(l2) | (f2bf(l3) << 16) };
            *(uint2*)(Alo + (size_t)i0 * 64 + 2 * c2) = w;
        }
    }
    {
        unsigned h0 = f2bf(accB.x), h1 = f2bf(accB.y);
        unsigned h2 = f2bf(accB.z), h3 = f2bf(accB.w);
        if (half == 0) {
            uint2 w = { h0 | (h1 << 16), h2 | (h3 << 16) };
            *(uint2*)(Ahi + (size_t)(i0 + 1) * 64 + 2 * c2) = w;
        } else {
            float l0 = accB.x - bf2f(h0), l1 = accB.y - bf2f(h1);
            float l2 = accB.z - bf2f(h2), l3 = accB.w - bf2f(h3);
            uint2 w = { f2bf(l0) | (f2bf(l1) << 16), f2bf(l2) | (f2bf(l3) << 16) };
            *(uint2*)(Alo + (size_t)(i0 + 1) * 64 + 2 * c2) = w;
        }
    }
}

// ---------------- MFMA GEMM, split-precision bf16 (3-mfma ~ fp32 accuracy) -----

template<bool LAYER0>
__global__ __launch_bounds__(256) void gemm_kernel(
    const unsigned* __restrict__ Ahi_g, const unsigned* __restrict__ Alo_g,
    const float* __restrict__ W, const float* __restrict__ bias,
    const float* __restrict__ norm_s, const float* __restrict__ norm_d,
    const float* __restrict__ gamma, const float* __restrict__ beta,
    const float* __restrict__ rmean, const float* __restrict__ rvar,
    float* __restrict__ outf, unsigned short* __restrict__ outb)
{
    __shared__ unsigned lhi[64 * 68];   // 64 rows x 136 bf16 (pad 8)
    __shared__ unsigned llo[64 * 68];

    const int w    = threadIdx.x >> 6;
    const int lane = threadIdx.x & 63;
    const int quad = lane >> 4;
    const int l16  = lane & 15;

    // ---- B fragments (hi/lo) for this wave's 2 col-tiles, all K ----
    v8s Bhi[2][4], Blo[2][4];
    int col[2];
    #pragma unroll
    for (int ct = 0; ct < 2; ++ct) {
        col[ct] = 32 * w + 16 * ct + l16;
        #pragma unroll
        for (int q = 0; q < 4; ++q) {
            int kb = 32 * q + quad * 8;
            v8s hi8, lo8;
            #pragma unroll
            for (int kk = 0; kk < 8; ++kk) {
                float wv = W[(kb + kk) * D + col[ct]];
                unsigned h = f2bf(wv);
                hi8[kk] = (short)h;
                lo8[kk] = (short)f2bf(wv - bf2f(h));
            }
            Bhi[ct][q] = hi8;
            Blo[ct][q] = lo8;
        }
    }

    float bcol[2], s[2] = {0.f, 0.f}, sh[2] = {0.f, 0.f};
    #pragma unroll
    for (int ct = 0; ct < 2; ++ct) {
        bcol[ct] = bias[col[ct]];
        if (LAYER0) {
            s[ct]  = gamma[col[ct]] * rsqrtf(rvar[col[ct]] + BNEPS);
            sh[ct] = beta[col[ct]] - rmean[col[ct]] * s[ct];
        }
    }

    for (int row0 = blockIdx.x * 64; row0 < NN; row0 += gridDim.x * 64) {
        __syncthreads();
        for (int idx = threadIdx.x; idx < 64 * 64; idx += 256) {
            int r = idx >> 6, cp = idx & 63;
            int rw = row0 + r;
            unsigned vh = 0, vl = 0;
            if (rw < NN) {
                vh = Ahi_g[(size_t)rw * 64 + cp];
                vl = Alo_g[(size_t)rw * 64 + cp];
            }
            lhi[r * 68 + cp] = vh;
            llo[r * 68 + cp] = vl;
        }
        __syncthreads();

        #pragma unroll
        for (int rt = 0; rt < 4; ++rt) {
            v4f acc0 = {0.f, 0.f, 0.f, 0.f};
            v4f acc1 = {0.f, 0.f, 0.f, 0.f};
            #pragma unroll
            for (int q = 0; q < 4; ++q) {
                const unsigned short* ph = (const unsigned short*)lhi
                    + (rt * 16 + l16) * 136 + q * 32 + quad * 8;
                const unsigned short* pl = (const unsigned short*)llo
                    + (rt * 16 + l16) * 136 + q * 32 + quad * 8;
                v8s ahi = *(const v8s*)ph;
                v8s alo = *(const v8s*)pl;
                acc0 = __builtin_amdgcn_mfma_f32_16x16x32_bf16(ahi, Bhi[0][q], acc0, 0, 0, 0);
                acc0 = __builtin_amdgcn_mfma_f32_16x16x32_bf16(alo, Bhi[0][q], acc0, 0, 0, 0);
                acc0 = __builtin_amdgcn_mfma_f32_16x16x32_bf16(ahi, Blo[0][q], acc0, 0, 0, 0);
                acc1 = __builtin_amdgcn_mfma_f32_16x16x32_bf16(ahi, Bhi[1][q], acc1, 0, 0, 0);
                acc1 = __builtin_amdgcn_mfma_f32_16x16x32_bf16(alo, Bhi[1][q], acc1, 0, 0, 0);
                acc1 = __builtin_amdgcn_mfma_f32_16x16x32_bf16(ahi, Blo[1][q], acc1, 0, 0, 0);
            }
            #pragma unroll
            for (int r = 0; r < 4; ++r) {
                int rw = row0 + rt * 16 + quad * 4 + r;
                if (rw >= NN) continue;
                float nd = norm_d[rw];
                float o0 = acc0[r] * nd + bcol[0];
                float o1 = acc1[r] * nd + bcol[1];
                if (LAYER0) {
                    o0 = o0 * s[0] + sh[0];
                    o1 = o1 * s[1] + sh[1];
                    o0 = o0 > 0.f ? o0 : LEAKY * o0;
                    o1 = o1 > 0.f ? o1 : LEAKY * o1;
                    float ns = norm_s[rw];
                    o0 *= ns; o1 *= ns;
                    outb[(size_t)rw * D + col[0]] = (unsigned short)f2bf(o0);
                    outb[(size_t)rw * D + col[1]] = (unsigned short)f2bf(o1);
                } else {
                    outf[(size_t)rw * D + col[0]] = o0;
                    outf[(size_t)rw * D + col[1]] = o1;
                }
            }
        }
    }
}

// ---------------- launch ----------------

extern "C" void kernel_launch(void* const* d_in, const int* in_sizes, int n_in,
                              void* d_out, int out_size, void* d_ws, size_t ws_size,
                              hipStream_t stream) {
    const float* x     = (const float*)d_in[0];
    const int*   src   = (const int*)d_in[1];
    const int*   dst   = (const int*)d_in[2];
    const float* W1    = (const float*)d_in[3];
    const float* b1    = (const float*)d_in[4];
    const float* W2    = (const float*)d_in[5];
    const float* b2    = (const float*)d_in[6];
    const float* gamma = (const float*)d_in[7];
    const float* beta  = (const float*)d_in[8];
    const float* rmean = (const float*)d_in[9];
    const float* rvar  = (const float*)d_in[10];
    float* out = (float*)d_out;

    // bf16 gather-source scratch lives in d_out's first half (dead once the
    // final GEMM overwrites all of d_out with fp32 results).
    unsigned* hb = (unsigned*)d_out;                    // NN*64 u32 = 25.6 MB

    // ws layout (4B units)
    unsigned* Ahi   = (unsigned*)d_ws;                  // NN*64 u32 (bf16 hi pairs)
    unsigned* Alo   = Ahi + (size_t)NN * 64;            // NN*64 u32 (bf16 lo pairs)
    float*    norm  = (float*)(Alo + (size_t)NN * 64);  // 2N f32
    int*      aux   = (int*)(norm + 2 * NN);            // N int slot (bsum2/boffs2)
    int*      hist  = aux + NN;                         // B*G int; row[] aliases after scanC
    int*      offs  = hist + B * G;                     // B*G int
    int*      bsum  = offs + B * G;                     // B int
    int*      boffs = bsum + B;                         // B int
    unsigned* ebuf  = (unsigned*)(boffs + B);           // NE u32
    float* norm_s = norm;
    float* norm_d = norm + NN;
    int*   row    = hist;                // aliases hist (dead after scanC)
    int*   bsum2  = aux;                 // B int
    int*   boffs2 = aux + B;             // B int

    // src-side scratch aliases the Ahi slot (dead until csr_agg writes it):
    int*      hist2 = (int*)Ahi;                        // B*G int
    int*      offs2 = hist2 + B * G;                    // B*G int
    unsigned* sbuf  = (unsigned*)(offs2 + B * G);       // NE u32  (total 8 MB < 25.6 MB)

    // counting sort by dst bucket + src-bucket scatter (no global atomics)
    hist_kernel<<<G, 1024, 0, stream>>>(src, dst, hist, hist2);
    scanA2<<<2 * NSB, 256, 0, stream>>>(hist, hist2, bsum, bsum2);
    scanB2<<<1, 64, 0, stream>>>(bsum, boffs, bsum2, boffs2);
    scanC2<<<2 * NSB, 256, 0, stream>>>(hist, hist2, boffs, boffs2, offs, offs2);
    sort_kernel<<<G, 1024, 0, stream>>>(src, dst, offs, offs2, ebuf, sbuf);
    conv_deg<<<B, 256, 0, stream>>>(offs2, sbuf, x, norm_s, hb);
    local_sort<<<B, 256, 0, stream>>>(offs, ebuf, row, norm_d);

    const int AGG_BLOCKS = (NN + 7) / 8;   // 2 nodes/wave, 4 waves/block
    const int GEMM_BLOCKS = 784;
    // layer 0: agg = selfloop + sum_e xs[src]  -> split bf16 hi/lo
    csr_agg<<<AGG_BLOCKS, 256, 0, stream>>>(row, (const int*)ebuf, hb, Ahi, Alo);
    gemm_kernel<true><<<GEMM_BLOCKS, 256, 0, stream>>>(Ahi, Alo, W1, b1,
                                                       norm_s, norm_d,
                                                       gamma, beta, rmean, rvar,
                                                       nullptr, (unsigned short*)hb);
    // layer 1: gather source = bf16 hs (norm_src folded)
    csr_agg<<<AGG_BLOCKS, 256, 0, stream>>>(row, (const int*)ebuf, hb, Ahi, Alo);
    gemm_kernel<false><<<GEMM_BLOCKS, 256, 0, stream>>>(Ahi, Alo, W2, b2,
                                                        norm_s, norm_d,
                                                        nullptr, nullptr, nullptr, nullptr,
                                                        out, nullptr);
}

// Round 6
// 419.273 us; speedup vs baseline: 1.2890x; 1.0190x over previous
//
#include <hip/hip_runtime.h>

#define NN 100000
#define NE 1600000
#define D 128
#define LEAKY 0.01f
#define BNEPS 1e-5f

#define G 256        // sort groups (workgroups)
#define CHUNK 6250   // NE / G exactly
#define B 782        // ceil(NN/128) buckets (128 nodes each)
#define BSHIFT 7
#define BMASK 127
#define NSB (B * G / 256)   // 782 scan blocks per histogram

typedef short v8s __attribute__((ext_vector_type(8)));
typedef float v4f __attribute__((ext_vector_type(4)));

// round-to-nearest-even f32 -> bf16 (returns low 16 bits)
__device__ __forceinline__ unsigned f2bf(float f) {
    unsigned u = __float_as_uint(f);
    return (u + 0x7fffu + ((u >> 16) & 1u)) >> 16;
}
__device__ __forceinline__ float bf2f(unsigned h) {
    return __uint_as_float(h << 16);
}

// ---------------- counting sort by dst bucket + src bucket ---------------------

__global__ __launch_bounds__(1024) void hist_kernel(const int* __restrict__ src,
                                                    const int* __restrict__ dst,
                                                    int* __restrict__ hist,
                                                    int* __restrict__ hist2) {
    __shared__ int h[B];
    __shared__ int h2[B];
    for (int i = threadIdx.x; i < B; i += 1024) { h[i] = 0; h2[i] = 0; }
    __syncthreads();
    int g = blockIdx.x;
    const int* dp = dst + g * CHUNK;
    const int* sp = src + g * CHUNK;
    for (int k = threadIdx.x; k < CHUNK; k += 1024) {
        atomicAdd(&h[dp[k] >> BSHIFT], 1);
        atomicAdd(&h2[sp[k] >> BSHIFT], 1);
    }
    __syncthreads();
    for (int i = threadIdx.x; i < B; i += 1024) {
        hist[i * G + g]  = h[i];
        hist2[i * G + g] = h2[i];
    }
}

// merged scans: one launch covers both histograms (round-5: 15 -> 11 dispatches)

__global__ void scanA2(const int* __restrict__ a, const int* __restrict__ a2,
                       int* __restrict__ bsum, int* __restrict__ bsum2) {
    __shared__ int sm[256];
    int t = threadIdx.x;
    bool second = blockIdx.x >= NSB;
    int blk = second ? blockIdx.x - NSB : blockIdx.x;
    const int* sp = second ? a2 : a;
    sm[t] = sp[blk * 256 + t];
    __syncthreads();
    for (int s = 128; s > 0; s >>= 1) {
        if (t < s) sm[t] += sm[t + s];
        __syncthreads();
    }
    if (t == 0) (second ? bsum2 : bsum)[blk] = sm[0];
}

__device__ __forceinline__ void scanB_one(const int* __restrict__ bsum,
                                          int* __restrict__ boffs, int lane) {
    int run = 0;
    for (int base = 0; base < B; base += 64) {
        int i = base + lane;
        int v = (i < B) ? bsum[i] : 0;
        int orig = v;
        for (int off = 1; off < 64; off <<= 1) {
            int t = __shfl_up(v, off);
            if (lane >= off) v += t;
        }
        if (i < B) boffs[i] = run + v - orig;   // exclusive
        run += __shfl(v, 63);
    }
}

__global__ void scanB2(const int* __restrict__ bsum, int* __restrict__ boffs,
                       const int* __restrict__ bsum2, int* __restrict__ boffs2) {
    int lane = threadIdx.x;
    scanB_one(bsum, boffs, lane);
    scanB_one(bsum2, boffs2, lane);
}

__global__ void scanC2(const int* __restrict__ a, const int* __restrict__ a2,
                       const int* __restrict__ boffs, const int* __restrict__ boffs2,
                       int* __restrict__ offs, int* __restrict__ offs2) {
    __shared__ int sm[256];
    int t = threadIdx.x;
    bool second = blockIdx.x >= NSB;
    int blk = second ? blockIdx.x - NSB : blockIdx.x;
    const int* sp = second ? a2 : a;
    int i = blk * 256 + t;
    int v = sp[i];
    sm[t] = v;
    __syncthreads();
    for (int off = 1; off < 256; off <<= 1) {
        int x = (t >= off) ? sm[t - off] : 0;
        __syncthreads();
        sm[t] += x;
        __syncthreads();
    }
    (second ? offs2 : offs)[i] = (second ? boffs2 : boffs)[blk] + sm[t] - v;
}

__global__ __launch_bounds__(1024) void sort_kernel(const int* __restrict__ src,
                                                    const int* __restrict__ dst,
                                                    const int* __restrict__ offs,
                                                    const int* __restrict__ offs2,
                                                    unsigned* __restrict__ ebuf,
                                                    unsigned* __restrict__ sbuf) {
    __shared__ int cur[B];
    __shared__ int cur2[B];
    int g = blockIdx.x;
    for (int i = threadIdx.x; i < B; i += 1024) {
        cur[i]  = offs[i * G + g];
        cur2[i] = offs2[i * G + g];
    }
    __syncthreads();
    const int* sp = src + g * CHUNK;
    const int* dp = dst + g * CHUNK;
    for (int k = threadIdx.x; k < CHUNK; k += 1024) {
        int d = dp[k], s = sp[k];
        int pos = atomicAdd(&cur[d >> BSHIFT], 1);
        ebuf[pos] = ((unsigned)(d & BMASK) << 17) | (unsigned)s;   // src < 2^17
        int pos2 = atomicAdd(&cur2[s >> BSHIFT], 1);
        sbuf[pos2] = (unsigned)s;
    }
}

// ---------------- out-degree count + norm_s + x*norm_s -> bf16 (fused) ---------

__global__ __launch_bounds__(256) void conv_deg(const int* __restrict__ offs2,
                                                const unsigned* __restrict__ sbuf,
                                                const float* __restrict__ x,
                                                float* __restrict__ norm_s,
                                                unsigned* __restrict__ hb) {
    __shared__ int cnt[128];
    __shared__ float nsm[128];
    const int b = blockIdx.x;
    const int t = threadIdx.x;
    const int s = offs2[b * G];
    const int e = (b == B - 1) ? NE : offs2[(b + 1) * G];
    if (t < 128) cnt[t] = 0;
    __syncthreads();
    for (int k = s + t; k < e; k += 256)
        atomicAdd(&cnt[sbuf[k] & BMASK], 1);
    __syncthreads();
    if (t < 128) {
        int node = b * 128 + t;
        if (node < NN) {
            float ns = rsqrtf((float)(cnt[t] + 1));   // +1 = self-loop
            norm_s[node] = ns;
            nsm[t] = ns;
        }
    }
    __syncthreads();
    // convert 128 rows x 32 float4-quads
    for (int idx = t; idx < 128 * 32; idx += 256) {
        int r = idx >> 5, q = idx & 31;
        int node = b * 128 + r;
        if (node >= NN) continue;
        float ns = nsm[r];
        float4 v = ((const float4*)x)[(size_t)node * 32 + q];
        uint2 w;
        w.x = f2bf(v.x * ns) | (f2bf(v.y * ns) << 16);
        w.y = f2bf(v.z * ns) | (f2bf(v.w * ns) << 16);
        *(uint2*)(hb + (size_t)node * 64 + 2 * q) = w;
    }
}

// ---------------- per-bucket local sort: bucket order -> per-node CSR ----------

__global__ __launch_bounds__(256) void local_sort(
    const int* __restrict__ offs, unsigned* __restrict__ ebuf,
    int* __restrict__ row, float* __restrict__ norm_d)
{
    __shared__ int cnt[128];
    __shared__ int sc[128];
    const int b = blockIdx.x;
    const int t = threadIdx.x;
    const int s = offs[b * G];
    const int e = (b == B - 1) ? NE : offs[(b + 1) * G];
    if (t < 128) cnt[t] = 0;
    __syncthreads();

    unsigned ent[16];   // 16*256 = 4096 capacity; bucket mean 2048, sd ~45
    int nent = 0;
    for (int k = s + t; k < e && nent < 16; k += 256) {
        unsigned u = ebuf[k];
        ent[nent++] = u;
        atomicAdd(&cnt[u >> 17], 1);
    }
    __syncthreads();

    if (t < 128) sc[t] = cnt[t];
    __syncthreads();
    for (int off = 1; off < 128; off <<= 1) {
        int v = 0;
        if (t < 128 && t >= off) v = sc[t - off];
        __syncthreads();
        if (t < 128) sc[t] += v;
        __syncthreads();
    }
    if (t < 128) {
        int st = s + sc[t] - cnt[t];   // exclusive start
        int node = b * 128 + t;
        if (node < NN) {
            row[node] = st;
            norm_d[node] = rsqrtf((float)(cnt[t] + 1));
        }
        cnt[t] = st;                   // becomes cursor
    }
    if (b == B - 1 && t == 0) row[NN] = NE;
    __syncthreads();

    for (int i = 0; i < nent; ++i) {
        unsigned u = ent[i];
        int pos = atomicAdd(&cnt[u >> 17], 1);
        ebuf[pos] = u & 0x1FFFFu;      // strip bucket bits -> plain src id
    }
}

// ---------------- CSR gather-aggregate over bf16 rows, fp32 accumulate --------
// Round-6: single node/wave (round-5's 2-node pairing cost VGPR 24->44,
// occupancy 72->46%, REGRESSED; throughput ~ occupancy on this gather).
// n is wave-uniform, so full 16-edge blocks run with NO clamp and NO per-edge
// predication (scalar loop bound); only the final partial block is masked.

__global__ __launch_bounds__(256) void csr_agg(
    const int* __restrict__ rowp, const int* __restrict__ csr,
    const unsigned* __restrict__ hp,
    unsigned* __restrict__ Ahi, unsigned* __restrict__ Alo)
{
    int i = blockIdx.x * 4 + (threadIdx.x >> 6);
    if (i >= NN) return;
    const int lane = threadIdx.x & 63;
    const int half = lane >> 5;     // 0: even edges, 1: odd edges
    const int c2   = lane & 31;     // u32 column pair [2c2, 2c2+1]

    float4 acc = {0.f, 0.f, 0.f, 0.f};
    if (half == 0) {                // self-loop row counted once
        uint2 u = *(const uint2*)(hp + (size_t)i * 64 + 2 * c2);
        acc.x = __uint_as_float(u.x << 16);
        acc.y = __uint_as_float(u.x & 0xffff0000u);
        acc.z = __uint_as_float(u.y << 16);
        acc.w = __uint_as_float(u.y & 0xffff0000u);
    }

    int start = rowp[i], end = rowp[i + 1];
    for (int base = start; base < end; base += 64) {
        int n = end - base; if (n > 64) n = 64;
        int sv = csr[base + (lane < n ? lane : n - 1)];
        int nfull = n & ~15;
        int j = 0;
        // full blocks: unpredicated, unclamped
        for (; j < nfull; j += 16) {
            int ss[8]; uint2 uu[8];
            #pragma unroll
            for (int t = 0; t < 8; ++t) ss[t] = __shfl(sv, j + 2 * t + half);
            #pragma unroll
            for (int t = 0; t < 8; ++t)
                uu[t] = *(const uint2*)(hp + (size_t)ss[t] * 64 + 2 * c2);
            #pragma unroll
            for (int t = 0; t < 8; ++t) {
                acc.x += __uint_as_float(uu[t].x << 16);
                acc.y += __uint_as_float(uu[t].x & 0xffff0000u);
                acc.z += __uint_as_float(uu[t].y << 16);
                acc.w += __uint_as_float(uu[t].y & 0xffff0000u);
            }
        }
        // single masked tail block
        if (j < n) {
            int ss[8]; uint2 uu[8];
            #pragma unroll
            for (int t = 0; t < 8; ++t) {
                int e = j + 2 * t + half;
                ss[t] = __shfl(sv, e < n ? e : n - 1);
            }
            #pragma unroll
            for (int t = 0; t < 8; ++t)
                uu[t] = *(const uint2*)(hp + (size_t)ss[t] * 64 + 2 * c2);
            #pragma unroll
            for (int t = 0; t < 8; ++t) {
                if (j + 2 * t + half < n) {
                    acc.x += __uint_as_float(uu[t].x << 16);
                    acc.y += __uint_as_float(uu[t].x & 0xffff0000u);
                    acc.z += __uint_as_float(uu[t].y << 16);
                    acc.w += __uint_as_float(uu[t].y & 0xffff0000u);
                }
            }
        }
    }

    // combine halves: both sides end with the full sum
    acc.x += __shfl_xor(acc.x, 32);
    acc.y += __shfl_xor(acc.y, 32);
    acc.z += __shfl_xor(acc.z, 32);
    acc.w += __shfl_xor(acc.w, 32);

    unsigned h0 = f2bf(acc.x), h1 = f2bf(acc.y);
    unsigned h2 = f2bf(acc.z), h3 = f2bf(acc.w);
    if (half == 0) {
        uint2 w = { h0 | (h1 << 16), h2 | (h3 << 16) };
        *(uint2*)(Ahi + (size_t)i * 64 + 2 * c2) = w;
    } else {
        float l0 = acc.x - bf2f(h0), l1 = acc.y - bf2f(h1);
        float l2 = acc.z - bf2f(h2), l3 = acc.w - bf2f(h3);
        uint2 w = { f2bf(l0) | (f2bf(l1) << 16), f2bf(l2) | (f2bf(l3) << 16) };
        *(uint2*)(Alo + (size_t)i * 64 + 2 * c2) = w;
    }
}

// ---------------- MFMA GEMM, split-precision bf16 (3-mfma ~ fp32 accuracy) -----

template<bool LAYER0>
__global__ __launch_bounds__(256) void gemm_kernel(
    const unsigned* __restrict__ Ahi_g, const unsigned* __restrict__ Alo_g,
    const float* __restrict__ W, const float* __restrict__ bias,
    const float* __restrict__ norm_s, const float* __restrict__ norm_d,
    const float* __restrict__ gamma, const float* __restrict__ beta,
    const float* __restrict__ rmean, const float* __restrict__ rvar,
    float* __restrict__ outf, unsigned short* __restrict__ outb)
{
    __shared__ unsigned lhi[64 * 68];   // 64 rows x 136 bf16 (pad 8)
    __shared__ unsigned llo[64 * 68];

    const int w    = threadIdx.x >> 6;
    const int lane = threadIdx.x & 63;
    const int quad = lane >> 4;
    const int l16  = lane & 15;

    // ---- B fragments (hi/lo) for this wave's 2 col-tiles, all K ----
    v8s Bhi[2][4], Blo[2][4];
    int col[2];
    #pragma unroll
    for (int ct = 0; ct < 2; ++ct) {
        col[ct] = 32 * w + 16 * ct + l16;
        #pragma unroll
        for (int q = 0; q < 4; ++q) {
            int kb = 32 * q + quad * 8;
            v8s hi8, lo8;
            #pragma unroll
            for (int kk = 0; kk < 8; ++kk) {
                float wv = W[(kb + kk) * D + col[ct]];
                unsigned h = f2bf(wv);
                hi8[kk] = (short)h;
                lo8[kk] = (short)f2bf(wv - bf2f(h));
            }
            Bhi[ct][q] = hi8;
            Blo[ct][q] = lo8;
        }
    }

    float bcol[2], s[2] = {0.f, 0.f}, sh[2] = {0.f, 0.f};
    #pragma unroll
    for (int ct = 0; ct < 2; ++ct) {
        bcol[ct] = bias[col[ct]];
        if (LAYER0) {
            s[ct]  = gamma[col[ct]] * rsqrtf(rvar[col[ct]] + BNEPS);
            sh[ct] = beta[col[ct]] - rmean[col[ct]] * s[ct];
        }
    }

    for (int row0 = blockIdx.x * 64; row0 < NN; row0 += gridDim.x * 64) {
        __syncthreads();
        for (int idx = threadIdx.x; idx < 64 * 64; idx += 256) {
            int r = idx >> 6, cp = idx & 63;
            int rw = row0 + r;
            unsigned vh = 0, vl = 0;
            if (rw < NN) {
                vh = Ahi_g[(size_t)rw * 64 + cp];
                vl = Alo_g[(size_t)rw * 64 + cp];
            }
            lhi[r * 68 + cp] = vh;
            llo[r * 68 + cp] = vl;
        }
        __syncthreads();

        #pragma unroll
        for (int rt = 0; rt < 4; ++rt) {
            v4f acc0 = {0.f, 0.f, 0.f, 0.f};
            v4f acc1 = {0.f, 0.f, 0.f, 0.f};
            #pragma unroll
            for (int q = 0; q < 4; ++q) {
                const unsigned short* ph = (const unsigned short*)lhi
                    + (rt * 16 + l16) * 136 + q * 32 + quad * 8;
                const unsigned short* pl = (const unsigned short*)llo
                    + (rt * 16 + l16) * 136 + q * 32 + quad * 8;
                v8s ahi = *(const v8s*)ph;
                v8s alo = *(const v8s*)pl;
                acc0 = __builtin_amdgcn_mfma_f32_16x16x32_bf16(ahi, Bhi[0][q], acc0, 0, 0, 0);
                acc0 = __builtin_amdgcn_mfma_f32_16x16x32_bf16(alo, Bhi[0][q], acc0, 0, 0, 0);
                acc0 = __builtin_amdgcn_mfma_f32_16x16x32_bf16(ahi, Blo[0][q], acc0, 0, 0, 0);
                acc1 = __builtin_amdgcn_mfma_f32_16x16x32_bf16(ahi, Bhi[1][q], acc1, 0, 0, 0);
                acc1 = __builtin_amdgcn_mfma_f32_16x16x32_bf16(alo, Bhi[1][q], acc1, 0, 0, 0);
                acc1 = __builtin_amdgcn_mfma_f32_16x16x32_bf16(ahi, Blo[1][q], acc1, 0, 0, 0);
            }
            #pragma unroll
            for (int r = 0; r < 4; ++r) {
                int rw = row0 + rt * 16 + quad * 4 + r;
                if (rw >= NN) continue;
                float nd = norm_d[rw];
                float o0 = acc0[r] * nd + bcol[0];
                float o1 = acc1[r] * nd + bcol[1];
                if (LAYER0) {
                    o0 = o0 * s[0] + sh[0];
                    o1 = o1 * s[1] + sh[1];
                    o0 = o0 > 0.f ? o0 : LEAKY * o0;
                    o1 = o1 > 0.f ? o1 : LEAKY * o1;
                    float ns = norm_s[rw];
                    o0 *= ns; o1 *= ns;
                    outb[(size_t)rw * D + col[0]] = (unsigned short)f2bf(o0);
                    outb[(size_t)rw * D + col[1]] = (unsigned short)f2bf(o1);
                } else {
                    outf[(size_t)rw * D + col[0]] = o0;
                    outf[(size_t)rw * D + col[1]] = o1;
                }
            }
        }
    }
}

// ---------------- launch ----------------

extern "C" void kernel_launch(void* const* d_in, const int* in_sizes, int n_in,
                              void* d_out, int out_size, void* d_ws, size_t ws_size,
                              hipStream_t stream) {
    const float* x     = (const float*)d_in[0];
    const int*   src   = (const int*)d_in[1];
    const int*   dst   = (const int*)d_in[2];
    const float* W1    = (const float*)d_in[3];
    const float* b1    = (const float*)d_in[4];
    const float* W2    = (const float*)d_in[5];
    const float* b2    = (const float*)d_in[6];
    const float* gamma = (const float*)d_in[7];
    const float* beta  = (const float*)d_in[8];
    const float* rmean = (const float*)d_in[9];
    const float* rvar  = (const float*)d_in[10];
    float* out = (float*)d_out;

    // bf16 gather-source scratch lives in d_out's first half (dead once the
    // final GEMM overwrites all of d_out with fp32 results).
    unsigned* hb = (unsigned*)d_out;                    // NN*64 u32 = 25.6 MB

    // ws layout (4B units)
    unsigned* Ahi   = (unsigned*)d_ws;                  // NN*64 u32 (bf16 hi pairs)
    unsigned* Alo   = Ahi + (size_t)NN * 64;            // NN*64 u32 (bf16 lo pairs)
    float*    norm  = (float*)(Alo + (size_t)NN * 64);  // 2N f32
    int*      aux   = (int*)(norm + 2 * NN);            // N int slot (bsum2/boffs2)
    int*      hist  = aux + NN;                         // B*G int; row[] aliases after scanC
    int*      offs  = hist + B * G;                     // B*G int
    int*      bsum  = offs + B * G;                     // B int
    int*      boffs = bsum + B;                         // B int
    unsigned* ebuf  = (unsigned*)(boffs + B);           // NE u32
    float* norm_s = norm;
    float* norm_d = norm + NN;
    int*   row    = hist;                // aliases hist (dead after scanC)
    int*   bsum2  = aux;                 // B int
    int*   boffs2 = aux + B;             // B int

    // src-side scratch aliases the Ahi slot (dead until csr_agg writes it):
    int*      hist2 = (int*)Ahi;                        // B*G int
    int*      offs2 = hist2 + B * G;                    // B*G int
    unsigned* sbuf  = (unsigned*)(offs2 + B * G);       // NE u32  (total 8 MB < 25.6 MB)

    // counting sort by dst bucket + src-bucket scatter (no global atomics)
    hist_kernel<<<G, 1024, 0, stream>>>(src, dst, hist, hist2);
    scanA2<<<2 * NSB, 256, 0, stream>>>(hist, hist2, bsum, bsum2);
    scanB2<<<1, 64, 0, stream>>>(bsum, boffs, bsum2, boffs2);
    scanC2<<<2 * NSB, 256, 0, stream>>>(hist, hist2, boffs, boffs2, offs, offs2);
    sort_kernel<<<G, 1024, 0, stream>>>(src, dst, offs, offs2, ebuf, sbuf);
    conv_deg<<<B, 256, 0, stream>>>(offs2, sbuf, x, norm_s, hb);
    local_sort<<<B, 256, 0, stream>>>(offs, ebuf, row, norm_d);

    const int AGG_BLOCKS = (NN + 3) / 4;
    const int GEMM_BLOCKS = 784;
    // layer 0: agg = selfloop + sum_e xs[src]  -> split bf16 hi/lo
    csr_agg<<<AGG_BLOCKS, 256, 0, stream>>>(row, (const int*)ebuf, hb, Ahi, Alo);
    gemm_kernel<true><<<GEMM_BLOCKS, 256, 0, stream>>>(Ahi, Alo, W1, b1,
                                                       norm_s, norm_d,
                                                       gamma, beta, rmean, rvar,
                                                       nullptr, (unsigned short*)hb);
    // layer 1: gather source = bf16 hs (norm_src folded)
    csr_agg<<<AGG_BLOCKS, 256, 0, stream>>>(row, (const int*)ebuf, hb, Ahi, Alo);
    gemm_kernel<false><<<GEMM_BLOCKS, 256, 0, stream>>>(Ahi, Alo, W2, b2,
                                                        norm_s, norm_d,
                                                        nullptr, nullptr, nullptr, nullptr,
                                                        out, nullptr);
}

// Round 7
// 418.790 us; speedup vs baseline: 1.2905x; 1.0012x over previous
//
#include <hip/hip_runtime.h>

#define NN 100000
#define NE 1600000
#define D 128
#define LEAKY 0.01f
#define BNEPS 1e-5f

#define G 256        // sort groups (workgroups)
#define CHUNK 6250   // NE / G exactly
#define B 782        // ceil(NN/128) buckets (128 nodes each)
#define BSHIFT 7
#define BMASK 127
#define NSB (B * G / 256)   // 782 scan blocks per histogram

typedef short v8s __attribute__((ext_vector_type(8)));
typedef float v4f __attribute__((ext_vector_type(4)));

// round-to-nearest-even f32 -> bf16 (returns low 16 bits)
__device__ __forceinline__ unsigned f2bf(float f) {
    unsigned u = __float_as_uint(f);
    return (u + 0x7fffu + ((u >> 16) & 1u)) >> 16;
}
__device__ __forceinline__ float bf2f(unsigned h) {
    return __uint_as_float(h << 16);
}
__device__ __forceinline__ float blo(unsigned u) { return __uint_as_float(u << 16); }
__device__ __forceinline__ float bhi(unsigned u) { return __uint_as_float(u & 0xffff0000u); }

// ---------------- counting sort by dst bucket + src bucket ---------------------

__global__ __launch_bounds__(1024) void hist_kernel(const int* __restrict__ src,
                                                    const int* __restrict__ dst,
                                                    int* __restrict__ hist,
                                                    int* __restrict__ hist2) {
    __shared__ int h[B];
    __shared__ int h2[B];
    for (int i = threadIdx.x; i < B; i += 1024) { h[i] = 0; h2[i] = 0; }
    __syncthreads();
    int g = blockIdx.x;
    const int* dp = dst + g * CHUNK;
    const int* sp = src + g * CHUNK;
    for (int k = threadIdx.x; k < CHUNK; k += 1024) {
        atomicAdd(&h[dp[k] >> BSHIFT], 1);
        atomicAdd(&h2[sp[k] >> BSHIFT], 1);
    }
    __syncthreads();
    for (int i = threadIdx.x; i < B; i += 1024) {
        hist[i * G + g]  = h[i];
        hist2[i * G + g] = h2[i];
    }
}

__global__ void scanA2(const int* __restrict__ a, const int* __restrict__ a2,
                       int* __restrict__ bsum, int* __restrict__ bsum2) {
    __shared__ int sm[256];
    int t = threadIdx.x;
    bool second = blockIdx.x >= NSB;
    int blk = second ? blockIdx.x - NSB : blockIdx.x;
    const int* sp = second ? a2 : a;
    sm[t] = sp[blk * 256 + t];
    __syncthreads();
    for (int s = 128; s > 0; s >>= 1) {
        if (t < s) sm[t] += sm[t + s];
        __syncthreads();
    }
    if (t == 0) (second ? bsum2 : bsum)[blk] = sm[0];
}

// round-7: scanB folded in — each block derives its own offset from bsum
// (<=4 loads/thread + LDS reduce), removing the serial 1-block scanB2 launch.
__global__ void scanC2(const int* __restrict__ a, const int* __restrict__ a2,
                       const int* __restrict__ bsum, const int* __restrict__ bsum2,
                       int* __restrict__ offs, int* __restrict__ offs2) {
    __shared__ int sm[256];
    __shared__ int bo;
    int t = threadIdx.x;
    bool second = blockIdx.x >= NSB;
    int blk = second ? blockIdx.x - NSB : blockIdx.x;
    const int* sp = second ? a2 : a;
    const int* bs = second ? bsum2 : bsum;
    int part = 0;
    for (int j = t; j < blk; j += 256) part += bs[j];
    sm[t] = part;
    __syncthreads();
    for (int s = 128; s > 0; s >>= 1) {
        if (t < s) sm[t] += sm[t + s];
        __syncthreads();
    }
    if (t == 0) bo = sm[0];
    __syncthreads();
    int i = blk * 256 + t;
    int v = sp[i];
    sm[t] = v;
    __syncthreads();
    for (int off = 1; off < 256; off <<= 1) {
        int x = (t >= off) ? sm[t - off] : 0;
        __syncthreads();
        sm[t] += x;
        __syncthreads();
    }
    (second ? offs2 : offs)[i] = bo + sm[t] - v;    // exclusive
}

__global__ __launch_bounds__(1024) void sort_kernel(const int* __restrict__ src,
                                                    const int* __restrict__ dst,
                                                    const int* __restrict__ offs,
                                                    const int* __restrict__ offs2,
                                                    unsigned* __restrict__ ebuf,
                                                    unsigned* __restrict__ sbuf) {
    __shared__ int cur[B];
    __shared__ int cur2[B];
    int g = blockIdx.x;
    for (int i = threadIdx.x; i < B; i += 1024) {
        cur[i]  = offs[i * G + g];
        cur2[i] = offs2[i * G + g];
    }
    __syncthreads();
    const int* sp = src + g * CHUNK;
    const int* dp = dst + g * CHUNK;
    for (int k = threadIdx.x; k < CHUNK; k += 1024) {
        int d = dp[k], s = sp[k];
        int pos = atomicAdd(&cur[d >> BSHIFT], 1);
        ebuf[pos] = ((unsigned)(d & BMASK) << 17) | (unsigned)s;   // src < 2^17
        int pos2 = atomicAdd(&cur2[s >> BSHIFT], 1);
        sbuf[pos2] = (unsigned)s;
    }
}

// ---------------- bucket_prep: (out-deg + conv) then (local sort -> CSR) -------
// round-7: conv_deg and local_sort fused (same 782-block/256-thread shape,
// independent inputs) — one launch saved.

__global__ __launch_bounds__(256) void bucket_prep(
    const int* __restrict__ offs, const int* __restrict__ offs2,
    unsigned* __restrict__ ebuf, const unsigned* __restrict__ sbuf,
    const float* __restrict__ x, int* __restrict__ row,
    float* __restrict__ norm_s, float* __restrict__ norm_d,
    unsigned* __restrict__ hb)
{
    __shared__ int cnt[128];
    __shared__ int sc[128];
    __shared__ float nsm[128];
    const int b = blockIdx.x;
    const int t = threadIdx.x;

    // ---- part 1: out-degree count + norm_s + x*norm_s -> bf16 hb ----
    {
        const int s = offs2[b * G];
        const int e = (b == B - 1) ? NE : offs2[(b + 1) * G];
        if (t < 128) cnt[t] = 0;
        __syncthreads();
        for (int k = s + t; k < e; k += 256)
            atomicAdd(&cnt[sbuf[k] & BMASK], 1);
        __syncthreads();
        if (t < 128) {
            int node = b * 128 + t;
            if (node < NN) {
                float ns = rsqrtf((float)(cnt[t] + 1));   // +1 = self-loop
                norm_s[node] = ns;
                nsm[t] = ns;
            }
        }
        __syncthreads();
        for (int idx = t; idx < 128 * 32; idx += 256) {
            int r = idx >> 5, q = idx & 31;
            int node = b * 128 + r;
            if (node >= NN) continue;
            float ns = nsm[r];
            float4 v = ((const float4*)x)[(size_t)node * 32 + q];
            uint2 w;
            w.x = f2bf(v.x * ns) | (f2bf(v.y * ns) << 16);
            w.y = f2bf(v.z * ns) | (f2bf(v.w * ns) << 16);
            *(uint2*)(hb + (size_t)node * 64 + 2 * q) = w;
        }
    }
    __syncthreads();

    // ---- part 2: per-bucket local sort: bucket order -> per-node CSR ----
    {
        const int s = offs[b * G];
        const int e = (b == B - 1) ? NE : offs[(b + 1) * G];
        if (t < 128) cnt[t] = 0;
        __syncthreads();

        unsigned ent[16];   // 16*256 = 4096 capacity; bucket mean 2048, sd ~45
        int nent = 0;
        for (int k = s + t; k < e && nent < 16; k += 256) {
            unsigned u = ebuf[k];
            ent[nent++] = u;
            atomicAdd(&cnt[u >> 17], 1);
        }
        __syncthreads();

        if (t < 128) sc[t] = cnt[t];
        __syncthreads();
        for (int off = 1; off < 128; off <<= 1) {
            int v = 0;
            if (t < 128 && t >= off) v = sc[t - off];
            __syncthreads();
            if (t < 128) sc[t] += v;
            __syncthreads();
        }
        if (t < 128) {
            int st = s + sc[t] - cnt[t];   // exclusive start
            int node = b * 128 + t;
            if (node < NN) {
                row[node] = st;
                norm_d[node] = rsqrtf((float)(cnt[t] + 1));
            }
            cnt[t] = st;                   // becomes cursor
        }
        if (b == B - 1 && t == 0) row[NN] = NE;
        __syncthreads();

        for (int i = 0; i < nent; ++i) {
            unsigned u = ent[i];
            int pos = atomicAdd(&cnt[u >> 17], 1);
            ebuf[pos] = u & 0x1FFFFu;      // strip bucket bits -> plain src id
        }
    }
}

// ---------------- CSR gather-aggregate over bf16 rows, fp32 accumulate --------
// Round-7: quarter-wave gather. 16 lanes x uint4 per edge -> one batch of 8
// load slots covers 32 edges (was 16). Mean deg 16, so deg-17..64 rows (43%)
// collapse from 2-4 dependent batches to 1 (E[batches] 1.55 -> 1.04).
// Wave-uniform guard (4t < rem) skips wholly-empty slots so deg<=16 rows pay
// nothing extra. One node per wave (round-5's dual-node divergence avoided).

__global__ __launch_bounds__(256) void csr_agg(
    const int* __restrict__ rowp, const int* __restrict__ csr,
    const unsigned* __restrict__ hp,
    unsigned* __restrict__ Ahi, unsigned* __restrict__ Alo)
{
    int i = blockIdx.x * 4 + (threadIdx.x >> 6);
    if (i >= NN) return;
    const int lane = threadIdx.x & 63;
    const int q    = lane >> 4;     // quarter 0..3: edge subset
    const int f    = lane & 15;     // 16B feature slice (4 u32 words)

    float acc[8] = {0.f, 0.f, 0.f, 0.f, 0.f, 0.f, 0.f, 0.f};
    if (q == 0) {                   // self-loop row counted once
        uint4 u = *(const uint4*)(hp + (size_t)i * 64 + 4 * f);
        acc[0] = blo(u.x); acc[1] = bhi(u.x);
        acc[2] = blo(u.y); acc[3] = bhi(u.y);
        acc[4] = blo(u.z); acc[5] = bhi(u.z);
        acc[6] = blo(u.w); acc[7] = bhi(u.w);
    }

    int start = rowp[i], end = rowp[i + 1];
    for (int base = start; base < end; base += 64) {
        int n = end - base; if (n > 64) n = 64;
        int sv = csr[base + (lane < n ? lane : n - 1)];
        for (int j = 0; j < n; j += 32) {
            int rem = n - j;
            uint4 uu[8];
            #pragma unroll
            for (int tt = 0; tt < 8; ++tt) {
                if (4 * tt < rem) {                 // wave-uniform slot guard
                    int e = j + 4 * tt + q;
                    int s = __shfl(sv, e < n ? e : n - 1);
                    uu[tt] = *(const uint4*)(hp + (size_t)s * 64 + 4 * f);
                }
            }
            #pragma unroll
            for (int tt = 0; tt < 8; ++tt) {
                if (4 * tt < rem) {
                    if (j + 4 * tt + q < n) {       // per-quarter predicate
                        acc[0] += blo(uu[tt].x); acc[1] += bhi(uu[tt].x);
                        acc[2] += blo(uu[tt].y); acc[3] += bhi(uu[tt].y);
                        acc[4] += blo(uu[tt].z); acc[5] += bhi(uu[tt].z);
                        acc[6] += blo(uu[tt].w); acc[7] += bhi(uu[tt].w);
                    }
                }
            }
        }
    }

    // combine quarters: lanes {f, f+16, f+32, f+48} hold partial sums
    #pragma unroll
    for (int k = 0; k < 8; ++k) {
        acc[k] += __shfl_xor(acc[k], 16);
        acc[k] += __shfl_xor(acc[k], 32);
    }

    unsigned h[8];
    #pragma unroll
    for (int k = 0; k < 8; ++k) h[k] = f2bf(acc[k]);
    if (q == 0) {
        uint4 w = { h[0] | (h[1] << 16), h[2] | (h[3] << 16),
                    h[4] | (h[5] << 16), h[6] | (h[7] << 16) };
        *(uint4*)(Ahi + (size_t)i * 64 + 4 * f) = w;
    } else if (q == 1) {
        unsigned l[8];
        #pragma unroll
        for (int k = 0; k < 8; ++k) l[k] = f2bf(acc[k] - bf2f(h[k]));
        uint4 w = { l[0] | (l[1] << 16), l[2] | (l[3] << 16),
                    l[4] | (l[5] << 16), l[6] | (l[7] << 16) };
        *(uint4*)(Alo + (size_t)i * 64 + 4 * f) = w;
    }
}

// ---------------- MFMA GEMM, split-precision bf16 (3-mfma ~ fp32 accuracy) -----

template<bool LAYER0>
__global__ __launch_bounds__(256) void gemm_kernel(
    const unsigned* __restrict__ Ahi_g, const unsigned* __restrict__ Alo_g,
    const float* __restrict__ W, const float* __restrict__ bias,
    const float* __restrict__ norm_s, const float* __restrict__ norm_d,
    const float* __restrict__ gamma, const float* __restrict__ beta,
    const float* __restrict__ rmean, const float* __restrict__ rvar,
    float* __restrict__ outf, unsigned short* __restrict__ outb)
{
    __shared__ unsigned lhi[64 * 68];   // 64 rows x 136 bf16 (pad 8)
    __shared__ unsigned llo[64 * 68];

    const int w    = threadIdx.x >> 6;
    const int lane = threadIdx.x & 63;
    const int quad = lane >> 4;
    const int l16  = lane & 15;

    // ---- B fragments (hi/lo) for this wave's 2 col-tiles, all K ----
    v8s Bhi[2][4], Blo[2][4];
    int col[2];
    #pragma unroll
    for (int ct = 0; ct < 2; ++ct) {
        col[ct] = 32 * w + 16 * ct + l16;
        #pragma unroll
        for (int q = 0; q < 4; ++q) {
            int kb = 32 * q + quad * 8;
            v8s hi8, lo8;
            #pragma unroll
            for (int kk = 0; kk < 8; ++kk) {
                float wv = W[(kb + kk) * D + col[ct]];
                unsigned h = f2bf(wv);
                hi8[kk] = (short)h;
                lo8[kk] = (short)f2bf(wv - bf2f(h));
            }
            Bhi[ct][q] = hi8;
            Blo[ct][q] = lo8;
        }
    }

    float bcol[2], s[2] = {0.f, 0.f}, sh[2] = {0.f, 0.f};
    #pragma unroll
    for (int ct = 0; ct < 2; ++ct) {
        bcol[ct] = bias[col[ct]];
        if (LAYER0) {
            s[ct]  = gamma[col[ct]] * rsqrtf(rvar[col[ct]] + BNEPS);
            sh[ct] = beta[col[ct]] - rmean[col[ct]] * s[ct];
        }
    }

    for (int row0 = blockIdx.x * 64; row0 < NN; row0 += gridDim.x * 64) {
        __syncthreads();
        for (int idx = threadIdx.x; idx < 64 * 64; idx += 256) {
            int r = idx >> 6, cp = idx & 63;
            int rw = row0 + r;
            unsigned vh = 0, vl = 0;
            if (rw < NN) {
                vh = Ahi_g[(size_t)rw * 64 + cp];
                vl = Alo_g[(size_t)rw * 64 + cp];
            }
            lhi[r * 68 + cp] = vh;
            llo[r * 68 + cp] = vl;
        }
        __syncthreads();

        #pragma unroll
        for (int rt = 0; rt < 4; ++rt) {
            v4f acc0 = {0.f, 0.f, 0.f, 0.f};
            v4f acc1 = {0.f, 0.f, 0.f, 0.f};
            #pragma unroll
            for (int q = 0; q < 4; ++q) {
                const unsigned short* ph = (const unsigned short*)lhi
                    + (rt * 16 + l16) * 136 + q * 32 + quad * 8;
                const unsigned short* pl = (const unsigned short*)llo
                    + (rt * 16 + l16) * 136 + q * 32 + quad * 8;
                v8s ahi = *(const v8s*)ph;
                v8s alo = *(const v8s*)pl;
                acc0 = __builtin_amdgcn_mfma_f32_16x16x32_bf16(ahi, Bhi[0][q], acc0, 0, 0, 0);
                acc0 = __builtin_amdgcn_mfma_f32_16x16x32_bf16(alo, Bhi[0][q], acc0, 0, 0, 0);
                acc0 = __builtin_amdgcn_mfma_f32_16x16x32_bf16(ahi, Blo[0][q], acc0, 0, 0, 0);
                acc1 = __builtin_amdgcn_mfma_f32_16x16x32_bf16(ahi, Bhi[1][q], acc1, 0, 0, 0);
                acc1 = __builtin_amdgcn_mfma_f32_16x16x32_bf16(alo, Bhi[1][q], acc1, 0, 0, 0);
                acc1 = __builtin_amdgcn_mfma_f32_16x16x32_bf16(ahi, Blo[1][q], acc1, 0, 0, 0);
            }
            #pragma unroll
            for (int r = 0; r < 4; ++r) {
                int rw = row0 + rt * 16 + quad * 4 + r;
                if (rw >= NN) continue;
                float nd = norm_d[rw];
                float o0 = acc0[r] * nd + bcol[0];
                float o1 = acc1[r] * nd + bcol[1];
                if (LAYER0) {
                    o0 = o0 * s[0] + sh[0];
                    o1 = o1 * s[1] + sh[1];
                    o0 = o0 > 0.f ? o0 : LEAKY * o0;
                    o1 = o1 > 0.f ? o1 : LEAKY * o1;
                    float ns = norm_s[rw];
                    o0 *= ns; o1 *= ns;
                    outb[(size_t)rw * D + col[0]] = (unsigned short)f2bf(o0);
                    outb[(size_t)rw * D + col[1]] = (unsigned short)f2bf(o1);
                } else {
                    outf[(size_t)rw * D + col[0]] = o0;
                    outf[(size_t)rw * D + col[1]] = o1;
                }
            }
        }
    }
}

// ---------------- launch ----------------

extern "C" void kernel_launch(void* const* d_in, const int* in_sizes, int n_in,
                              void* d_out, int out_size, void* d_ws, size_t ws_size,
                              hipStream_t stream) {
    const float* x     = (const float*)d_in[0];
    const int*   src   = (const int*)d_in[1];
    const int*   dst   = (const int*)d_in[2];
    const float* W1    = (const float*)d_in[3];
    const float* b1    = (const float*)d_in[4];
    const float* W2    = (const float*)d_in[5];
    const float* b2    = (const float*)d_in[6];
    const float* gamma = (const float*)d_in[7];
    const float* beta  = (const float*)d_in[8];
    const float* rmean = (const float*)d_in[9];
    const float* rvar  = (const float*)d_in[10];
    float* out = (float*)d_out;

    // bf16 gather-source scratch lives in d_out's first half (dead once the
    // final GEMM overwrites all of d_out with fp32 results).
    unsigned* hb = (unsigned*)d_out;                    // NN*64 u32 = 25.6 MB

    // ws layout (4B units)
    unsigned* Ahi   = (unsigned*)d_ws;                  // NN*64 u32 (bf16 hi pairs)
    unsigned* Alo   = Ahi + (size_t)NN * 64;            // NN*64 u32 (bf16 lo pairs)
    float*    norm  = (float*)(Alo + (size_t)NN * 64);  // 2N f32
    int*      aux   = (int*)(norm + 2 * NN);            // N int slot (bsum2)
    int*      hist  = aux + NN;                         // B*G int; row[] aliases after scanC
    int*      offs  = hist + B * G;                     // B*G int
    int*      bsum  = offs + B * G;                     // B int
    int*      boffs = bsum + B;                         // B int (unused, layout keep)
    unsigned* ebuf  = (unsigned*)(boffs + B);           // NE u32
    float* norm_s = norm;
    float* norm_d = norm + NN;
    int*   row    = hist;                // aliases hist (dead after scanC)
    int*   bsum2  = aux;                 // B int

    // src-side scratch aliases the Ahi slot (dead until csr_agg writes it):
    int*      hist2 = (int*)Ahi;                        // B*G int
    int*      offs2 = hist2 + B * G;                    // B*G int
    unsigned* sbuf  = (unsigned*)(offs2 + B * G);       // NE u32  (total 8 MB < 25.6 MB)

    // counting sort by dst bucket + src-bucket scatter (no global atomics)
    hist_kernel<<<G, 1024, 0, stream>>>(src, dst, hist, hist2);
    scanA2<<<2 * NSB, 256, 0, stream>>>(hist, hist2, bsum, bsum2);
    scanC2<<<2 * NSB, 256, 0, stream>>>(hist, hist2, bsum, bsum2, offs, offs2);
    sort_kernel<<<G, 1024, 0, stream>>>(src, dst, offs, offs2, ebuf, sbuf);
    bucket_prep<<<B, 256, 0, stream>>>(offs, offs2, ebuf, sbuf, x, row,
                                       norm_s, norm_d, hb);

    const int AGG_BLOCKS = (NN + 3) / 4;
    const int GEMM_BLOCKS = 784;
    // layer 0: agg = selfloop + sum_e xs[src]  -> split bf16 hi/lo
    csr_agg<<<AGG_BLOCKS, 256, 0, stream>>>(row, (const int*)ebuf, hb, Ahi, Alo);
    gemm_kernel<true><<<GEMM_BLOCKS, 256, 0, stream>>>(Ahi, Alo, W1, b1,
                                                       norm_s, norm_d,
                                                       gamma, beta, rmean, rvar,
                                                       nullptr, (unsigned short*)hb);
    // layer 1: gather source = bf16 hs (norm_src folded)
    csr_agg<<<AGG_BLOCKS, 256, 0, stream>>>(row, (const int*)ebuf, hb, Ahi, Alo);
    gemm_kernel<false><<<GEMM_BLOCKS, 256, 0, stream>>>(Ahi, Alo, W2, b2,
                                                        norm_s, norm_d,
                                                        nullptr, nullptr, nullptr, nullptr,
                                                        out, nullptr);
}

// Round 8
// 399.322 us; speedup vs baseline: 1.3534x; 1.0488x over previous
//
#include <hip/hip_runtime.h>

#define NN 100000
#define NE 1600000
#define D 128
#define LEAKY 0.01f
#define BNEPS 1e-5f

#define G 256        // sort groups (workgroups)
#define CHUNK 6250   // NE / G exactly
#define B 782        // ceil(NN/128) buckets (128 nodes each)
#define BSHIFT 7
#define BMASK 127
#define NSB (B * G / 256)   // 782 scan blocks per histogram

typedef short v8s __attribute__((ext_vector_type(8)));
typedef float v4f __attribute__((ext_vector_type(4)));

// round-to-nearest-even f32 -> bf16 (returns low 16 bits)
__device__ __forceinline__ unsigned f2bf(float f) {
    unsigned u = __float_as_uint(f);
    return (u + 0x7fffu + ((u >> 16) & 1u)) >> 16;
}
__device__ __forceinline__ float bf2f(unsigned h) {
    return __uint_as_float(h << 16);
}

// ---------------- counting sort by dst bucket + src bucket ---------------------

__global__ __launch_bounds__(1024) void hist_kernel(const int* __restrict__ src,
                                                    const int* __restrict__ dst,
                                                    int* __restrict__ hist,
                                                    int* __restrict__ hist2) {
    __shared__ int h[B];
    __shared__ int h2[B];
    for (int i = threadIdx.x; i < B; i += 1024) { h[i] = 0; h2[i] = 0; }
    __syncthreads();
    int g = blockIdx.x;
    const int* dp = dst + g * CHUNK;
    const int* sp = src + g * CHUNK;
    for (int k = threadIdx.x; k < CHUNK; k += 1024) {
        atomicAdd(&h[dp[k] >> BSHIFT], 1);
        atomicAdd(&h2[sp[k] >> BSHIFT], 1);
    }
    __syncthreads();
    for (int i = threadIdx.x; i < B; i += 1024) {
        hist[i * G + g]  = h[i];
        hist2[i * G + g] = h2[i];
    }
}

__global__ void scanA2(const int* __restrict__ a, const int* __restrict__ a2,
                       int* __restrict__ bsum, int* __restrict__ bsum2) {
    __shared__ int sm[256];
    int t = threadIdx.x;
    bool second = blockIdx.x >= NSB;
    int blk = second ? blockIdx.x - NSB : blockIdx.x;
    const int* sp = second ? a2 : a;
    sm[t] = sp[blk * 256 + t];
    __syncthreads();
    for (int s = 128; s > 0; s >>= 1) {
        if (t < s) sm[t] += sm[t + s];
        __syncthreads();
    }
    if (t == 0) (second ? bsum2 : bsum)[blk] = sm[0];
}

// scanB folded in — each block derives its own offset from bsum
// (<=4 loads/thread + LDS reduce), removing the serial 1-block scanB2 launch.
__global__ void scanC2(const int* __restrict__ a, const int* __restrict__ a2,
                       const int* __restrict__ bsum, const int* __restrict__ bsum2,
                       int* __restrict__ offs, int* __restrict__ offs2) {
    __shared__ int sm[256];
    __shared__ int bo;
    int t = threadIdx.x;
    bool second = blockIdx.x >= NSB;
    int blk = second ? blockIdx.x - NSB : blockIdx.x;
    const int* sp = second ? a2 : a;
    const int* bs = second ? bsum2 : bsum;
    int part = 0;
    for (int j = t; j < blk; j += 256) part += bs[j];
    sm[t] = part;
    __syncthreads();
    for (int s = 128; s > 0; s >>= 1) {
        if (t < s) sm[t] += sm[t + s];
        __syncthreads();
    }
    if (t == 0) bo = sm[0];
    __syncthreads();
    int i = blk * 256 + t;
    int v = sp[i];
    sm[t] = v;
    __syncthreads();
    for (int off = 1; off < 256; off <<= 1) {
        int x = (t >= off) ? sm[t - off] : 0;
        __syncthreads();
        sm[t] += x;
        __syncthreads();
    }
    (second ? offs2 : offs)[i] = bo + sm[t] - v;    // exclusive
}

__global__ __launch_bounds__(1024) void sort_kernel(const int* __restrict__ src,
                                                    const int* __restrict__ dst,
                                                    const int* __restrict__ offs,
                                                    const int* __restrict__ offs2,
                                                    unsigned* __restrict__ ebuf,
                                                    unsigned* __restrict__ sbuf) {
    __shared__ int cur[B];
    __shared__ int cur2[B];
    int g = blockIdx.x;
    for (int i = threadIdx.x; i < B; i += 1024) {
        cur[i]  = offs[i * G + g];
        cur2[i] = offs2[i * G + g];
    }
    __syncthreads();
    const int* sp = src + g * CHUNK;
    const int* dp = dst + g * CHUNK;
    for (int k = threadIdx.x; k < CHUNK; k += 1024) {
        int d = dp[k], s = sp[k];
        int pos = atomicAdd(&cur[d >> BSHIFT], 1);
        ebuf[pos] = ((unsigned)(d & BMASK) << 17) | (unsigned)s;   // src < 2^17
        int pos2 = atomicAdd(&cur2[s >> BSHIFT], 1);
        sbuf[pos2] = (unsigned)s;
    }
}

// ---------------- bucket_prep: (out-deg + conv) then (local sort -> CSR) -------

__global__ __launch_bounds__(256) void bucket_prep(
    const int* __restrict__ offs, const int* __restrict__ offs2,
    unsigned* __restrict__ ebuf, const unsigned* __restrict__ sbuf,
    const float* __restrict__ x, int* __restrict__ row,
    float* __restrict__ norm_s, float* __restrict__ norm_d,
    unsigned* __restrict__ hb)
{
    __shared__ int cnt[128];
    __shared__ int sc[128];
    __shared__ float nsm[128];
    const int b = blockIdx.x;
    const int t = threadIdx.x;

    // ---- part 1: out-degree count + norm_s + x*norm_s -> bf16 hb ----
    {
        const int s = offs2[b * G];
        const int e = (b == B - 1) ? NE : offs2[(b + 1) * G];
        if (t < 128) cnt[t] = 0;
        __syncthreads();
        for (int k = s + t; k < e; k += 256)
            atomicAdd(&cnt[sbuf[k] & BMASK], 1);
        __syncthreads();
        if (t < 128) {
            int node = b * 128 + t;
            if (node < NN) {
                float ns = rsqrtf((float)(cnt[t] + 1));   // +1 = self-loop
                norm_s[node] = ns;
                nsm[t] = ns;
            }
        }
        __syncthreads();
        for (int idx = t; idx < 128 * 32; idx += 256) {
            int r = idx >> 5, q = idx & 31;
            int node = b * 128 + r;
            if (node >= NN) continue;
            float ns = nsm[r];
            float4 v = ((const float4*)x)[(size_t)node * 32 + q];
            uint2 w;
            w.x = f2bf(v.x * ns) | (f2bf(v.y * ns) << 16);
            w.y = f2bf(v.z * ns) | (f2bf(v.w * ns) << 16);
            *(uint2*)(hb + (size_t)node * 64 + 2 * q) = w;
        }
    }
    __syncthreads();

    // ---- part 2: per-bucket local sort: bucket order -> per-node CSR ----
    {
        const int s = offs[b * G];
        const int e = (b == B - 1) ? NE : offs[(b + 1) * G];
        if (t < 128) cnt[t] = 0;
        __syncthreads();

        unsigned ent[16];   // 16*256 = 4096 capacity; bucket mean 2048, sd ~45
        int nent = 0;
        for (int k = s + t; k < e && nent < 16; k += 256) {
            unsigned u = ebuf[k];
            ent[nent++] = u;
            atomicAdd(&cnt[u >> 17], 1);
        }
        __syncthreads();

        if (t < 128) sc[t] = cnt[t];
        __syncthreads();
        for (int off = 1; off < 128; off <<= 1) {
            int v = 0;
            if (t < 128 && t >= off) v = sc[t - off];
            __syncthreads();
            if (t < 128) sc[t] += v;
            __syncthreads();
        }
        if (t < 128) {
            int st = s + sc[t] - cnt[t];   // exclusive start
            int node = b * 128 + t;
            if (node < NN) {
                row[node] = st;
                norm_d[node] = rsqrtf((float)(cnt[t] + 1));
            }
            cnt[t] = st;                   // becomes cursor
        }
        if (b == B - 1 && t == 0) row[NN] = NE;
        __syncthreads();

        for (int i = 0; i < nent; ++i) {
            unsigned u = ent[i];
            int pos = atomicAdd(&cnt[u >> 17], 1);
            ebuf[pos] = u & 0x1FFFFu;      // strip bucket bits -> plain src id
        }
    }
}

// ---------------- CSR gather-aggregate over bf16 rows, fp32 accumulate --------
// Round-8: exact revert to the round-6 structure (proven 63.5 us, VGPR 32,
// occ 72%). Rounds 5 & 7 proved any structure adding live registers or
// branches to the 8-deep uint2 load batch loses more from occupancy/issue
// than it gains in MLP. n is wave-uniform: full 16-edge blocks run
// unpredicated/unclamped; single masked tail block.

__global__ __launch_bounds__(256) void csr_agg(
    const int* __restrict__ rowp, const int* __restrict__ csr,
    const unsigned* __restrict__ hp,
    unsigned* __restrict__ Ahi, unsigned* __restrict__ Alo)
{
    int i = blockIdx.x * 4 + (threadIdx.x >> 6);
    if (i >= NN) return;
    const int lane = threadIdx.x & 63;
    const int half = lane >> 5;     // 0: even edges, 1: odd edges
    const int c2   = lane & 31;     // u32 column pair [2c2, 2c2+1]

    float4 acc = {0.f, 0.f, 0.f, 0.f};
    if (half == 0) {                // self-loop row counted once
        uint2 u = *(const uint2*)(hp + (size_t)i * 64 + 2 * c2);
        acc.x = __uint_as_float(u.x << 16);
        acc.y = __uint_as_float(u.x & 0xffff0000u);
        acc.z = __uint_as_float(u.y << 16);
        acc.w = __uint_as_float(u.y & 0xffff0000u);
    }

    int start = rowp[i], end = rowp[i + 1];
    for (int base = start; base < end; base += 64) {
        int n = end - base; if (n > 64) n = 64;
        int sv = csr[base + (lane < n ? lane : n - 1)];
        int nfull = n & ~15;
        int j = 0;
        // full blocks: unpredicated, unclamped
        for (; j < nfull; j += 16) {
            int ss[8]; uint2 uu[8];
            #pragma unroll
            for (int t = 0; t < 8; ++t) ss[t] = __shfl(sv, j + 2 * t + half);
            #pragma unroll
            for (int t = 0; t < 8; ++t)
                uu[t] = *(const uint2*)(hp + (size_t)ss[t] * 64 + 2 * c2);
            #pragma unroll
            for (int t = 0; t < 8; ++t) {
                acc.x += __uint_as_float(uu[t].x << 16);
                acc.y += __uint_as_float(uu[t].x & 0xffff0000u);
                acc.z += __uint_as_float(uu[t].y << 16);
                acc.w += __uint_as_float(uu[t].y & 0xffff0000u);
            }
        }
        // single masked tail block
        if (j < n) {
            int ss[8]; uint2 uu[8];
            #pragma unroll
            for (int t = 0; t < 8; ++t) {
                int e = j + 2 * t + half;
                ss[t] = __shfl(sv, e < n ? e : n - 1);
            }
            #pragma unroll
            for (int t = 0; t < 8; ++t)
                uu[t] = *(const uint2*)(hp + (size_t)ss[t] * 64 + 2 * c2);
            #pragma unroll
            for (int t = 0; t < 8; ++t) {
                if (j + 2 * t + half < n) {
                    acc.x += __uint_as_float(uu[t].x << 16);
                    acc.y += __uint_as_float(uu[t].x & 0xffff0000u);
                    acc.z += __uint_as_float(uu[t].y << 16);
                    acc.w += __uint_as_float(uu[t].y & 0xffff0000u);
                }
            }
        }
    }

    // combine halves: both sides end with the full sum
    acc.x += __shfl_xor(acc.x, 32);
    acc.y += __shfl_xor(acc.y, 32);
    acc.z += __shfl_xor(acc.z, 32);
    acc.w += __shfl_xor(acc.w, 32);

    unsigned h0 = f2bf(acc.x), h1 = f2bf(acc.y);
    unsigned h2 = f2bf(acc.z), h3 = f2bf(acc.w);
    if (half == 0) {
        uint2 w = { h0 | (h1 << 16), h2 | (h3 << 16) };
        *(uint2*)(Ahi + (size_t)i * 64 + 2 * c2) = w;
    } else {
        float l0 = acc.x - bf2f(h0), l1 = acc.y - bf2f(h1);
        float l2 = acc.z - bf2f(h2), l3 = acc.w - bf2f(h3);
        uint2 w = { f2bf(l0) | (f2bf(l1) << 16), f2bf(l2) | (f2bf(l3) << 16) };
        *(uint2*)(Alo + (size_t)i * 64 + 2 * c2) = w;
    }
}

// ---------------- MFMA GEMM, split-precision bf16 (3-mfma ~ fp32 accuracy) -----

template<bool LAYER0>
__global__ __launch_bounds__(256) void gemm_kernel(
    const unsigned* __restrict__ Ahi_g, const unsigned* __restrict__ Alo_g,
    const float* __restrict__ W, const float* __restrict__ bias,
    const float* __restrict__ norm_s, const float* __restrict__ norm_d,
    const float* __restrict__ gamma, const float* __restrict__ beta,
    const float* __restrict__ rmean, const float* __restrict__ rvar,
    float* __restrict__ outf, unsigned short* __restrict__ outb)
{
    __shared__ unsigned lhi[64 * 68];   // 64 rows x 136 bf16 (pad 8)
    __shared__ unsigned llo[64 * 68];

    const int w    = threadIdx.x >> 6;
    const int lane = threadIdx.x & 63;
    const int quad = lane >> 4;
    const int l16  = lane & 15;

    // ---- B fragments (hi/lo) for this wave's 2 col-tiles, all K ----
    v8s Bhi[2][4], Blo[2][4];
    int col[2];
    #pragma unroll
    for (int ct = 0; ct < 2; ++ct) {
        col[ct] = 32 * w + 16 * ct + l16;
        #pragma unroll
        for (int q = 0; q < 4; ++q) {
            int kb = 32 * q + quad * 8;
            v8s hi8, lo8;
            #pragma unroll
            for (int kk = 0; kk < 8; ++kk) {
                float wv = W[(kb + kk) * D + col[ct]];
                unsigned h = f2bf(wv);
                hi8[kk] = (short)h;
                lo8[kk] = (short)f2bf(wv - bf2f(h));
            }
            Bhi[ct][q] = hi8;
            Blo[ct][q] = lo8;
        }
    }

    float bcol[2], s[2] = {0.f, 0.f}, sh[2] = {0.f, 0.f};
    #pragma unroll
    for (int ct = 0; ct < 2; ++ct) {
        bcol[ct] = bias[col[ct]];
        if (LAYER0) {
            s[ct]  = gamma[col[ct]] * rsqrtf(rvar[col[ct]] + BNEPS);
            sh[ct] = beta[col[ct]] - rmean[col[ct]] * s[ct];
        }
    }

    for (int row0 = blockIdx.x * 64; row0 < NN; row0 += gridDim.x * 64) {
        __syncthreads();
        for (int idx = threadIdx.x; idx < 64 * 64; idx += 256) {
            int r = idx >> 6, cp = idx & 63;
            int rw = row0 + r;
            unsigned vh = 0, vl = 0;
            if (rw < NN) {
                vh = Ahi_g[(size_t)rw * 64 + cp];
                vl = Alo_g[(size_t)rw * 64 + cp];
            }
            lhi[r * 68 + cp] = vh;
            llo[r * 68 + cp] = vl;
        }
        __syncthreads();

        #pragma unroll
        for (int rt = 0; rt < 4; ++rt) {
            v4f acc0 = {0.f, 0.f, 0.f, 0.f};
            v4f acc1 = {0.f, 0.f, 0.f, 0.f};
            #pragma unroll
            for (int q = 0; q < 4; ++q) {
                const unsigned short* ph = (const unsigned short*)lhi
                    + (rt * 16 + l16) * 136 + q * 32 + quad * 8;
                const unsigned short* pl = (const unsigned short*)llo
                    + (rt * 16 + l16) * 136 + q * 32 + quad * 8;
                v8s ahi = *(const v8s*)ph;
                v8s alo = *(const v8s*)pl;
                acc0 = __builtin_amdgcn_mfma_f32_16x16x32_bf16(ahi, Bhi[0][q], acc0, 0, 0, 0);
                acc0 = __builtin_amdgcn_mfma_f32_16x16x32_bf16(alo, Bhi[0][q], acc0, 0, 0, 0);
                acc0 = __builtin_amdgcn_mfma_f32_16x16x32_bf16(ahi, Blo[0][q], acc0, 0, 0, 0);
                acc1 = __builtin_amdgcn_mfma_f32_16x16x32_bf16(ahi, Bhi[1][q], acc1, 0, 0, 0);
                acc1 = __builtin_amdgcn_mfma_f32_16x16x32_bf16(alo, Bhi[1][q], acc1, 0, 0, 0);
                acc1 = __builtin_amdgcn_mfma_f32_16x16x32_bf16(ahi, Blo[1][q], acc1, 0, 0, 0);
            }
            #pragma unroll
            for (int r = 0; r < 4; ++r) {
                int rw = row0 + rt * 16 + quad * 4 + r;
                if (rw >= NN) continue;
                float nd = norm_d[rw];
                float o0 = acc0[r] * nd + bcol[0];
                float o1 = acc1[r] * nd + bcol[1];
                if (LAYER0) {
                    o0 = o0 * s[0] + sh[0];
                    o1 = o1 * s[1] + sh[1];
                    o0 = o0 > 0.f ? o0 : LEAKY * o0;
                    o1 = o1 > 0.f ? o1 : LEAKY * o1;
                    float ns = norm_s[rw];
                    o0 *= ns; o1 *= ns;
                    outb[(size_t)rw * D + col[0]] = (unsigned short)f2bf(o0);
                    outb[(size_t)rw * D + col[1]] = (unsigned short)f2bf(o1);
                } else {
                    outf[(size_t)rw * D + col[0]] = o0;
                    outf[(size_t)rw * D + col[1]] = o1;
                }
            }
        }
    }
}

// ---------------- launch ----------------

extern "C" void kernel_launch(void* const* d_in, const int* in_sizes, int n_in,
                              void* d_out, int out_size, void* d_ws, size_t ws_size,
                              hipStream_t stream) {
    const float* x     = (const float*)d_in[0];
    const int*   src   = (const int*)d_in[1];
    const int*   dst   = (const int*)d_in[2];
    const float* W1    = (const float*)d_in[3];
    const float* b1    = (const float*)d_in[4];
    const float* W2    = (const float*)d_in[5];
    const float* b2    = (const float*)d_in[6];
    const float* gamma = (const float*)d_in[7];
    const float* beta  = (const float*)d_in[8];
    const float* rmean = (const float*)d_in[9];
    const float* rvar  = (const float*)d_in[10];
    float* out = (float*)d_out;

    // bf16 gather-source scratch lives in d_out's first half (dead once the
    // final GEMM overwrites all of d_out with fp32 results).
    unsigned* hb = (unsigned*)d_out;                    // NN*64 u32 = 25.6 MB

    // ws layout (4B units)
    unsigned* Ahi   = (unsigned*)d_ws;                  // NN*64 u32 (bf16 hi pairs)
    unsigned* Alo   = Ahi + (size_t)NN * 64;            // NN*64 u32 (bf16 lo pairs)
    float*    norm  = (float*)(Alo + (size_t)NN * 64);  // 2N f32
    int*      aux   = (int*)(norm + 2 * NN);            // N int slot (bsum2)
    int*      hist  = aux + NN;                         // B*G int; row[] aliases after scanC
    int*      offs  = hist + B * G;                     // B*G int
    int*      bsum  = offs + B * G;                     // B int
    int*      boffs = bsum + B;                         // B int (unused, layout keep)
    unsigned* ebuf  = (unsigned*)(boffs + B);           // NE u32
    float* norm_s = norm;
    float* norm_d = norm + NN;
    int*   row    = hist;                // aliases hist (dead after scanC)
    int*   bsum2  = aux;                 // B int

    // src-side scratch aliases the Ahi slot (dead until csr_agg writes it):
    int*      hist2 = (int*)Ahi;                        // B*G int
    int*      offs2 = hist2 + B * G;                    // B*G int
    unsigned* sbuf  = (unsigned*)(offs2 + B * G);       // NE u32  (total 8 MB < 25.6 MB)

    // counting sort by dst bucket + src-bucket scatter (no global atomics)
    hist_kernel<<<G, 1024, 0, stream>>>(src, dst, hist, hist2);
    scanA2<<<2 * NSB, 256, 0, stream>>>(hist, hist2, bsum, bsum2);
    scanC2<<<2 * NSB, 256, 0, stream>>>(hist, hist2, bsum, bsum2, offs, offs2);
    sort_kernel<<<G, 1024, 0, stream>>>(src, dst, offs, offs2, ebuf, sbuf);
    bucket_prep<<<B, 256, 0, stream>>>(offs, offs2, ebuf, sbuf, x, row,
                                       norm_s, norm_d, hb);

    const int AGG_BLOCKS = (NN + 3) / 4;
    const int GEMM_BLOCKS = 784;
    // layer 0: agg = selfloop + sum_e xs[src]  -> split bf16 hi/lo
    csr_agg<<<AGG_BLOCKS, 256, 0, stream>>>(row, (const int*)ebuf, hb, Ahi, Alo);
    gemm_kernel<true><<<GEMM_BLOCKS, 256, 0, stream>>>(Ahi, Alo, W1, b1,
                                                       norm_s, norm_d,
                                                       gamma, beta, rmean, rvar,
                                                       nullptr, (unsigned short*)hb);
    // layer 1: gather source = bf16 hs (norm_src folded)
    csr_agg<<<AGG_BLOCKS, 256, 0, stream>>>(row, (const int*)ebuf, hb, Ahi, Alo);
    gemm_kernel<false><<<GEMM_BLOCKS, 256, 0, stream>>>(Ahi, Alo, W2, b2,
                                                        norm_s, norm_d,
                                                        nullptr, nullptr, nullptr, nullptr,
                                                        out, nullptr);
}

// Round 9
// 399.232 us; speedup vs baseline: 1.3537x; 1.0002x over previous
//
#include <hip/hip_runtime.h>

#define NN 100000
#define NE 1600000
#define D 128
#define LEAKY 0.01f
#define BNEPS 1e-5f

#define GS 128        // sort groups (round-9: 256->128, full-line scatter runs)
#define CHUNK 12500   // NE / GS exactly
#define B 782         // ceil(NN/128) buckets (128 nodes each)
#define BSHIFT 7
#define BMASK 127
#define NSB (B * GS / 256)   // 391 scan blocks per histogram (100096/256)

typedef short v8s __attribute__((ext_vector_type(8)));
typedef float v4f __attribute__((ext_vector_type(4)));

// round-to-nearest-even f32 -> bf16 (returns low 16 bits)
__device__ __forceinline__ unsigned f2bf(float f) {
    unsigned u = __float_as_uint(f);
    return (u + 0x7fffu + ((u >> 16) & 1u)) >> 16;
}
__device__ __forceinline__ float bf2f(unsigned h) {
    return __uint_as_float(h << 16);
}

// ---------------- counting sort by dst bucket + src bucket ---------------------
// Round-9: GS=128. Scatter runs per (bucket,block) double to ~16 entries = one
// full 64B line -> one XCD writes one line once (was: ~8-entry 32B runs shared
// across XCDs, each XCD flushing its partial dirty copy). sbuf stores only the
// within-bucket id (7 bits) -> 1 byte/edge instead of 4.

__global__ __launch_bounds__(1024) void hist_kernel(const int* __restrict__ src,
                                                    const int* __restrict__ dst,
                                                    int* __restrict__ hist,
                                                    int* __restrict__ hist2) {
    __shared__ int h[B];
    __shared__ int h2[B];
    for (int i = threadIdx.x; i < B; i += 1024) { h[i] = 0; h2[i] = 0; }
    __syncthreads();
    int g = blockIdx.x;
    const int* dp = dst + g * CHUNK;
    const int* sp = src + g * CHUNK;
    for (int k = threadIdx.x; k < CHUNK; k += 1024) {
        atomicAdd(&h[dp[k] >> BSHIFT], 1);
        atomicAdd(&h2[sp[k] >> BSHIFT], 1);
    }
    __syncthreads();
    for (int i = threadIdx.x; i < B; i += 1024) {
        hist[i * GS + g]  = h[i];
        hist2[i * GS + g] = h2[i];
    }
}

__global__ void scanA2(const int* __restrict__ a, const int* __restrict__ a2,
                       int* __restrict__ bsum, int* __restrict__ bsum2) {
    __shared__ int sm[256];
    int t = threadIdx.x;
    bool second = blockIdx.x >= NSB;
    int blk = second ? blockIdx.x - NSB : blockIdx.x;
    const int* sp = second ? a2 : a;
    sm[t] = sp[blk * 256 + t];
    __syncthreads();
    for (int s = 128; s > 0; s >>= 1) {
        if (t < s) sm[t] += sm[t + s];
        __syncthreads();
    }
    if (t == 0) (second ? bsum2 : bsum)[blk] = sm[0];
}

// scanB folded in — each block derives its own offset from bsum
// (<=2 loads/thread + LDS reduce), no serial 1-block scan launch.
__global__ void scanC2(const int* __restrict__ a, const int* __restrict__ a2,
                       const int* __restrict__ bsum, const int* __restrict__ bsum2,
                       int* __restrict__ offs, int* __restrict__ offs2) {
    __shared__ int sm[256];
    __shared__ int bo;
    int t = threadIdx.x;
    bool second = blockIdx.x >= NSB;
    int blk = second ? blockIdx.x - NSB : blockIdx.x;
    const int* sp = second ? a2 : a;
    const int* bs = second ? bsum2 : bsum;
    int part = 0;
    for (int j = t; j < blk; j += 256) part += bs[j];
    sm[t] = part;
    __syncthreads();
    for (int s = 128; s > 0; s >>= 1) {
        if (t < s) sm[t] += sm[t + s];
        __syncthreads();
    }
    if (t == 0) bo = sm[0];
    __syncthreads();
    int i = blk * 256 + t;
    int v = sp[i];
    sm[t] = v;
    __syncthreads();
    for (int off = 1; off < 256; off <<= 1) {
        int x = (t >= off) ? sm[t - off] : 0;
        __syncthreads();
        sm[t] += x;
        __syncthreads();
    }
    (second ? offs2 : offs)[i] = bo + sm[t] - v;    // exclusive
}

__global__ __launch_bounds__(1024) void sort_kernel(const int* __restrict__ src,
                                                    const int* __restrict__ dst,
                                                    const int* __restrict__ offs,
                                                    const int* __restrict__ offs2,
                                                    unsigned* __restrict__ ebuf,
                                                    unsigned char* __restrict__ sbuf8) {
    __shared__ int cur[B];
    __shared__ int cur2[B];
    int g = blockIdx.x;
    for (int i = threadIdx.x; i < B; i += 1024) {
        cur[i]  = offs[i * GS + g];
        cur2[i] = offs2[i * GS + g];
    }
    __syncthreads();
    const int* sp = src + g * CHUNK;
    const int* dp = dst + g * CHUNK;
    for (int k = threadIdx.x; k < CHUNK; k += 1024) {
        int d = dp[k], s = sp[k];
        int pos = atomicAdd(&cur[d >> BSHIFT], 1);
        ebuf[pos] = ((unsigned)(d & BMASK) << 17) | (unsigned)s;   // src < 2^17
        int pos2 = atomicAdd(&cur2[s >> BSHIFT], 1);
        sbuf8[pos2] = (unsigned char)(s & BMASK);   // within-bucket id only
    }
}

// ---------------- bucket_prep: (out-deg + conv) then (local sort -> CSR) -------

__global__ __launch_bounds__(256) void bucket_prep(
    const int* __restrict__ offs, const int* __restrict__ offs2,
    unsigned* __restrict__ ebuf, const unsigned char* __restrict__ sbuf8,
    const float* __restrict__ x, int* __restrict__ row,
    float* __restrict__ norm_s, float* __restrict__ norm_d,
    unsigned* __restrict__ hb)
{
    __shared__ int cnt[128];
    __shared__ int sc[128];
    __shared__ float nsm[128];
    const int b = blockIdx.x;
    const int t = threadIdx.x;

    // ---- part 1: out-degree count + norm_s + x*norm_s -> bf16 hb ----
    {
        const int s = offs2[b * GS];
        const int e = (b == B - 1) ? NE : offs2[(b + 1) * GS];
        if (t < 128) cnt[t] = 0;
        __syncthreads();
        for (int k = s + t; k < e; k += 256)
            atomicAdd(&cnt[sbuf8[k]], 1);
        __syncthreads();
        if (t < 128) {
            int node = b * 128 + t;
            if (node < NN) {
                float ns = rsqrtf((float)(cnt[t] + 1));   // +1 = self-loop
                norm_s[node] = ns;
                nsm[t] = ns;
            }
        }
        __syncthreads();
        for (int idx = t; idx < 128 * 32; idx += 256) {
            int r = idx >> 5, q = idx & 31;
            int node = b * 128 + r;
            if (node >= NN) continue;
            float ns = nsm[r];
            float4 v = ((const float4*)x)[(size_t)node * 32 + q];
            uint2 w;
            w.x = f2bf(v.x * ns) | (f2bf(v.y * ns) << 16);
            w.y = f2bf(v.z * ns) | (f2bf(v.w * ns) << 16);
            *(uint2*)(hb + (size_t)node * 64 + 2 * q) = w;
        }
    }
    __syncthreads();

    // ---- part 2: per-bucket local sort: bucket order -> per-node CSR ----
    {
        const int s = offs[b * GS];
        const int e = (b == B - 1) ? NE : offs[(b + 1) * GS];
        if (t < 128) cnt[t] = 0;
        __syncthreads();

        unsigned ent[16];   // 16*256 = 4096 capacity; bucket mean 2048, sd ~45
        int nent = 0;
        for (int k = s + t; k < e && nent < 16; k += 256) {
            unsigned u = ebuf[k];
            ent[nent++] = u;
            atomicAdd(&cnt[u >> 17], 1);
        }
        __syncthreads();

        if (t < 128) sc[t] = cnt[t];
        __syncthreads();
        for (int off = 1; off < 128; off <<= 1) {
            int v = 0;
            if (t < 128 && t >= off) v = sc[t - off];
            __syncthreads();
            if (t < 128) sc[t] += v;
            __syncthreads();
        }
        if (t < 128) {
            int st = s + sc[t] - cnt[t];   // exclusive start
            int node = b * 128 + t;
            if (node < NN) {
                row[node] = st;
                norm_d[node] = rsqrtf((float)(cnt[t] + 1));
            }
            cnt[t] = st;                   // becomes cursor
        }
        if (b == B - 1 && t == 0) row[NN] = NE;
        __syncthreads();

        for (int i = 0; i < nent; ++i) {
            unsigned u = ent[i];
            int pos = atomicAdd(&cnt[u >> 17], 1);
            ebuf[pos] = u & 0x1FFFFu;      // strip bucket bits -> plain src id
        }
    }
}

// ---------------- CSR gather-aggregate over bf16 rows, fp32 accumulate --------
// Proven optimum (round 6/8): 8-deep uint2 batches, VGPR 32, occ 72%. n is
// wave-uniform: full 16-edge blocks unpredicated/unclamped; one masked tail.

__global__ __launch_bounds__(256) void csr_agg(
    const int* __restrict__ rowp, const int* __restrict__ csr,
    const unsigned* __restrict__ hp,
    unsigned* __restrict__ Ahi, unsigned* __restrict__ Alo)
{
    int i = blockIdx.x * 4 + (threadIdx.x >> 6);
    if (i >= NN) return;
    const int lane = threadIdx.x & 63;
    const int half = lane >> 5;     // 0: even edges, 1: odd edges
    const int c2   = lane & 31;     // u32 column pair [2c2, 2c2+1]

    float4 acc = {0.f, 0.f, 0.f, 0.f};
    if (half == 0) {                // self-loop row counted once
        uint2 u = *(const uint2*)(hp + (size_t)i * 64 + 2 * c2);
        acc.x = __uint_as_float(u.x << 16);
        acc.y = __uint_as_float(u.x & 0xffff0000u);
        acc.z = __uint_as_float(u.y << 16);
        acc.w = __uint_as_float(u.y & 0xffff0000u);
    }

    int start = rowp[i], end = rowp[i + 1];
    for (int base = start; base < end; base += 64) {
        int n = end - base; if (n > 64) n = 64;
        int sv = csr[base + (lane < n ? lane : n - 1)];
        int nfull = n & ~15;
        int j = 0;
        // full blocks: unpredicated, unclamped
        for (; j < nfull; j += 16) {
            int ss[8]; uint2 uu[8];
            #pragma unroll
            for (int t = 0; t < 8; ++t) ss[t] = __shfl(sv, j + 2 * t + half);
            #pragma unroll
            for (int t = 0; t < 8; ++t)
                uu[t] = *(const uint2*)(hp + (size_t)ss[t] * 64 + 2 * c2);
            #pragma unroll
            for (int t = 0; t < 8; ++t) {
                acc.x += __uint_as_float(uu[t].x << 16);
                acc.y += __uint_as_float(uu[t].x & 0xffff0000u);
                acc.z += __uint_as_float(uu[t].y << 16);
                acc.w += __uint_as_float(uu[t].y & 0xffff0000u);
            }
        }
        // single masked tail block
        if (j < n) {
            int ss[8]; uint2 uu[8];
            #pragma unroll
            for (int t = 0; t < 8; ++t) {
                int e = j + 2 * t + half;
                ss[t] = __shfl(sv, e < n ? e : n - 1);
            }
            #pragma unroll
            for (int t = 0; t < 8; ++t)
                uu[t] = *(const uint2*)(hp + (size_t)ss[t] * 64 + 2 * c2);
            #pragma unroll
            for (int t = 0; t < 8; ++t) {
                if (j + 2 * t + half < n) {
                    acc.x += __uint_as_float(uu[t].x << 16);
                    acc.y += __uint_as_float(uu[t].x & 0xffff0000u);
                    acc.z += __uint_as_float(uu[t].y << 16);
                    acc.w += __uint_as_float(uu[t].y & 0xffff0000u);
                }
            }
        }
    }

    // combine halves: both sides end with the full sum
    acc.x += __shfl_xor(acc.x, 32);
    acc.y += __shfl_xor(acc.y, 32);
    acc.z += __shfl_xor(acc.z, 32);
    acc.w += __shfl_xor(acc.w, 32);

    unsigned h0 = f2bf(acc.x), h1 = f2bf(acc.y);
    unsigned h2 = f2bf(acc.z), h3 = f2bf(acc.w);
    if (half == 0) {
        uint2 w = { h0 | (h1 << 16), h2 | (h3 << 16) };
        *(uint2*)(Ahi + (size_t)i * 64 + 2 * c2) = w;
    } else {
        float l0 = acc.x - bf2f(h0), l1 = acc.y - bf2f(h1);
        float l2 = acc.z - bf2f(h2), l3 = acc.w - bf2f(h3);
        uint2 w = { f2bf(l0) | (f2bf(l1) << 16), f2bf(l2) | (f2bf(l3) << 16) };
        *(uint2*)(Alo + (size_t)i * 64 + 2 * c2) = w;
    }
}

// ---------------- MFMA GEMM, split-precision bf16 (3-mfma ~ fp32 accuracy) -----

template<bool LAYER0>
__global__ __launch_bounds__(256) void gemm_kernel(
    const unsigned* __restrict__ Ahi_g, const unsigned* __restrict__ Alo_g,
    const float* __restrict__ W, const float* __restrict__ bias,
    const float* __restrict__ norm_s, const float* __restrict__ norm_d,
    const float* __restrict__ gamma, const float* __restrict__ beta,
    const float* __restrict__ rmean, const float* __restrict__ rvar,
    float* __restrict__ outf, unsigned short* __restrict__ outb)
{
    __shared__ unsigned lhi[64 * 68];   // 64 rows x 136 bf16 (pad 8)
    __shared__ unsigned llo[64 * 68];

    const int w    = threadIdx.x >> 6;
    const int lane = threadIdx.x & 63;
    const int quad = lane >> 4;
    const int l16  = lane & 15;

    // ---- B fragments (hi/lo) for this wave's 2 col-tiles, all K ----
    v8s Bhi[2][4], Blo[2][4];
    int col[2];
    #pragma unroll
    for (int ct = 0; ct < 2; ++ct) {
        col[ct] = 32 * w + 16 * ct + l16;
        #pragma unroll
        for (int q = 0; q < 4; ++q) {
            int kb = 32 * q + quad * 8;
            v8s hi8, lo8;
            #pragma unroll
            for (int kk = 0; kk < 8; ++kk) {
                float wv = W[(kb + kk) * D + col[ct]];
                unsigned h = f2bf(wv);
                hi8[kk] = (short)h;
                lo8[kk] = (short)f2bf(wv - bf2f(h));
            }
            Bhi[ct][q] = hi8;
            Blo[ct][q] = lo8;
        }
    }

    float bcol[2], s[2] = {0.f, 0.f}, sh[2] = {0.f, 0.f};
    #pragma unroll
    for (int ct = 0; ct < 2; ++ct) {
        bcol[ct] = bias[col[ct]];
        if (LAYER0) {
            s[ct]  = gamma[col[ct]] * rsqrtf(rvar[col[ct]] + BNEPS);
            sh[ct] = beta[col[ct]] - rmean[col[ct]] * s[ct];
        }
    }

    for (int row0 = blockIdx.x * 64; row0 < NN; row0 += gridDim.x * 64) {
        __syncthreads();
        for (int idx = threadIdx.x; idx < 64 * 64; idx += 256) {
            int r = idx >> 6, cp = idx & 63;
            int rw = row0 + r;
            unsigned vh = 0, vl = 0;
            if (rw < NN) {
                vh = Ahi_g[(size_t)rw * 64 + cp];
                vl = Alo_g[(size_t)rw * 64 + cp];
            }
            lhi[r * 68 + cp] = vh;
            llo[r * 68 + cp] = vl;
        }
        __syncthreads();

        #pragma unroll
        for (int rt = 0; rt < 4; ++rt) {
            v4f acc0 = {0.f, 0.f, 0.f, 0.f};
            v4f acc1 = {0.f, 0.f, 0.f, 0.f};
            #pragma unroll
            for (int q = 0; q < 4; ++q) {
                const unsigned short* ph = (const unsigned short*)lhi
                    + (rt * 16 + l16) * 136 + q * 32 + quad * 8;
                const unsigned short* pl = (const unsigned short*)llo
                    + (rt * 16 + l16) * 136 + q * 32 + quad * 8;
                v8s ahi = *(const v8s*)ph;
                v8s alo = *(const v8s*)pl;
                acc0 = __builtin_amdgcn_mfma_f32_16x16x32_bf16(ahi, Bhi[0][q], acc0, 0, 0, 0);
                acc0 = __builtin_amdgcn_mfma_f32_16x16x32_bf16(alo, Bhi[0][q], acc0, 0, 0, 0);
                acc0 = __builtin_amdgcn_mfma_f32_16x16x32_bf16(ahi, Blo[0][q], acc0, 0, 0, 0);
                acc1 = __builtin_amdgcn_mfma_f32_16x16x32_bf16(ahi, Bhi[1][q], acc1, 0, 0, 0);
                acc1 = __builtin_amdgcn_mfma_f32_16x16x32_bf16(alo, Bhi[1][q], acc1, 0, 0, 0);
                acc1 = __builtin_amdgcn_mfma_f32_16x16x32_bf16(ahi, Blo[1][q], acc1, 0, 0, 0);
            }
            #pragma unroll
            for (int r = 0; r < 4; ++r) {
                int rw = row0 + rt * 16 + quad * 4 + r;
                if (rw >= NN) continue;
                float nd = norm_d[rw];
                float o0 = acc0[r] * nd + bcol[0];
                float o1 = acc1[r] * nd + bcol[1];
                if (LAYER0) {
                    o0 = o0 * s[0] + sh[0];
                    o1 = o1 * s[1] + sh[1];
                    o0 = o0 > 0.f ? o0 : LEAKY * o0;
                    o1 = o1 > 0.f ? o1 : LEAKY * o1;
                    float ns = norm_s[rw];
                    o0 *= ns; o1 *= ns;
                    outb[(size_t)rw * D + col[0]] = (unsigned short)f2bf(o0);
                    outb[(size_t)rw * D + col[1]] = (unsigned short)f2bf(o1);
                } else {
                    outf[(size_t)rw * D + col[0]] = o0;
                    outf[(size_t)rw * D + col[1]] = o1;
                }
            }
        }
    }
}

// ---------------- launch ----------------

extern "C" void kernel_launch(void* const* d_in, const int* in_sizes, int n_in,
                              void* d_out, int out_size, void* d_ws, size_t ws_size,
                              hipStream_t stream) {
    const float* x     = (const float*)d_in[0];
    const int*   src   = (const int*)d_in[1];
    const int*   dst   = (const int*)d_in[2];
    const float* W1    = (const float*)d_in[3];
    const float* b1    = (const float*)d_in[4];
    const float* W2    = (const float*)d_in[5];
    const float* b2    = (const float*)d_in[6];
    const float* gamma = (const float*)d_in[7];
    const float* beta  = (const float*)d_in[8];
    const float* rmean = (const float*)d_in[9];
    const float* rvar  = (const float*)d_in[10];
    float* out = (float*)d_out;

    // bf16 gather-source scratch lives in d_out's first half (dead once the
    // final GEMM overwrites all of d_out with fp32 results).
    unsigned* hb = (unsigned*)d_out;                    // NN*64 u32 = 25.6 MB

    // ws layout (4B units)
    unsigned* Ahi   = (unsigned*)d_ws;                  // NN*64 u32 (bf16 hi pairs)
    unsigned* Alo   = Ahi + (size_t)NN * 64;            // NN*64 u32 (bf16 lo pairs)
    float*    norm  = (float*)(Alo + (size_t)NN * 64);  // 2N f32
    int*      aux   = (int*)(norm + 2 * NN);            // N int slot (bsum2)
    int*      hist  = aux + NN;                         // B*GS int; row[] aliases after scanC
    int*      offs  = hist + B * GS;                    // B*GS int
    int*      bsum  = offs + B * GS;                    // B int
    int*      boffs = bsum + B;                         // B int (unused, layout keep)
    unsigned* ebuf  = (unsigned*)(boffs + B);           // NE u32
    float* norm_s = norm;
    float* norm_d = norm + NN;
    int*   row    = hist;                // aliases hist (B*GS=100096 ints >= NN+1)
    int*   bsum2  = aux;                 // B int

    // src-side scratch aliases the Ahi slot (dead until csr_agg writes it):
    int*           hist2 = (int*)Ahi;                   // B*GS int
    int*           offs2 = hist2 + B * GS;              // B*GS int
    unsigned char* sbuf8 = (unsigned char*)(offs2 + B * GS);  // NE bytes (1.6 MB)

    // counting sort by dst bucket + src-bucket byte scatter (no global atomics)
    hist_kernel<<<GS, 1024, 0, stream>>>(src, dst, hist, hist2);
    scanA2<<<2 * NSB, 256, 0, stream>>>(hist, hist2, bsum, bsum2);
    scanC2<<<2 * NSB, 256, 0, stream>>>(hist, hist2, bsum, bsum2, offs, offs2);
    sort_kernel<<<GS, 1024, 0, stream>>>(src, dst, offs, offs2, ebuf, sbuf8);
    bucket_prep<<<B, 256, 0, stream>>>(offs, offs2, ebuf, sbuf8, x, row,
                                       norm_s, norm_d, hb);

    const int AGG_BLOCKS = (NN + 3) / 4;
    const int GEMM_BLOCKS = 784;
    // layer 0: agg = selfloop + sum_e xs[src]  -> split bf16 hi/lo
    csr_agg<<<AGG_BLOCKS, 256, 0, stream>>>(row, (const int*)ebuf, hb, Ahi, Alo);
    gemm_kernel<true><<<GEMM_BLOCKS, 256, 0, stream>>>(Ahi, Alo, W1, b1,
                                                       norm_s, norm_d,
                                                       gamma, beta, rmean, rvar,
                                                       nullptr, (unsigned short*)hb);
    // layer 1: gather source = bf16 hs (norm_src folded)
    csr_agg<<<AGG_BLOCKS, 256, 0, stream>>>(row, (const int*)ebuf, hb, Ahi, Alo);
    gemm_kernel<false><<<GEMM_BLOCKS, 256, 0, stream>>>(Ahi, Alo, W2, b2,
                                                        norm_s, norm_d,
                                                        nullptr, nullptr, nullptr, nullptr,
                                                        out, nullptr);
}

// Round 10
// 391.543 us; speedup vs baseline: 1.3803x; 1.0196x over previous
//
#include <hip/hip_runtime.h>

#define NN 100000
#define NE 1600000
#define D 128
#define LEAKY 0.01f
#define BNEPS 1e-5f

#define GS 256        // sort groups (full machine; round-9's GS=128 idled half the CUs)
#define CHUNK 6250    // NE / GS exactly
#define B 782         // ceil(NN/128) buckets (128 nodes each)
#define BSHIFT 7
#define BMASK 127
#define NSB (B * GS / 256)   // 782 scan blocks per histogram

typedef short v8s __attribute__((ext_vector_type(8)));
typedef float v4f __attribute__((ext_vector_type(4)));

// round-to-nearest-even f32 -> bf16 (returns low 16 bits)
__device__ __forceinline__ unsigned f2bf(float f) {
    unsigned u = __float_as_uint(f);
    return (u + 0x7fffu + ((u >> 16) & 1u)) >> 16;
}
__device__ __forceinline__ float bf2f(unsigned h) {
    return __uint_as_float(h << 16);
}

// ---------------- counting sort by dst bucket + src bucket ---------------------

__global__ __launch_bounds__(1024) void hist_kernel(const int* __restrict__ src,
                                                    const int* __restrict__ dst,
                                                    int* __restrict__ hist,
                                                    int* __restrict__ hist2) {
    __shared__ int h[B];
    __shared__ int h2[B];
    for (int i = threadIdx.x; i < B; i += 1024) { h[i] = 0; h2[i] = 0; }
    __syncthreads();
    int g = blockIdx.x;
    const int* dp = dst + g * CHUNK;
    const int* sp = src + g * CHUNK;
    for (int k = threadIdx.x; k < CHUNK; k += 1024) {
        atomicAdd(&h[dp[k] >> BSHIFT], 1);
        atomicAdd(&h2[sp[k] >> BSHIFT], 1);
    }
    __syncthreads();
    for (int i = threadIdx.x; i < B; i += 1024) {
        hist[i * GS + g]  = h[i];
        hist2[i * GS + g] = h2[i];
    }
}

__global__ void scanA2(const int* __restrict__ a, const int* __restrict__ a2,
                       int* __restrict__ bsum, int* __restrict__ bsum2) {
    __shared__ int sm[256];
    int t = threadIdx.x;
    bool second = blockIdx.x >= NSB;
    int blk = second ? blockIdx.x - NSB : blockIdx.x;
    const int* sp = second ? a2 : a;
    sm[t] = sp[blk * 256 + t];
    __syncthreads();
    for (int s = 128; s > 0; s >>= 1) {
        if (t < s) sm[t] += sm[t + s];
        __syncthreads();
    }
    if (t == 0) (second ? bsum2 : bsum)[blk] = sm[0];
}

// scanB folded in — each block derives its own offset from bsum
__global__ void scanC2(const int* __restrict__ a, const int* __restrict__ a2,
                       const int* __restrict__ bsum, const int* __restrict__ bsum2,
                       int* __restrict__ offs, int* __restrict__ offs2) {
    __shared__ int sm[256];
    __shared__ int bo;
    int t = threadIdx.x;
    bool second = blockIdx.x >= NSB;
    int blk = second ? blockIdx.x - NSB : blockIdx.x;
    const int* sp = second ? a2 : a;
    const int* bs = second ? bsum2 : bsum;
    int part = 0;
    for (int j = t; j < blk; j += 256) part += bs[j];
    sm[t] = part;
    __syncthreads();
    for (int s = 128; s > 0; s >>= 1) {
        if (t < s) sm[t] += sm[t + s];
        __syncthreads();
    }
    if (t == 0) bo = sm[0];
    __syncthreads();
    int i = blk * 256 + t;
    int v = sp[i];
    sm[t] = v;
    __syncthreads();
    for (int off = 1; off < 256; off <<= 1) {
        int x = (t >= off) ? sm[t - off] : 0;
        __syncthreads();
        sm[t] += x;
        __syncthreads();
    }
    (second ? offs2 : offs)[i] = bo + sm[t] - v;    // exclusive
}

// ---------------- sort: two-phase LDS-staged local counting sort --------------
// Round-10: the old direct scatter issued 1.6M isolated 4B stores (each its own
// memory transaction). Now each block counting-sorts its chunk in LDS, then
// writes each bucket's run with consecutive threads -> consecutive addresses
// (coalesced 32B+ stores). Payload unchanged. LDS 47.9 KB, 1 block/CU.

__global__ __launch_bounds__(1024) void sort_kernel(const int* __restrict__ src,
                                                    const int* __restrict__ dst,
                                                    const int* __restrict__ offs,
                                                    const int* __restrict__ offs2,
                                                    unsigned* __restrict__ ebuf,
                                                    unsigned char* __restrict__ sbuf8) {
    __shared__ unsigned      lbuf[CHUNK];       // 25000 B
    __shared__ unsigned char lbuf2[CHUNK];      //  6250 B
    __shared__ int lst [B + 1];                 // local exclusive starts (dst)
    __shared__ int lst2[B + 1];                 // local exclusive starts (src)
    __shared__ int cur [B];                     // cursors
    __shared__ int cur2[B];
    __shared__ int ss[1024];                    // scan scratch

    const int g = blockIdx.x;
    const int t = threadIdx.x;
    const int* sp = src + g * CHUNK;
    const int* dp = dst + g * CHUNK;

    // pass 1: local counts (reuse cur/cur2 as counters)
    for (int i = t; i < B; i += 1024) { cur[i] = 0; cur2[i] = 0; }
    __syncthreads();
    for (int k = t; k < CHUNK; k += 1024) {
        atomicAdd(&cur [dp[k] >> BSHIFT], 1);
        atomicAdd(&cur2[sp[k] >> BSHIFT], 1);
    }
    __syncthreads();

    // exclusive scan of cur -> lst  (Hillis-Steele over 1024, B=782 padded)
    {
        int v = (t < B) ? cur[t] : 0;
        ss[t] = v;
        __syncthreads();
        for (int off = 1; off < 1024; off <<= 1) {
            int x = (t >= off) ? ss[t - off] : 0;
            __syncthreads();
            ss[t] += x;
            __syncthreads();
        }
        if (t < B) lst[t] = ss[t] - v;
        if (t == 0) lst[B] = CHUNK;
    }
    __syncthreads();
    // exclusive scan of cur2 -> lst2
    {
        int v = (t < B) ? cur2[t] : 0;
        ss[t] = v;
        __syncthreads();
        for (int off = 1; off < 1024; off <<= 1) {
            int x = (t >= off) ? ss[t - off] : 0;
            __syncthreads();
            ss[t] += x;
            __syncthreads();
        }
        if (t < B) lst2[t] = ss[t] - v;
        if (t == 0) lst2[B] = CHUNK;
    }
    __syncthreads();
    // cursors = starts
    for (int i = t; i < B; i += 1024) { cur[i] = lst[i]; cur2[i] = lst2[i]; }
    __syncthreads();

    // pass 2: place into LDS (src/dst re-read, L2-hot)
    for (int k = t; k < CHUNK; k += 1024) {
        int d = dp[k], s = sp[k];
        int p  = atomicAdd(&cur [d >> BSHIFT], 1);
        lbuf[p] = ((unsigned)(d & BMASK) << 17) | (unsigned)s;   // src < 2^17
        int p2 = atomicAdd(&cur2[s >> BSHIFT], 1);
        lbuf2[p2] = (unsigned char)(s & BMASK);
    }
    __syncthreads();

    // write-out: consecutive idx -> consecutive global addresses within runs
    for (int idx = t; idx < CHUNK; idx += 1024) {
        // upper-bound search: b with lst[b] <= idx < lst[b+1]
        int lo = 0, hi = B;
        while (hi - lo > 1) { int mid = (lo + hi) >> 1; if (lst[mid] <= idx) lo = mid; else hi = mid; }
        ebuf[offs[lo * GS + g] + (idx - lst[lo])] = lbuf[idx];
    }
    for (int idx = t; idx < CHUNK; idx += 1024) {
        int lo = 0, hi = B;
        while (hi - lo > 1) { int mid = (lo + hi) >> 1; if (lst2[mid] <= idx) lo = mid; else hi = mid; }
        sbuf8[offs2[lo * GS + g] + (idx - lst2[lo])] = lbuf2[idx];
    }
}

// ---------------- bucket_prep: (out-deg + conv) then (local sort -> CSR) -------

__global__ __launch_bounds__(256) void bucket_prep(
    const int* __restrict__ offs, const int* __restrict__ offs2,
    unsigned* __restrict__ ebuf, const unsigned char* __restrict__ sbuf8,
    const float* __restrict__ x, int* __restrict__ row,
    float* __restrict__ norm_s, float* __restrict__ norm_d,
    unsigned* __restrict__ hb)
{
    __shared__ int cnt[128];
    __shared__ int sc[128];
    __shared__ float nsm[128];
    const int b = blockIdx.x;
    const int t = threadIdx.x;

    // ---- part 1: out-degree count + norm_s + x*norm_s -> bf16 hb ----
    {
        const int s = offs2[b * GS];
        const int e = (b == B - 1) ? NE : offs2[(b + 1) * GS];
        if (t < 128) cnt[t] = 0;
        __syncthreads();
        for (int k = s + t; k < e; k += 256)
            atomicAdd(&cnt[sbuf8[k]], 1);
        __syncthreads();
        if (t < 128) {
            int node = b * 128 + t;
            if (node < NN) {
                float ns = rsqrtf((float)(cnt[t] + 1));   // +1 = self-loop
                norm_s[node] = ns;
                nsm[t] = ns;
            }
        }
        __syncthreads();
        for (int idx = t; idx < 128 * 32; idx += 256) {
            int r = idx >> 5, q = idx & 31;
            int node = b * 128 + r;
            if (node >= NN) continue;
            float ns = nsm[r];
            float4 v = ((const float4*)x)[(size_t)node * 32 + q];
            uint2 w;
            w.x = f2bf(v.x * ns) | (f2bf(v.y * ns) << 16);
            w.y = f2bf(v.z * ns) | (f2bf(v.w * ns) << 16);
            *(uint2*)(hb + (size_t)node * 64 + 2 * q) = w;
        }
    }
    __syncthreads();

    // ---- part 2: per-bucket local sort: bucket order -> per-node CSR ----
    {
        const int s = offs[b * GS];
        const int e = (b == B - 1) ? NE : offs[(b + 1) * GS];
        if (t < 128) cnt[t] = 0;
        __syncthreads();

        unsigned ent[16];   // 16*256 = 4096 capacity; bucket mean 2048, sd ~45
        int nent = 0;
        for (int k = s + t; k < e && nent < 16; k += 256) {
            unsigned u = ebuf[k];
            ent[nent++] = u;
            atomicAdd(&cnt[u >> 17], 1);
        }
        __syncthreads();

        if (t < 128) sc[t] = cnt[t];
        __syncthreads();
        for (int off = 1; off < 128; off <<= 1) {
            int v = 0;
            if (t < 128 && t >= off) v = sc[t - off];
            __syncthreads();
            if (t < 128) sc[t] += v;
            __syncthreads();
        }
        if (t < 128) {
            int st = s + sc[t] - cnt[t];   // exclusive start
            int node = b * 128 + t;
            if (node < NN) {
                row[node] = st;
                norm_d[node] = rsqrtf((float)(cnt[t] + 1));
            }
            cnt[t] = st;                   // becomes cursor
        }
        if (b == B - 1 && t == 0) row[NN] = NE;
        __syncthreads();

        for (int i = 0; i < nent; ++i) {
            unsigned u = ent[i];
            int pos = atomicAdd(&cnt[u >> 17], 1);
            ebuf[pos] = u & 0x1FFFFu;      // strip bucket bits -> plain src id
        }
    }
}

// ---------------- CSR gather-aggregate over bf16 rows, fp32 accumulate --------
// Proven optimum (round 6/8): 8-deep uint2 batches, VGPR 32, occ 72%. n is
// wave-uniform: full 16-edge blocks unpredicated/unclamped; one masked tail.

__global__ __launch_bounds__(256) void csr_agg(
    const int* __restrict__ rowp, const int* __restrict__ csr,
    const unsigned* __restrict__ hp,
    unsigned* __restrict__ Ahi, unsigned* __restrict__ Alo)
{
    int i = blockIdx.x * 4 + (threadIdx.x >> 6);
    if (i >= NN) return;
    const int lane = threadIdx.x & 63;
    const int half = lane >> 5;     // 0: even edges, 1: odd edges
    const int c2   = lane & 31;     // u32 column pair [2c2, 2c2+1]

    float4 acc = {0.f, 0.f, 0.f, 0.f};
    if (half == 0) {                // self-loop row counted once
        uint2 u = *(const uint2*)(hp + (size_t)i * 64 + 2 * c2);
        acc.x = __uint_as_float(u.x << 16);
        acc.y = __uint_as_float(u.x & 0xffff0000u);
        acc.z = __uint_as_float(u.y << 16);
        acc.w = __uint_as_float(u.y & 0xffff0000u);
    }

    int start = rowp[i], end = rowp[i + 1];
    for (int base = start; base < end; base += 64) {
        int n = end - base; if (n > 64) n = 64;
        int sv = csr[base + (lane < n ? lane : n - 1)];
        int nfull = n & ~15;
        int j = 0;
        // full blocks: unpredicated, unclamped
        for (; j < nfull; j += 16) {
            int ss[8]; uint2 uu[8];
            #pragma unroll
            for (int t = 0; t < 8; ++t) ss[t] = __shfl(sv, j + 2 * t + half);
            #pragma unroll
            for (int t = 0; t < 8; ++t)
                uu[t] = *(const uint2*)(hp + (size_t)ss[t] * 64 + 2 * c2);
            #pragma unroll
            for (int t = 0; t < 8; ++t) {
                acc.x += __uint_as_float(uu[t].x << 16);
                acc.y += __uint_as_float(uu[t].x & 0xffff0000u);
                acc.z += __uint_as_float(uu[t].y << 16);
                acc.w += __uint_as_float(uu[t].y & 0xffff0000u);
            }
        }
        // single masked tail block
        if (j < n) {
            int ss[8]; uint2 uu[8];
            #pragma unroll
            for (int t = 0; t < 8; ++t) {
                int e = j + 2 * t + half;
                ss[t] = __shfl(sv, e < n ? e : n - 1);
            }
            #pragma unroll
            for (int t = 0; t < 8; ++t)
                uu[t] = *(const uint2*)(hp + (size_t)ss[t] * 64 + 2 * c2);
            #pragma unroll
            for (int t = 0; t < 8; ++t) {
                if (j + 2 * t + half < n) {
                    acc.x += __uint_as_float(uu[t].x << 16);
                    acc.y += __uint_as_float(uu[t].x & 0xffff0000u);
                    acc.z += __uint_as_float(uu[t].y << 16);
                    acc.w += __uint_as_float(uu[t].y & 0xffff0000u);
                }
            }
        }
    }

    // combine halves: both sides end with the full sum
    acc.x += __shfl_xor(acc.x, 32);
    acc.y += __shfl_xor(acc.y, 32);
    acc.z += __shfl_xor(acc.z, 32);
    acc.w += __shfl_xor(acc.w, 32);

    unsigned h0 = f2bf(acc.x), h1 = f2bf(acc.y);
    unsigned h2 = f2bf(acc.z), h3 = f2bf(acc.w);
    if (half == 0) {
        uint2 w = { h0 | (h1 << 16), h2 | (h3 << 16) };
        *(uint2*)(Ahi + (size_t)i * 64 + 2 * c2) = w;
    } else {
        float l0 = acc.x - bf2f(h0), l1 = acc.y - bf2f(h1);
        float l2 = acc.z - bf2f(h2), l3 = acc.w - bf2f(h3);
        uint2 w = { f2bf(l0) | (f2bf(l1) << 16), f2bf(l2) | (f2bf(l3) << 16) };
        *(uint2*)(Alo + (size_t)i * 64 + 2 * c2) = w;
    }
}

// ---------------- MFMA GEMM, split-precision bf16 (3-mfma ~ fp32 accuracy) -----

template<bool LAYER0>
__global__ __launch_bounds__(256) void gemm_kernel(
    const unsigned* __restrict__ Ahi_g, const unsigned* __restrict__ Alo_g,
    const float* __restrict__ W, const float* __restrict__ bias,
    const float* __restrict__ norm_s, const float* __restrict__ norm_d,
    const float* __restrict__ gamma, const float* __restrict__ beta,
    const float* __restrict__ rmean, const float* __restrict__ rvar,
    float* __restrict__ outf, unsigned short* __restrict__ outb)
{
    __shared__ unsigned lhi[64 * 68];   // 64 rows x 136 bf16 (pad 8)
    __shared__ unsigned llo[64 * 68];

    const int w    = threadIdx.x >> 6;
    const int lane = threadIdx.x & 63;
    const int quad = lane >> 4;
    const int l16  = lane & 15;

    // ---- B fragments (hi/lo) for this wave's 2 col-tiles, all K ----
    v8s Bhi[2][4], Blo[2][4];
    int col[2];
    #pragma unroll
    for (int ct = 0; ct < 2; ++ct) {
        col[ct] = 32 * w + 16 * ct + l16;
        #pragma unroll
        for (int q = 0; q < 4; ++q) {
            int kb = 32 * q + quad * 8;
            v8s hi8, lo8;
            #pragma unroll
            for (int kk = 0; kk < 8; ++kk) {
                float wv = W[(kb + kk) * D + col[ct]];
                unsigned h = f2bf(wv);
                hi8[kk] = (short)h;
                lo8[kk] = (short)f2bf(wv - bf2f(h));
            }
            Bhi[ct][q] = hi8;
            Blo[ct][q] = lo8;
        }
    }

    float bcol[2], s[2] = {0.f, 0.f}, sh[2] = {0.f, 0.f};
    #pragma unroll
    for (int ct = 0; ct < 2; ++ct) {
        bcol[ct] = bias[col[ct]];
        if (LAYER0) {
            s[ct]  = gamma[col[ct]] * rsqrtf(rvar[col[ct]] + BNEPS);
            sh[ct] = beta[col[ct]] - rmean[col[ct]] * s[ct];
        }
    }

    for (int row0 = blockIdx.x * 64; row0 < NN; row0 += gridDim.x * 64) {
        __syncthreads();
        for (int idx = threadIdx.x; idx < 64 * 64; idx += 256) {
            int r = idx >> 6, cp = idx & 63;
            int rw = row0 + r;
            unsigned vh = 0, vl = 0;
            if (rw < NN) {
                vh = Ahi_g[(size_t)rw * 64 + cp];
                vl = Alo_g[(size_t)rw * 64 + cp];
            }
            lhi[r * 68 + cp] = vh;
            llo[r * 68 + cp] = vl;
        }
        __syncthreads();

        #pragma unroll
        for (int rt = 0; rt < 4; ++rt) {
            v4f acc0 = {0.f, 0.f, 0.f, 0.f};
            v4f acc1 = {0.f, 0.f, 0.f, 0.f};
            #pragma unroll
            for (int q = 0; q < 4; ++q) {
                const unsigned short* ph = (const unsigned short*)lhi
                    + (rt * 16 + l16) * 136 + q * 32 + quad * 8;
                const unsigned short* pl = (const unsigned short*)llo
                    + (rt * 16 + l16) * 136 + q * 32 + quad * 8;
                v8s ahi = *(const v8s*)ph;
                v8s alo = *(const v8s*)pl;
                acc0 = __builtin_amdgcn_mfma_f32_16x16x32_bf16(ahi, Bhi[0][q], acc0, 0, 0, 0);
                acc0 = __builtin_amdgcn_mfma_f32_16x16x32_bf16(alo, Bhi[0][q], acc0, 0, 0, 0);
                acc0 = __builtin_amdgcn_mfma_f32_16x16x32_bf16(ahi, Blo[0][q], acc0, 0, 0, 0);
                acc1 = __builtin_amdgcn_mfma_f32_16x16x32_bf16(ahi, Bhi[1][q], acc1, 0, 0, 0);
                acc1 = __builtin_amdgcn_mfma_f32_16x16x32_bf16(alo, Bhi[1][q], acc1, 0, 0, 0);
                acc1 = __builtin_amdgcn_mfma_f32_16x16x32_bf16(ahi, Blo[1][q], acc1, 0, 0, 0);
            }
            #pragma unroll
            for (int r = 0; r < 4; ++r) {
                int rw = row0 + rt * 16 + quad * 4 + r;
                if (rw >= NN) continue;
                float nd = norm_d[rw];
                float o0 = acc0[r] * nd + bcol[0];
                float o1 = acc1[r] * nd + bcol[1];
                if (LAYER0) {
                    o0 = o0 * s[0] + sh[0];
                    o1 = o1 * s[1] + sh[1];
                    o0 = o0 > 0.f ? o0 : LEAKY * o0;
                    o1 = o1 > 0.f ? o1 : LEAKY * o1;
                    float ns = norm_s[rw];
                    o0 *= ns; o1 *= ns;
                    outb[(size_t)rw * D + col[0]] = (unsigned short)f2bf(o0);
                    outb[(size_t)rw * D + col[1]] = (unsigned short)f2bf(o1);
                } else {
                    outf[(size_t)rw * D + col[0]] = o0;
                    outf[(size_t)rw * D + col[1]] = o1;
                }
            }
        }
    }
}

// ---------------- launch ----------------

extern "C" void kernel_launch(void* const* d_in, const int* in_sizes, int n_in,
                              void* d_out, int out_size, void* d_ws, size_t ws_size,
                              hipStream_t stream) {
    const float* x     = (const float*)d_in[0];
    const int*   src   = (const int*)d_in[1];
    const int*   dst   = (const int*)d_in[2];
    const float* W1    = (const float*)d_in[3];
    const float* b1    = (const float*)d_in[4];
    const float* W2    = (const float*)d_in[5];
    const float* b2    = (const float*)d_in[6];
    const float* gamma = (const float*)d_in[7];
    const float* beta  = (const float*)d_in[8];
    const float* rmean = (const float*)d_in[9];
    const float* rvar  = (const float*)d_in[10];
    float* out = (float*)d_out;

    // bf16 gather-source scratch lives in d_out's first half (dead once the
    // final GEMM overwrites all of d_out with fp32 results).
    unsigned* hb = (unsigned*)d_out;                    // NN*64 u32 = 25.6 MB

    // ws layout (4B units)
    unsigned* Ahi   = (unsigned*)d_ws;                  // NN*64 u32 (bf16 hi pairs)
    unsigned* Alo   = Ahi + (size_t)NN * 64;            // NN*64 u32 (bf16 lo pairs)
    float*    norm  = (float*)(Alo + (size_t)NN * 64);  // 2N f32
    int*      aux   = (int*)(norm + 2 * NN);            // N int slot (bsum2)
    int*      hist  = aux + NN;                         // B*GS int; row[] aliases after scanC
    int*      offs  = hist + B * GS;                    // B*GS int
    int*      bsum  = offs + B * GS;                    // B int
    int*      boffs = bsum + B;                         // B int (unused, layout keep)
    unsigned* ebuf  = (unsigned*)(boffs + B);           // NE u32
    float* norm_s = norm;
    float* norm_d = norm + NN;
    int*   row    = hist;                // aliases hist (B*GS=200192 ints >= NN+1)
    int*   bsum2  = aux;                 // B int

    // src-side scratch aliases the Ahi slot (dead until csr_agg writes it):
    int*           hist2 = (int*)Ahi;                   // B*GS int
    int*           offs2 = hist2 + B * GS;              // B*GS int
    unsigned char* sbuf8 = (unsigned char*)(offs2 + B * GS);  // NE bytes (1.6 MB)

    // counting sort by dst bucket + src-bucket byte scatter (no global atomics)
    hist_kernel<<<GS, 1024, 0, stream>>>(src, dst, hist, hist2);
    scanA2<<<2 * NSB, 256, 0, stream>>>(hist, hist2, bsum, bsum2);
    scanC2<<<2 * NSB, 256, 0, stream>>>(hist, hist2, bsum, bsum2, offs, offs2);
    sort_kernel<<<GS, 1024, 0, stream>>>(src, dst, offs, offs2, ebuf, sbuf8);
    bucket_prep<<<B, 256, 0, stream>>>(offs, offs2, ebuf, sbuf8, x, row,
                                       norm_s, norm_d, hb);

    const int AGG_BLOCKS = (NN + 3) / 4;
    const int GEMM_BLOCKS = 784;
    // layer 0: agg = selfloop + sum_e xs[src]  -> split bf16 hi/lo
    csr_agg<<<AGG_BLOCKS, 256, 0, stream>>>(row, (const int*)ebuf, hb, Ahi, Alo);
    gemm_kernel<true><<<GEMM_BLOCKS, 256, 0, stream>>>(Ahi, Alo, W1, b1,
                                                       norm_s, norm_d,
                                                       gamma, beta, rmean, rvar,
                                                       nullptr, (unsigned short*)hb);
    // layer 1: gather source = bf16 hs (norm_src folded)
    csr_agg<<<AGG_BLOCKS, 256, 0, stream>>>(row, (const int*)ebuf, hb, Ahi, Alo);
    gemm_kernel<false><<<GEMM_BLOCKS, 256, 0, stream>>>(Ahi, Alo, W2, b2,
                                                        norm_s, norm_d,
                                                        nullptr, nullptr, nullptr, nullptr,
                                                        out, nullptr);
}

// Round 11
// 375.472 us; speedup vs baseline: 1.4394x; 1.0428x over previous
//
#include <hip/hip_runtime.h>

#define NN 100000
#define NE 1600000
#define D 128
#define LEAKY 0.01f
#define BNEPS 1e-5f

#define GS 256        // sort groups (full machine)
#define CHUNK 6250    // NE / GS exactly
#define B 782         // ceil(NN/128) buckets (128 nodes each)
#define BSHIFT 7
#define BMASK 127
#define NSB (B * GS / 256)   // 782 scan blocks per histogram

typedef short v8s __attribute__((ext_vector_type(8)));
typedef float v4f __attribute__((ext_vector_type(4)));

// round-to-nearest-even f32 -> bf16 (returns low 16 bits)
__device__ __forceinline__ unsigned f2bf(float f) {
    unsigned u = __float_as_uint(f);
    return (u + 0x7fffu + ((u >> 16) & 1u)) >> 16;
}
__device__ __forceinline__ float bf2f(unsigned h) {
    return __uint_as_float(h << 16);
}

// ---------------- counting sort by dst bucket + src bucket ---------------------

__global__ __launch_bounds__(1024) void hist_kernel(const int* __restrict__ src,
                                                    const int* __restrict__ dst,
                                                    int* __restrict__ hist,
                                                    int* __restrict__ hist2) {
    __shared__ int h[B];
    __shared__ int h2[B];
    for (int i = threadIdx.x; i < B; i += 1024) { h[i] = 0; h2[i] = 0; }
    __syncthreads();
    int g = blockIdx.x;
    const int* dp = dst + g * CHUNK;
    const int* sp = src + g * CHUNK;
    for (int k = threadIdx.x; k < CHUNK; k += 1024) {
        atomicAdd(&h[dp[k] >> BSHIFT], 1);
        atomicAdd(&h2[sp[k] >> BSHIFT], 1);
    }
    __syncthreads();
    for (int i = threadIdx.x; i < B; i += 1024) {
        hist[i * GS + g]  = h[i];
        hist2[i * GS + g] = h2[i];
    }
}

__global__ void scanA2(const int* __restrict__ a, const int* __restrict__ a2,
                       int* __restrict__ bsum, int* __restrict__ bsum2) {
    __shared__ int sm[256];
    int t = threadIdx.x;
    bool second = blockIdx.x >= NSB;
    int blk = second ? blockIdx.x - NSB : blockIdx.x;
    const int* sp = second ? a2 : a;
    sm[t] = sp[blk * 256 + t];
    __syncthreads();
    for (int s = 128; s > 0; s >>= 1) {
        if (t < s) sm[t] += sm[t + s];
        __syncthreads();
    }
    if (t == 0) (second ? bsum2 : bsum)[blk] = sm[0];
}

// scanB folded in — each block derives its own offset from bsum
__global__ void scanC2(const int* __restrict__ a, const int* __restrict__ a2,
                       const int* __restrict__ bsum, const int* __restrict__ bsum2,
                       int* __restrict__ offs, int* __restrict__ offs2) {
    __shared__ int sm[256];
    __shared__ int bo;
    int t = threadIdx.x;
    bool second = blockIdx.x >= NSB;
    int blk = second ? blockIdx.x - NSB : blockIdx.x;
    const int* sp = second ? a2 : a;
    const int* bs = second ? bsum2 : bsum;
    int part = 0;
    for (int j = t; j < blk; j += 256) part += bs[j];
    sm[t] = part;
    __syncthreads();
    for (int s = 128; s > 0; s >>= 1) {
        if (t < s) sm[t] += sm[t + s];
        __syncthreads();
    }
    if (t == 0) bo = sm[0];
    __syncthreads();
    int i = blk * 256 + t;
    int v = sp[i];
    sm[t] = v;
    __syncthreads();
    for (int off = 1; off < 256; off <<= 1) {
        int x = (t >= off) ? sm[t - off] : 0;
        __syncthreads();
        sm[t] += x;
        __syncthreads();
    }
    (second ? offs2 : offs)[i] = bo + sm[t] - v;    // exclusive
}

// inclusive scan over 1024 threads: wave shfl-scan + 16-wave LDS combine
// (2 barriers vs Hillis-Steele's 20)
__device__ __forceinline__ int scan1024_incl(int v, int t, int* ws) {
    int lane = t & 63, wid = t >> 6;
    for (int off = 1; off < 64; off <<= 1) {
        int x = __shfl_up(v, off);
        if (lane >= off) v += x;
    }
    if (lane == 63) ws[wid] = v;
    __syncthreads();
    if (wid == 0) {
        int w = (lane < 16) ? ws[lane] : 0;
        for (int off = 1; off < 16; off <<= 1) {
            int x = __shfl_up(w, off);
            if (lane >= off) w += x;
        }
        if (lane < 16) ws[lane] = w;
    }
    __syncthreads();
    return v + (wid ? ws[wid - 1] : 0);
}

// ---------------- sort: LDS-staged local counting sort -------------------------
// Round-11: pass-1 recount deleted — per-block counts are exactly hist[i*GS+g]
// (written by hist_kernel, untouched until bucket_prep aliases row onto hist).
// Saves 12.8 MB global re-read + 3.2M LDS atomics per launch. Scans use
// wave-shfl (2 barriers vs 20). Write-out stays coalesced (round-10 win).

__global__ __launch_bounds__(1024) void sort_kernel(const int* __restrict__ src,
                                                    const int* __restrict__ dst,
                                                    const int* __restrict__ hist,
                                                    const int* __restrict__ hist2,
                                                    const int* __restrict__ offs,
                                                    const int* __restrict__ offs2,
                                                    unsigned* __restrict__ ebuf,
                                                    unsigned char* __restrict__ sbuf8) {
    __shared__ unsigned      lbuf[CHUNK];       // 25000 B
    __shared__ unsigned char lbuf2[CHUNK];      //  6250 B
    __shared__ int lst [B + 1];                 // local exclusive starts (dst)
    __shared__ int lst2[B + 1];                 // local exclusive starts (src)
    __shared__ int cur [B];                     // cursors
    __shared__ int cur2[B];
    __shared__ int ws[16];                      // wave-scan scratch

    const int g = blockIdx.x;
    const int t = threadIdx.x;
    const int* sp = src + g * CHUNK;
    const int* dp = dst + g * CHUNK;

    // local exclusive starts from precomputed histogram columns
    {
        int v = (t < B) ? hist[t * GS + g] : 0;
        int incl = scan1024_incl(v, t, ws);
        if (t < B) { lst[t] = incl - v; cur[t] = incl - v; }
        if (t == 0) lst[B] = CHUNK;
    }
    __syncthreads();
    {
        int v = (t < B) ? hist2[t * GS + g] : 0;
        int incl = scan1024_incl(v, t, ws);
        if (t < B) { lst2[t] = incl - v; cur2[t] = incl - v; }
        if (t == 0) lst2[B] = CHUNK;
    }
    __syncthreads();

    // place into LDS
    for (int k = t; k < CHUNK; k += 1024) {
        int d = dp[k], s = sp[k];
        int p  = atomicAdd(&cur [d >> BSHIFT], 1);
        lbuf[p] = ((unsigned)(d & BMASK) << 17) | (unsigned)s;   // src < 2^17
        int p2 = atomicAdd(&cur2[s >> BSHIFT], 1);
        lbuf2[p2] = (unsigned char)(s & BMASK);
    }
    __syncthreads();

    // write-out: consecutive idx -> consecutive global addresses within runs
    for (int idx = t; idx < CHUNK; idx += 1024) {
        int lo = 0, hi = B;
        while (hi - lo > 1) { int mid = (lo + hi) >> 1; if (lst[mid] <= idx) lo = mid; else hi = mid; }
        ebuf[offs[lo * GS + g] + (idx - lst[lo])] = lbuf[idx];
    }
    for (int idx = t; idx < CHUNK; idx += 1024) {
        int lo = 0, hi = B;
        while (hi - lo > 1) { int mid = (lo + hi) >> 1; if (lst2[mid] <= idx) lo = mid; else hi = mid; }
        sbuf8[offs2[lo * GS + g] + (idx - lst2[lo])] = lbuf2[idx];
    }
}

// ---------------- bucket_prep: (out-deg + conv) then (local sort -> CSR) -------

__global__ __launch_bounds__(256) void bucket_prep(
    const int* __restrict__ offs, const int* __restrict__ offs2,
    unsigned* __restrict__ ebuf, const unsigned char* __restrict__ sbuf8,
    const float* __restrict__ x, int* __restrict__ row,
    float* __restrict__ norm_s, float* __restrict__ norm_d,
    unsigned* __restrict__ hb)
{
    __shared__ int cnt[128];
    __shared__ int sc[128];
    __shared__ float nsm[128];
    const int b = blockIdx.x;
    const int t = threadIdx.x;

    // ---- part 1: out-degree count + norm_s + x*norm_s -> bf16 hb ----
    {
        const int s = offs2[b * GS];
        const int e = (b == B - 1) ? NE : offs2[(b + 1) * GS];
        if (t < 128) cnt[t] = 0;
        __syncthreads();
        for (int k = s + t; k < e; k += 256)
            atomicAdd(&cnt[sbuf8[k]], 1);
        __syncthreads();
        if (t < 128) {
            int node = b * 128 + t;
            if (node < NN) {
                float ns = rsqrtf((float)(cnt[t] + 1));   // +1 = self-loop
                norm_s[node] = ns;
                nsm[t] = ns;
            }
        }
        __syncthreads();
        for (int idx = t; idx < 128 * 32; idx += 256) {
            int r = idx >> 5, q = idx & 31;
            int node = b * 128 + r;
            if (node >= NN) continue;
            float ns = nsm[r];
            float4 v = ((const float4*)x)[(size_t)node * 32 + q];
            uint2 w;
            w.x = f2bf(v.x * ns) | (f2bf(v.y * ns) << 16);
            w.y = f2bf(v.z * ns) | (f2bf(v.w * ns) << 16);
            *(uint2*)(hb + (size_t)node * 64 + 2 * q) = w;
        }
    }
    __syncthreads();

    // ---- part 2: per-bucket local sort: bucket order -> per-node CSR ----
    {
        const int s = offs[b * GS];
        const int e = (b == B - 1) ? NE : offs[(b + 1) * GS];
        if (t < 128) cnt[t] = 0;
        __syncthreads();

        unsigned ent[16];   // 16*256 = 4096 capacity; bucket mean 2048, sd ~45
        int nent = 0;
        for (int k = s + t; k < e && nent < 16; k += 256) {
            unsigned u = ebuf[k];
            ent[nent++] = u;
            atomicAdd(&cnt[u >> 17], 1);
        }
        __syncthreads();

        if (t < 128) sc[t] = cnt[t];
        __syncthreads();
        for (int off = 1; off < 128; off <<= 1) {
            int v = 0;
            if (t < 128 && t >= off) v = sc[t - off];
            __syncthreads();
            if (t < 128) sc[t] += v;
            __syncthreads();
        }
        if (t < 128) {
            int st = s + sc[t] - cnt[t];   // exclusive start
            int node = b * 128 + t;
            if (node < NN) {
                row[node] = st;
                norm_d[node] = rsqrtf((float)(cnt[t] + 1));
            }
            cnt[t] = st;                   // becomes cursor
        }
        if (b == B - 1 && t == 0) row[NN] = NE;
        __syncthreads();

        for (int i = 0; i < nent; ++i) {
            unsigned u = ent[i];
            int pos = atomicAdd(&cnt[u >> 17], 1);
            ebuf[pos] = u & 0x1FFFFu;      // strip bucket bits -> plain src id
        }
    }
}

// ---------------- CSR gather-aggregate over bf16 rows, fp32 accumulate --------
// Proven optimum (round 6/8): 8-deep uint2 batches, VGPR 32, occ 72%. n is
// wave-uniform: full 16-edge blocks unpredicated/unclamped; one masked tail.

__global__ __launch_bounds__(256) void csr_agg(
    const int* __restrict__ rowp, const int* __restrict__ csr,
    const unsigned* __restrict__ hp,
    unsigned* __restrict__ Ahi, unsigned* __restrict__ Alo)
{
    int i = blockIdx.x * 4 + (threadIdx.x >> 6);
    if (i >= NN) return;
    const int lane = threadIdx.x & 63;
    const int half = lane >> 5;     // 0: even edges, 1: odd edges
    const int c2   = lane & 31;     // u32 column pair [2c2, 2c2+1]

    float4 acc = {0.f, 0.f, 0.f, 0.f};
    if (half == 0) {                // self-loop row counted once
        uint2 u = *(const uint2*)(hp + (size_t)i * 64 + 2 * c2);
        acc.x = __uint_as_float(u.x << 16);
        acc.y = __uint_as_float(u.x & 0xffff0000u);
        acc.z = __uint_as_float(u.y << 16);
        acc.w = __uint_as_float(u.y & 0xffff0000u);
    }

    int start = rowp[i], end = rowp[i + 1];
    for (int base = start; base < end; base += 64) {
        int n = end - base; if (n > 64) n = 64;
        int sv = csr[base + (lane < n ? lane : n - 1)];
        int nfull = n & ~15;
        int j = 0;
        // full blocks: unpredicated, unclamped
        for (; j < nfull; j += 16) {
            int ss[8]; uint2 uu[8];
            #pragma unroll
            for (int t = 0; t < 8; ++t) ss[t] = __shfl(sv, j + 2 * t + half);
            #pragma unroll
            for (int t = 0; t < 8; ++t)
                uu[t] = *(const uint2*)(hp + (size_t)ss[t] * 64 + 2 * c2);
            #pragma unroll
            for (int t = 0; t < 8; ++t) {
                acc.x += __uint_as_float(uu[t].x << 16);
                acc.y += __uint_as_float(uu[t].x & 0xffff0000u);
                acc.z += __uint_as_float(uu[t].y << 16);
                acc.w += __uint_as_float(uu[t].y & 0xffff0000u);
            }
        }
        // single masked tail block
        if (j < n) {
            int ss[8]; uint2 uu[8];
            #pragma unroll
            for (int t = 0; t < 8; ++t) {
                int e = j + 2 * t + half;
                ss[t] = __shfl(sv, e < n ? e : n - 1);
            }
            #pragma unroll
            for (int t = 0; t < 8; ++t)
                uu[t] = *(const uint2*)(hp + (size_t)ss[t] * 64 + 2 * c2);
            #pragma unroll
            for (int t = 0; t < 8; ++t) {
                if (j + 2 * t + half < n) {
                    acc.x += __uint_as_float(uu[t].x << 16);
                    acc.y += __uint_as_float(uu[t].x & 0xffff0000u);
                    acc.z += __uint_as_float(uu[t].y << 16);
                    acc.w += __uint_as_float(uu[t].y & 0xffff0000u);
                }
            }
        }
    }

    // combine halves: both sides end with the full sum
    acc.x += __shfl_xor(acc.x, 32);
    acc.y += __shfl_xor(acc.y, 32);
    acc.z += __shfl_xor(acc.z, 32);
    acc.w += __shfl_xor(acc.w, 32);

    unsigned h0 = f2bf(acc.x), h1 = f2bf(acc.y);
    unsigned h2 = f2bf(acc.z), h3 = f2bf(acc.w);
    if (half == 0) {
        uint2 w = { h0 | (h1 << 16), h2 | (h3 << 16) };
        *(uint2*)(Ahi + (size_t)i * 64 + 2 * c2) = w;
    } else {
        float l0 = acc.x - bf2f(h0), l1 = acc.y - bf2f(h1);
        float l2 = acc.z - bf2f(h2), l3 = acc.w - bf2f(h3);
        uint2 w = { f2bf(l0) | (f2bf(l1) << 16), f2bf(l2) | (f2bf(l3) << 16) };
        *(uint2*)(Alo + (size_t)i * 64 + 2 * c2) = w;
    }
}

// ---------------- MFMA GEMM, split-precision bf16 (3-mfma ~ fp32 accuracy) -----

template<bool LAYER0>
__global__ __launch_bounds__(256) void gemm_kernel(
    const unsigned* __restrict__ Ahi_g, const unsigned* __restrict__ Alo_g,
    const float* __restrict__ W, const float* __restrict__ bias,
    const float* __restrict__ norm_s, const float* __restrict__ norm_d,
    const float* __restrict__ gamma, const float* __restrict__ beta,
    const float* __restrict__ rmean, const float* __restrict__ rvar,
    float* __restrict__ outf, unsigned short* __restrict__ outb)
{
    __shared__ unsigned lhi[64 * 68];   // 64 rows x 136 bf16 (pad 8)
    __shared__ unsigned llo[64 * 68];

    const int w    = threadIdx.x >> 6;
    const int lane = threadIdx.x & 63;
    const int quad = lane >> 4;
    const int l16  = lane & 15;

    // ---- B fragments (hi/lo) for this wave's 2 col-tiles, all K ----
    v8s Bhi[2][4], Blo[2][4];
    int col[2];
    #pragma unroll
    for (int ct = 0; ct < 2; ++ct) {
        col[ct] = 32 * w + 16 * ct + l16;
        #pragma unroll
        for (int q = 0; q < 4; ++q) {
            int kb = 32 * q + quad * 8;
            v8s hi8, lo8;
            #pragma unroll
            for (int kk = 0; kk < 8; ++kk) {
                float wv = W[(kb + kk) * D + col[ct]];
                unsigned h = f2bf(wv);
                hi8[kk] = (short)h;
                lo8[kk] = (short)f2bf(wv - bf2f(h));
            }
            Bhi[ct][q] = hi8;
            Blo[ct][q] = lo8;
        }
    }

    float bcol[2], s[2] = {0.f, 0.f}, sh[2] = {0.f, 0.f};
    #pragma unroll
    for (int ct = 0; ct < 2; ++ct) {
        bcol[ct] = bias[col[ct]];
        if (LAYER0) {
            s[ct]  = gamma[col[ct]] * rsqrtf(rvar[col[ct]] + BNEPS);
            sh[ct] = beta[col[ct]] - rmean[col[ct]] * s[ct];
        }
    }

    for (int row0 = blockIdx.x * 64; row0 < NN; row0 += gridDim.x * 64) {
        __syncthreads();
        for (int idx = threadIdx.x; idx < 64 * 64; idx += 256) {
            int r = idx >> 6, cp = idx & 63;
            int rw = row0 + r;
            unsigned vh = 0, vl = 0;
            if (rw < NN) {
                vh = Ahi_g[(size_t)rw * 64 + cp];
                vl = Alo_g[(size_t)rw * 64 + cp];
            }
            lhi[r * 68 + cp] = vh;
            llo[r * 68 + cp] = vl;
        }
        __syncthreads();

        #pragma unroll
        for (int rt = 0; rt < 4; ++rt) {
            v4f acc0 = {0.f, 0.f, 0.f, 0.f};
            v4f acc1 = {0.f, 0.f, 0.f, 0.f};
            #pragma unroll
            for (int q = 0; q < 4; ++q) {
                const unsigned short* ph = (const unsigned short*)lhi
                    + (rt * 16 + l16) * 136 + q * 32 + quad * 8;
                const unsigned short* pl = (const unsigned short*)llo
                    + (rt * 16 + l16) * 136 + q * 32 + quad * 8;
                v8s ahi = *(const v8s*)ph;
                v8s alo = *(const v8s*)pl;
                acc0 = __builtin_amdgcn_mfma_f32_16x16x32_bf16(ahi, Bhi[0][q], acc0, 0, 0, 0);
                acc0 = __builtin_amdgcn_mfma_f32_16x16x32_bf16(alo, Bhi[0][q], acc0, 0, 0, 0);
                acc0 = __builtin_amdgcn_mfma_f32_16x16x32_bf16(ahi, Blo[0][q], acc0, 0, 0, 0);
                acc1 = __builtin_amdgcn_mfma_f32_16x16x32_bf16(ahi, Bhi[1][q], acc1, 0, 0, 0);
                acc1 = __builtin_amdgcn_mfma_f32_16x16x32_bf16(alo, Bhi[1][q], acc1, 0, 0, 0);
                acc1 = __builtin_amdgcn_mfma_f32_16x16x32_bf16(ahi, Blo[1][q], acc1, 0, 0, 0);
            }
            #pragma unroll
            for (int r = 0; r < 4; ++r) {
                int rw = row0 + rt * 16 + quad * 4 + r;
                if (rw >= NN) continue;
                float nd = norm_d[rw];
                float o0 = acc0[r] * nd + bcol[0];
                float o1 = acc1[r] * nd + bcol[1];
                if (LAYER0) {
                    o0 = o0 * s[0] + sh[0];
                    o1 = o1 * s[1] + sh[1];
                    o0 = o0 > 0.f ? o0 : LEAKY * o0;
                    o1 = o1 > 0.f ? o1 : LEAKY * o1;
                    float ns = norm_s[rw];
                    o0 *= ns; o1 *= ns;
                    outb[(size_t)rw * D + col[0]] = (unsigned short)f2bf(o0);
                    outb[(size_t)rw * D + col[1]] = (unsigned short)f2bf(o1);
                } else {
                    outf[(size_t)rw * D + col[0]] = o0;
                    outf[(size_t)rw * D + col[1]] = o1;
                }
            }
        }
    }
}

// ---------------- launch ----------------

extern "C" void kernel_launch(void* const* d_in, const int* in_sizes, int n_in,
                              void* d_out, int out_size, void* d_ws, size_t ws_size,
                              hipStream_t stream) {
    const float* x     = (const float*)d_in[0];
    const int*   src   = (const int*)d_in[1];
    const int*   dst   = (const int*)d_in[2];
    const float* W1    = (const float*)d_in[3];
    const float* b1    = (const float*)d_in[4];
    const float* W2    = (const float*)d_in[5];
    const float* b2    = (const float*)d_in[6];
    const float* gamma = (const float*)d_in[7];
    const float* beta  = (const float*)d_in[8];
    const float* rmean = (const float*)d_in[9];
    const float* rvar  = (const float*)d_in[10];
    float* out = (float*)d_out;

    // bf16 gather-source scratch lives in d_out's first half (dead once the
    // final GEMM overwrites all of d_out with fp32 results).
    unsigned* hb = (unsigned*)d_out;                    // NN*64 u32 = 25.6 MB

    // ws layout (4B units)
    unsigned* Ahi   = (unsigned*)d_ws;                  // NN*64 u32 (bf16 hi pairs)
    unsigned* Alo   = Ahi + (size_t)NN * 64;            // NN*64 u32 (bf16 lo pairs)
    float*    norm  = (float*)(Alo + (size_t)NN * 64);  // 2N f32
    int*      aux   = (int*)(norm + 2 * NN);            // N int slot (bsum2)
    int*      hist  = aux + NN;                         // B*GS int; row[] aliases after sort
    int*      offs  = hist + B * GS;                    // B*GS int
    int*      bsum  = offs + B * GS;                    // B int
    int*      boffs = bsum + B;                         // B int (unused, layout keep)
    unsigned* ebuf  = (unsigned*)(boffs + B);           // NE u32
    float* norm_s = norm;
    float* norm_d = norm + NN;
    int*   row    = hist;                // aliases hist (dead after sort_kernel)
    int*   bsum2  = aux;                 // B int

    // src-side scratch aliases the Ahi slot (dead until csr_agg writes it):
    int*           hist2 = (int*)Ahi;                   // B*GS int
    int*           offs2 = hist2 + B * GS;              // B*GS int
    unsigned char* sbuf8 = (unsigned char*)(offs2 + B * GS);  // NE bytes (1.6 MB)

    // counting sort by dst bucket + src-bucket byte scatter (no global atomics)
    hist_kernel<<<GS, 1024, 0, stream>>>(src, dst, hist, hist2);
    scanA2<<<2 * NSB, 256, 0, stream>>>(hist, hist2, bsum, bsum2);
    scanC2<<<2 * NSB, 256, 0, stream>>>(hist, hist2, bsum, bsum2, offs, offs2);
    sort_kernel<<<GS, 1024, 0, stream>>>(src, dst, hist, hist2, offs, offs2,
                                         ebuf, sbuf8);
    bucket_prep<<<B, 256, 0, stream>>>(offs, offs2, ebuf, sbuf8, x, row,
                                       norm_s, norm_d, hb);

    const int AGG_BLOCKS = (NN + 3) / 4;
    const int GEMM_BLOCKS = 1563;   // one 64-row tile per block
    // layer 0: agg = selfloop + sum_e xs[src]  -> split bf16 hi/lo
    csr_agg<<<AGG_BLOCKS, 256, 0, stream>>>(row, (const int*)ebuf, hb, Ahi, Alo);
    gemm_kernel<true><<<GEMM_BLOCKS, 256, 0, stream>>>(Ahi, Alo, W1, b1,
                                                       norm_s, norm_d,
                                                       gamma, beta, rmean, rvar,
                                                       nullptr, (unsigned short*)hb);
    // layer 1: gather source = bf16 hs (norm_src folded)
    csr_agg<<<AGG_BLOCKS, 256, 0, stream>>>(row, (const int*)ebuf, hb, Ahi, Alo);
    gemm_kernel<false><<<GEMM_BLOCKS, 256, 0, stream>>>(Ahi, Alo, W2, b2,
                                                        norm_s, norm_d,
                                                        nullptr, nullptr, nullptr, nullptr,
                                                        out, nullptr);
}